// Round 13
// baseline (534.099 us; speedup 1.0000x reference)
//
#include <hip/hip_runtime.h>
#include <math.h>

#define HW 21025        // 145*145
#define Hdim 145
#define Wdim 145
#define NBANDS 200
#define CONVH 147
#define CONVHW 21609    // 147*147
#define QC 64
#define NCH 329         // ceil(21025/64)
#define DTP 21056       // padded L for transposed dt
#define SP 72           // short stride for [.][64-k] MFMA tiles
#define SSD_GRID 1344   // 8 * 4 * 42 (xcd-sibling swizzled, tail-guarded)

typedef __attribute__((ext_vector_type(4))) float fv4;
typedef __attribute__((ext_vector_type(8))) short short8;

// ---------------- workspace layout (float offsets) ----------------
#define OFF_XN   ((size_t)0)           // 4,205,000  xn; later cls0
#define OFF_F1   ((size_t)4205000)     // 5,382,400  f1; later y (L x 256)
#define OFF_COMB ((size_t)9587400)     // 4,036,800  comb L x 192
#define OFF_P    ((size_t)13624200)    // 2,691,200  p; later cls1
#define OFF_ZX   ((size_t)16315400)    // 16,231,300 zxbcdt L x 772
#define OFF_XBC  ((size_t)32546700)    // 10,764,800 c1h+c2h first, then xbc packed u32
#define OFF_S    ((size_t)43311500)    // S as bf16 ushort
#define OFF_DT   ((size_t)54092172)    // 84,224 (dt transposed [4][DTP])
#define OFF_CT   ((size_t)54176396)    // 1,316
#define OFF_W    ((size_t)54177712)    // 82,944: packed conv weights (bf16 hi/lo)
#define OFF_WG   ((size_t)54260656)    // 262,144 u32: packed FC weights [col][Kp]

// FC weight segment offsets (u32 elems)
#define WG_FE1   0        // 256 cols x Kp224
#define WG_FE2   57344    // 128 x 256
#define WG_MP    90112    // 128 x 192
#define WG_IN    114688   // 768 x 128
#define WG_OUT   212992   // 128 x 256
#define WG_CLS1  245760   // 128 x 128
#define WG_TOTAL 262144

__device__ __forceinline__ float gelu_f(float x){
    return 0.5f * x * (1.0f + erff(x * 0.70710678118654752440f));
}
__device__ __forceinline__ float silu_f(float x){
    return x / (1.0f + expf(-x));
}

__device__ __forceinline__ void bf16_split(float x, unsigned short& hs, unsigned short& ls){
    unsigned u = __float_as_uint(x);
    hs = (unsigned short)(u >> 16);
    float hif = __uint_as_float(u & 0xFFFF0000u);
    float lof = x - hif;
    ls = (unsigned short)(__float_as_uint(lof) >> 16);
}
__device__ __forceinline__ unsigned pack2(unsigned short a, unsigned short b){
    return (unsigned)a | ((unsigned)b << 16);
}
__device__ __forceinline__ unsigned packsplit(float x){
    unsigned short hs, ls;
    bf16_split(x, hs, ls);
    return ((unsigned)hs << 16) | (unsigned)ls;
}
__device__ __forceinline__ float unpackf(unsigned u){
    return __uint_as_float(u & 0xFFFF0000u) + __uint_as_float(u << 16);
}
__device__ __forceinline__ unsigned short bf16rnd(float x){
    unsigned u = __float_as_uint(x);
    unsigned r = u + 0x7FFFu + ((u >> 16) & 1u);
    return (unsigned short)(r >> 16);
}
__device__ __forceinline__ float bf16f(unsigned short h){
    return __uint_as_float((unsigned)h << 16);
}
__device__ __forceinline__ void unpack8(const unsigned* p, short8& h8, short8& l8){
    uint4 a = *reinterpret_cast<const uint4*>(p);
    uint4 b = *reinterpret_cast<const uint4*>(p + 4);
    unsigned v0 = a.x, v1 = a.y, v2 = a.z, v3 = a.w;
    unsigned v4 = b.x, v5 = b.y, v6 = b.z, v7 = b.w;
    h8[0]=(short)(v0>>16); l8[0]=(short)(v0&0xFFFFu);
    h8[1]=(short)(v1>>16); l8[1]=(short)(v1&0xFFFFu);
    h8[2]=(short)(v2>>16); l8[2]=(short)(v2&0xFFFFu);
    h8[3]=(short)(v3>>16); l8[3]=(short)(v3&0xFFFFu);
    h8[4]=(short)(v4>>16); l8[4]=(short)(v4&0xFFFFu);
    h8[5]=(short)(v5>>16); l8[5]=(short)(v5&0xFFFFu);
    h8[6]=(short)(v6>>16); l8[6]=(short)(v6&0xFFFFu);
    h8[7]=(short)(v7>>16); l8[7]=(short)(v7&0xFFFFu);
}
__device__ __forceinline__ void split8f(fv4 a0, fv4 a1, short8& h8, short8& l8){
    unsigned short hs, ls;
    #pragma unroll
    for (int j = 0; j < 4; j++){
        bf16_split(a0[j], hs, ls); h8[j] = (short)hs; l8[j] = (short)ls;
        bf16_split(a1[j], hs, ls); h8[4 + j] = (short)hs; l8[4 + j] = (short)ls;
    }
}

// XCD-grouped decode
__device__ __forceinline__ bool gemm_decode(int bid, int NXB, int NYB, int& bx, int& by){
    int m = bid & 7;
    int r = bid >> 3;
    bx = r % NXB;
    by = (r / NXB) * 8 + m;
    return by < NYB;
}
__host__ __forceinline__ int gemm_grid(int NXB, int NYB){ return 8 * ((NYB + 7) / 8) * NXB; }

// ---------------- LayerNorm (pre-LN only) ----------------
template<int ACT>
__global__ void ln_kernel(const float* __restrict__ in, const float* __restrict__ g,
                          const float* __restrict__ b, float* __restrict__ out, int D){
    int row = blockIdx.x, tid = threadIdx.x;
    const float* r = in + (size_t)row * D;
    float s = 0.f, s2 = 0.f;
    for (int i = tid; i < D; i += 256){ float v = r[i]; s += v; s2 += v*v; }
    __shared__ float r1[4], r2[4];
    #pragma unroll
    for (int o = 32; o > 0; o >>= 1){ s += __shfl_down(s, o); s2 += __shfl_down(s2, o); }
    if ((tid & 63) == 0){ r1[tid >> 6] = s; r2[tid >> 6] = s2; }
    __syncthreads();
    float S = r1[0] + r1[1] + r1[2] + r1[3];
    float S2 = r2[0] + r2[1] + r2[2] + r2[3];
    float mean = S / (float)D;
    float var = S2 / (float)D - mean * mean;
    float rs = rsqrtf(fmaxf(var, 0.f) + 1e-5f);
    float* o_ = out + (size_t)row * D;
    for (int i = tid; i < D; i += 256){
        float v = (r[i] - mean) * rs * g[i] + b[i];
        if (ACT == 1) v = gelu_f(v);
        o_[i] = v;
    }
}

// ---------------- FC weight prepack: [col][Kp] packed (hi<<16|lo) ----------------
__global__ void prep_fc(const float* __restrict__ fe_w1, const float* __restrict__ fe_w2,
                        const float* __restrict__ mp_w, const float* __restrict__ in_w,
                        const float* __restrict__ out_w, const float* __restrict__ cls_w1,
                        unsigned* __restrict__ Wg){
    int idx = blockIdx.x * 256 + threadIdx.x;
    if (idx >= WG_TOTAL) return;
    const float* src; int Ksrc, Kp, ld, local;
    if (idx < WG_FE2)      { src = fe_w1;  Ksrc = 200; Kp = 224; ld = 256; local = idx; }
    else if (idx < WG_MP)  { src = fe_w2;  Ksrc = 256; Kp = 256; ld = 128; local = idx - WG_FE2; }
    else if (idx < WG_IN)  { src = mp_w;   Ksrc = 192; Kp = 192; ld = 128; local = idx - WG_MP; }
    else if (idx < WG_OUT) { src = in_w;   Ksrc = 128; Kp = 128; ld = 772; local = idx - WG_IN; }
    else if (idx < WG_CLS1){ src = out_w;  Ksrc = 256; Kp = 256; ld = 128; local = idx - WG_OUT; }
    else                   { src = cls_w1; Ksrc = 128; Kp = 128; ld = 128; local = idx - WG_CLS1; }
    int col = local / Kp, k = local % Kp;
    float v = (k < Ksrc) ? src[(size_t)k * ld + col] : 0.f;
    Wg[idx] = packsplit(v);
}

// ---------------- direct (LDS-free, barrier-free) split-bf16 MFMA GEMM -------------
// Each wave: MF*16 rows x 128 cols. ACT: 0 none, 1 gelu, 2 LN, 3 LN+gelu (N==128).
template<int ACT, int MF>
__global__ __launch_bounds__(256) void gemm_direct(const float* __restrict__ A, int lda,
                                                   const unsigned* __restrict__ Wg,
                                                   const float* __restrict__ bias,
                                                   const float* __restrict__ lng,
                                                   const float* __restrict__ lnb,
                                                   float* __restrict__ C, int ldc,
                                                   int M, int N, int K, int Kp,
                                                   int NXB, int NYB){
    int bx, by;
    if (!gemm_decode(blockIdx.x, NXB, NYB, bx, by)) return;
    int tid = threadIdx.x;
    int w = tid >> 6, lane = tid & 63;
    int l15 = lane & 15, g = lane >> 4;
    int bn = bx * 128;
    int bm_w = by * (4 * MF * 16) + w * (MF * 16);

    int arow[MF];
    #pragma unroll
    for (int mf = 0; mf < MF; mf++) arow[mf] = min(bm_w + mf * 16 + l15, M - 1);

    fv4 acc[MF][8];
    #pragma unroll
    for (int mf = 0; mf < MF; mf++)
        #pragma unroll
        for (int ni = 0; ni < 8; ni++) acc[mf][ni] = (fv4){0.f,0.f,0.f,0.f};

    for (int k0 = 0; k0 < K; k0 += 32){
        short8 ah[MF], al[MF];
        #pragma unroll
        for (int mf = 0; mf < MF; mf++){
            const float* ap = A + (size_t)arow[mf] * lda + k0 + g * 8;
            fv4 a0 = (fv4){0.f,0.f,0.f,0.f}, a1 = (fv4){0.f,0.f,0.f,0.f};
            if (k0 + g * 8 + 4 <= K) a0 = *reinterpret_cast<const fv4*>(ap);
            if (k0 + g * 8 + 8 <= K) a1 = *reinterpret_cast<const fv4*>(ap + 4);
            split8f(a0, a1, ah[mf], al[mf]);
        }
        #pragma unroll
        for (int ni = 0; ni < 8; ni++){
            const unsigned* bp = Wg + (size_t)(bn + ni * 16 + l15) * Kp + k0 + g * 8;
            short8 bh, bl;
            unpack8(bp, bh, bl);
            #pragma unroll
            for (int mf = 0; mf < MF; mf++){
                acc[mf][ni] = __builtin_amdgcn_mfma_f32_16x16x32_bf16(ah[mf], bh, acc[mf][ni], 0, 0, 0);
                acc[mf][ni] = __builtin_amdgcn_mfma_f32_16x16x32_bf16(ah[mf], bl, acc[mf][ni], 0, 0, 0);
                acc[mf][ni] = __builtin_amdgcn_mfma_f32_16x16x32_bf16(al[mf], bh, acc[mf][ni], 0, 0, 0);
            }
        }
    }
    // epilogue (per-wave; no LDS)
    float bv[8], lgv[8], lbv[8];
    #pragma unroll
    for (int ni = 0; ni < 8; ni++){
        int cc = bn + ni * 16 + l15;
        bv[ni] = bias ? bias[cc] : 0.f;
        if (ACT >= 2){ lgv[ni] = lng[cc]; lbv[ni] = lnb[cc]; }
    }
    #pragma unroll
    for (int mf = 0; mf < MF; mf++){
        if (ACT >= 2){
            #pragma unroll
            for (int j = 0; j < 4; j++){
                int row = bm_w + mf * 16 + g * 4 + j;
                float s = 0.f, s2 = 0.f;
                #pragma unroll
                for (int ni = 0; ni < 8; ni++){
                    float v = acc[mf][ni][j] + bv[ni];
                    s += v; s2 += v * v;
                }
                #pragma unroll
                for (int o = 1; o < 16; o <<= 1){
                    s += __shfl_xor(s, o); s2 += __shfl_xor(s2, o);
                }
                float mean = s / 128.f;
                float var = s2 / 128.f - mean * mean;
                float rsq = rsqrtf(fmaxf(var, 0.f) + 1e-5f);
                if (row < M){
                    #pragma unroll
                    for (int ni = 0; ni < 8; ni++){
                        int cc = bn + ni * 16 + l15;
                        float v = acc[mf][ni][j] + bv[ni];
                        v = (v - mean) * rsq * lgv[ni] + lbv[ni];
                        if (ACT == 3) v = gelu_f(v);
                        C[(size_t)row * ldc + cc] = v;
                    }
                }
            }
        } else {
            #pragma unroll
            for (int ni = 0; ni < 8; ni++){
                int cc = bn + ni * 16 + l15;
                if (cc >= N) continue;
                #pragma unroll
                for (int j = 0; j < 4; j++){
                    int row = bm_w + mf * 16 + g * 4 + j;
                    if (row >= M) continue;
                    float v = acc[mf][ni][j] + bv[ni];
                    if (ACT == 1) v = gelu_f(v);
                    C[(size_t)row * ldc + cc] = v;
                }
            }
        }
    }
}

// ---------------- fused classifier tail: out = (gelu(A@W2+b2))@W3 + b3 -------------
__global__ __launch_bounds__(256) void cls_tail(const float* __restrict__ A,
                                                const float* __restrict__ W2,
                                                const float* __restrict__ b2,
                                                const float* __restrict__ W3,
                                                const float* __restrict__ b3,
                                                float* __restrict__ out,
                                                int M, int NYB){
    const int SA = 40;
    __shared__ __align__(16) unsigned short Ah[64 * SA], Al[64 * SA];
    __shared__ __align__(16) unsigned short Bh[64 * SA], Bl[64 * SA];
    __shared__ __align__(16) unsigned short A2h[64 * 72], A2l[64 * 72];
    __shared__ __align__(16) unsigned short B3h[32 * 72], B3l[32 * 72];
    int bx, by;
    if (!gemm_decode(blockIdx.x, 1, NYB, bx, by)) return;
    int tid = threadIdx.x;
    int lane = tid & 63, wid = tid >> 6;
    int wy = wid >> 1, wx = wid & 1;
    int bm = by * 64;
    int l15 = lane & 15, g = lane >> 4;

    for (int e = tid; e < 2048; e += 256){
        int n = e >> 6, k = e & 63;
        float v = (n < 17) ? W3[(size_t)k * 17 + n] : 0.f;
        unsigned short hs, ls;
        bf16_split(v, hs, ls);
        B3h[n * 72 + k] = hs;
        B3l[n * 72 + k] = ls;
    }

    fv4 acc[2][2];
    #pragma unroll
    for (int mi = 0; mi < 2; mi++)
        #pragma unroll
        for (int ni = 0; ni < 2; ni++) acc[mi][ni] = (fv4){0.f,0.f,0.f,0.f};

    int bn_t = tid & 63;
    int bk8 = (tid >> 6) * 8;
    #pragma unroll
    for (int ks = 0; ks < 4; ks++){
        int k0 = ks * 32;
        #pragma unroll
        for (int f = 0; f < 2; f++){
            int idx = tid * 2 + f;
            int row = idx >> 3, qd = idx & 7;
            fv4 v = (fv4){0.f,0.f,0.f,0.f};
            if ((bm + row) < M)
                v = *reinterpret_cast<const fv4*>(A + (size_t)(bm + row) * 128 + k0 + qd * 4);
            unsigned short hs[4], ls[4];
            #pragma unroll
            for (int j = 0; j < 4; j++) bf16_split(v[j], hs[j], ls[j]);
            unsigned off = row * SA + qd * 4;
            *reinterpret_cast<uint2*>(&Ah[off]) = make_uint2(pack2(hs[0],hs[1]), pack2(hs[2],hs[3]));
            *reinterpret_cast<uint2*>(&Al[off]) = make_uint2(pack2(ls[0],ls[1]), pack2(ls[2],ls[3]));
        }
        {
            unsigned short hs[8], ls[8];
            #pragma unroll
            for (int j = 0; j < 8; j++){
                int kk = k0 + bk8 + j;
                float v = W2[(size_t)kk * 64 + bn_t];
                bf16_split(v, hs[j], ls[j]);
            }
            unsigned off = bn_t * SA + bk8;
            *reinterpret_cast<uint4*>(&Bh[off]) = make_uint4(pack2(hs[0],hs[1]), pack2(hs[2],hs[3]),
                                                             pack2(hs[4],hs[5]), pack2(hs[6],hs[7]));
            *reinterpret_cast<uint4*>(&Bl[off]) = make_uint4(pack2(ls[0],ls[1]), pack2(ls[2],ls[3]),
                                                             pack2(ls[4],ls[5]), pack2(ls[6],ls[7]));
        }
        __syncthreads();
        short8 afh[2], afl[2], bfh[2], bfl[2];
        #pragma unroll
        for (int mi = 0; mi < 2; mi++){
            unsigned off = (wy * 32 + mi * 16 + l15) * SA + g * 8;
            afh[mi] = *reinterpret_cast<const short8*>(&Ah[off]);
            afl[mi] = *reinterpret_cast<const short8*>(&Al[off]);
        }
        #pragma unroll
        for (int ni = 0; ni < 2; ni++){
            unsigned off = (wx * 32 + ni * 16 + l15) * SA + g * 8;
            bfh[ni] = *reinterpret_cast<const short8*>(&Bh[off]);
            bfl[ni] = *reinterpret_cast<const short8*>(&Bl[off]);
        }
        #pragma unroll
        for (int mi = 0; mi < 2; mi++)
            #pragma unroll
            for (int ni = 0; ni < 2; ni++){
                acc[mi][ni] = __builtin_amdgcn_mfma_f32_16x16x32_bf16(afh[mi], bfh[ni], acc[mi][ni], 0, 0, 0);
                acc[mi][ni] = __builtin_amdgcn_mfma_f32_16x16x32_bf16(afh[mi], bfl[ni], acc[mi][ni], 0, 0, 0);
                acc[mi][ni] = __builtin_amdgcn_mfma_f32_16x16x32_bf16(afl[mi], bfh[ni], acc[mi][ni], 0, 0, 0);
            }
        __syncthreads();
    }
    #pragma unroll
    for (int mi = 0; mi < 2; mi++)
        #pragma unroll
        for (int ni = 0; ni < 2; ni++){
            int col = wx * 32 + ni * 16 + l15;
            float bv = b2[col];
            #pragma unroll
            for (int j = 0; j < 4; j++){
                int row = wy * 32 + mi * 16 + g * 4 + j;
                float v = gelu_f(acc[mi][ni][j] + bv);
                unsigned short hs, ls;
                bf16_split(v, hs, ls);
                A2h[row * 72 + col] = hs;
                A2l[row * 72 + col] = ls;
            }
        }
    __syncthreads();
    fv4 acc3[2];
    acc3[0] = (fv4){0.f,0.f,0.f,0.f};
    acc3[1] = (fv4){0.f,0.f,0.f,0.f};
    #pragma unroll
    for (int ks = 0; ks < 2; ks++){
        unsigned aoff = (wid * 16 + l15) * 72 + ks * 32 + g * 8;
        short8 a2h = *reinterpret_cast<const short8*>(&A2h[aoff]);
        short8 a2l = *reinterpret_cast<const short8*>(&A2l[aoff]);
        #pragma unroll
        for (int ni = 0; ni < 2; ni++){
            unsigned boff = (ni * 16 + l15) * 72 + ks * 32 + g * 8;
            short8 b3h_ = *reinterpret_cast<const short8*>(&B3h[boff]);
            short8 b3l_ = *reinterpret_cast<const short8*>(&B3l[boff]);
            acc3[ni] = __builtin_amdgcn_mfma_f32_16x16x32_bf16(a2h, b3h_, acc3[ni], 0, 0, 0);
            acc3[ni] = __builtin_amdgcn_mfma_f32_16x16x32_bf16(a2h, b3l_, acc3[ni], 0, 0, 0);
            acc3[ni] = __builtin_amdgcn_mfma_f32_16x16x32_bf16(a2l, b3h_, acc3[ni], 0, 0, 0);
        }
    }
    #pragma unroll
    for (int ni = 0; ni < 2; ni++){
        int col = ni * 16 + l15;
        if (col >= 17) continue;
        float bv = b3[col];
        #pragma unroll
        for (int j = 0; j < 4; j++){
            int row = bm + wid * 16 + g * 4 + j;
            if (row >= M) continue;
            out[(size_t)row * 17 + col] = acc3[ni][j] + bv;
        }
    }
}

// ---------------- dt from p ----------------
__global__ __launch_bounds__(256) void dt_from_p(const float* __restrict__ p,
                                                 const float* __restrict__ w,
                                                 const float* __restrict__ dtb,
                                                 float* __restrict__ dtbT){
    __shared__ float wl[512];
    int tid = threadIdx.x;
    for (int i = tid; i < 512; i += 256){
        int k = i >> 2, h = i & 3;
        wl[i] = w[(size_t)k * 772 + 768 + h];
    }
    __syncthreads();
    int t = blockIdx.x * 64 + (tid >> 2);
    int h = tid & 3;
    if (t >= HW) return;
    const float* pr = p + (size_t)t * 128;
    float s = 0.f;
    for (int k = 0; k < 128; k += 4){
        fv4 v = *reinterpret_cast<const fv4*>(pr + k);
        s += v[0]*wl[k*4+h] + v[1]*wl[(k+1)*4+h] + v[2]*wl[(k+2)*4+h] + v[3]*wl[(k+3)*4+h];
    }
    s += dtb[h];
    dtbT[h * DTP + t] = (s > 20.f) ? s : log1pf(expf(s));
}

// ---------------- conv weight prepack ----------------
template<int IC, int OC, int NCHUNK>
__global__ void prep_w(const float* __restrict__ w, unsigned short* __restrict__ Wh,
                       unsigned short* __restrict__ Wl){
    const int KP = NCHUNK * 288;
    int idx = blockIdx.x * 256 + threadIdx.x;
    if (idx >= OC * KP) return;
    int o = idx / KP, k = idx % KP;
    int ch = k / 288, rest = k % 288, t = rest / 32, c = rest & 31;
    int ci = ch * 32 + c;
    float v = (ci < IC) ? w[((size_t)o * IC + ci) * 9 + t] : 0.f;
    unsigned short hs, ls;
    bf16_split(v, hs, ls);
    Wh[idx] = hs; Wl[idx] = ls;
}

// ---------------- MFMA direct conv 3x3 ----------------
template<int IC, int OC, int PAD, int NCHUNK, int NFRAG>
__global__ __launch_bounds__(256) void conv_mfma(const float* __restrict__ in,
                                                 int inH, int inW,
                                                 const unsigned short* __restrict__ Wh,
                                                 const unsigned short* __restrict__ Wl,
                                                 const float* __restrict__ bias,
                                                 float* __restrict__ out){
    const int KP = NCHUNK * 288;
    const int CST = 40;
    __shared__ __align__(16) unsigned short Xh[3 * 68 * CST], Xl[3 * 68 * CST];
    int y = blockIdx.y;
    int x0 = blockIdx.x * 64;
    int tid = threadIdx.x;
    int lane = tid & 63, wid = tid >> 6;
    int wy = wid >> 1, wx = wid & 1;
    int l15 = lane & 15, g = lane >> 4;

    fv4 acc[2][NFRAG];
    #pragma unroll
    for (int mi = 0; mi < 2; mi++)
        #pragma unroll
        for (int ni = 0; ni < NFRAG; ni++) acc[mi][ni] = (fv4){0.f,0.f,0.f,0.f};

    for (int ch = 0; ch < NCHUNK; ch++){
        int ci0 = ch * 32;
        if (ch > 0) __syncthreads();
        for (int e = tid; e < 3 * 68 * 8; e += 256){
            int qd = e & 7;
            int c  = (e >> 3) % 68;
            int r  = e / 544;
            int iy = y - PAD + r, ix = x0 - PAD + c;
            fv4 v = (fv4){0.f,0.f,0.f,0.f};
            if ((unsigned)iy < (unsigned)inH && (unsigned)ix < (unsigned)inW &&
                (ci0 + qd * 4 + 4) <= IC)
                v = *reinterpret_cast<const fv4*>(in + ((size_t)iy * inW + ix) * IC + ci0 + qd * 4);
            unsigned short hs[4], ls[4];
            #pragma unroll
            for (int j = 0; j < 4; j++) bf16_split(v[j], hs[j], ls[j]);
            unsigned off = (r * 68 + c) * CST + qd * 4;
            *reinterpret_cast<uint2*>(&Xh[off]) = make_uint2(pack2(hs[0],hs[1]), pack2(hs[2],hs[3]));
            *reinterpret_cast<uint2*>(&Xl[off]) = make_uint2(pack2(ls[0],ls[1]), pack2(ls[2],ls[3]));
        }
        __syncthreads();
        #pragma unroll
        for (int t = 0; t < 9; t++){
            int ky = t / 3, kx = t % 3;
            short8 ah[2], al[2], bh[NFRAG], bl[NFRAG];
            #pragma unroll
            for (int mi = 0; mi < 2; mi++){
                unsigned off = (ky * 68 + wy * 32 + mi * 16 + l15 + kx) * CST + g * 8;
                ah[mi] = *reinterpret_cast<const short8*>(&Xh[off]);
                al[mi] = *reinterpret_cast<const short8*>(&Xl[off]);
            }
            #pragma unroll
            for (int ni = 0; ni < NFRAG; ni++){
                int oc = wx * (16 * NFRAG) + ni * 16 + l15;
                size_t woff = (size_t)oc * KP + ch * 288 + t * 32 + g * 8;
                bh[ni] = *reinterpret_cast<const short8*>(&Wh[woff]);
                bl[ni] = *reinterpret_cast<const short8*>(&Wl[woff]);
            }
            #pragma unroll
            for (int mi = 0; mi < 2; mi++)
                #pragma unroll
                for (int ni = 0; ni < NFRAG; ni++){
                    acc[mi][ni] = __builtin_amdgcn_mfma_f32_16x16x32_bf16(ah[mi], bh[ni], acc[mi][ni], 0, 0, 0);
                    acc[mi][ni] = __builtin_amdgcn_mfma_f32_16x16x32_bf16(ah[mi], bl[ni], acc[mi][ni], 0, 0, 0);
                    acc[mi][ni] = __builtin_amdgcn_mfma_f32_16x16x32_bf16(al[mi], bh[ni], acc[mi][ni], 0, 0, 0);
                }
        }
    }
    #pragma unroll
    for (int mi = 0; mi < 2; mi++)
        #pragma unroll
        for (int ni = 0; ni < NFRAG; ni++){
            int oc = wx * (16 * NFRAG) + ni * 16 + l15;
            float bv = bias[oc];
            #pragma unroll
            for (int j = 0; j < 4; j++){
                int x = x0 + wy * 32 + mi * 16 + g * 4 + j;
                if (x >= CONVH) continue;
                out[((size_t)y * CONVH + x) * OC + oc] = gelu_f(acc[mi][ni][j] + bv);
            }
        }
}

// ---------------- adaptive pool ----------------
__global__ void pool_kernel(const float* __restrict__ c2, float* __restrict__ comb){
    int idx = blockIdx.x * 256 + threadIdx.x;
    if (idx >= HW * 64) return;
    int o = idx & 63;
    int pix = idx >> 6;
    int xo = pix % Wdim, yo = pix / Wdim;
    int ys = yo * CONVH / Hdim, ye = ((yo + 1) * CONVH + Hdim - 1) / Hdim;
    int xs = xo * CONVH / Wdim, xe = ((xo + 1) * CONVH + Wdim - 1) / Wdim;
    float s = 0.f;
    for (int yy = ys; yy < ye; yy++)
        for (int xx = xs; xx < xe; xx++)
            s += c2[((size_t)yy * CONVH + xx) * 64 + o];
    comb[(size_t)pix * 192 + 128 + o] = s / (float)((ye - ys) * (xe - xs));
}

// ---------------- conv1d + silu -> packed u32 ----------------
__global__ __launch_bounds__(256) void conv1d_tiled(const float* __restrict__ zx,
                                                    const float* __restrict__ w,
                                                    const float* __restrict__ b,
                                                    unsigned* __restrict__ xbcp){
    __shared__ float xs[67 * 128];
    __shared__ float wc[4 * 128];
    __shared__ float bc[128];
    int t0 = blockIdx.y * 64;
    int c0 = blockIdx.x * 128;
    int tid = threadIdx.x;
    for (int e = tid; e < 67 * 128; e += 256){
        int rr = e >> 7, cc = e & 127;
        int t = t0 - 3 + rr;
        xs[e] = (t >= 0 && t < HW) ? zx[(size_t)t * 772 + 256 + c0 + cc] : 0.f;
    }
    if (tid < 128){
        bc[tid] = b[c0 + tid];
        #pragma unroll
        for (int k = 0; k < 4; k++) wc[k * 128 + tid] = w[(c0 + tid) * 4 + k];
    }
    __syncthreads();
    for (int e = tid; e < 64 * 128; e += 256){
        int tt = e >> 7, cc = e & 127;
        if (t0 + tt >= HW) continue;
        float acc = bc[cc];
        #pragma unroll
        for (int k = 0; k < 4; k++) acc += xs[(tt + k) * 128 + cc] * wc[k * 128 + cc];
        xbcp[(size_t)(t0 + tt) * 512 + c0 + cc] = packsplit(silu_f(acc));
    }
}

// ---------------- chunk cumsum (wave 0) ----------------
__device__ __forceinline__ void chunk_cumsum_t(const float* __restrict__ dtbT, int t0, int Q,
                                               int h, const float* __restrict__ A_log,
                                               float* cum, float* dth){
    int tid = threadIdx.x;
    if (tid < 64){
        float d = (tid < Q) ? dtbT[h * DTP + t0 + tid] : 0.f;
        dth[tid] = d;
        float A = -expf(A_log[h]);
        float a = d * A;
        #pragma unroll
        for (int off = 1; off < 64; off <<= 1){
            float u = __shfl_up(a, off);
            if (tid >= off) a += u;
        }
        cum[tid] = a;
    }
    __syncthreads();
}

__device__ __forceinline__ bool ssd_decode(int bid, int& c, int& h){
    int m = bid & 7, rest = bid >> 3;
    h = rest & 3;
    c = (rest >> 2) * 8 + m;
    return c < NCH;
}

// ---------------- SSD phase A (MFMA, packed xbc in, bf16 S out) ----------------
__global__ __launch_bounds__(256) void ssd_phaseA(const unsigned* __restrict__ xbcp,
                                                  const float* __restrict__ dtbT,
                                                  const float* __restrict__ A_log,
                                                  unsigned short* __restrict__ Sb,
                                                  float* __restrict__ chunkT){
    __shared__ __align__(16) unsigned short BTh[128 * SP], BTl[128 * SP];
    __shared__ __align__(16) unsigned short XTh[64 * SP],  XTl[64 * SP];
    __shared__ float cum[64], dth[64], wln[64];
    int c, h;
    if (!ssd_decode(blockIdx.x, c, h)) return;
    int t0 = c * QC, Q = min(QC, HW - t0);
    int tid = threadIdx.x;
    chunk_cumsum_t(dtbT, t0, Q, h, A_log, cum, dth);
    float T = cum[Q - 1];
    if (tid == 0) chunkT[c * 4 + h] = T;
    if (tid < 64) wln[tid] = (tid < Q) ? __expf(T - cum[tid]) * dth[tid] : 0.f;
    __syncthreads();
    for (int e2 = tid; e2 < 4096; e2 += 256){
        int nn = e2 & 127, sp = e2 >> 7;
        int s0 = 2 * sp;
        unsigned v0 = (s0 < Q)     ? xbcp[(size_t)(t0 + s0) * 512 + 256 + nn] : 0u;
        unsigned v1 = (s0 + 1 < Q) ? xbcp[(size_t)(t0 + s0 + 1) * 512 + 256 + nn] : 0u;
        *reinterpret_cast<unsigned*>(&BTh[nn * SP + s0]) = pack2((unsigned short)(v0 >> 16), (unsigned short)(v1 >> 16));
        *reinterpret_cast<unsigned*>(&BTl[nn * SP + s0]) = pack2((unsigned short)(v0 & 0xFFFFu), (unsigned short)(v1 & 0xFFFFu));
    }
    for (int e2 = tid; e2 < 2048; e2 += 256){
        int pp = e2 & 63, sp = e2 >> 6;
        int s0 = 2 * sp;
        float v0 = (s0 < Q)     ? unpackf(xbcp[(size_t)(t0 + s0) * 512 + h * 64 + pp]) * wln[s0] : 0.f;
        float v1 = (s0 + 1 < Q) ? unpackf(xbcp[(size_t)(t0 + s0 + 1) * 512 + h * 64 + pp]) * wln[s0 + 1] : 0.f;
        unsigned short h0, l0, h1, l1;
        bf16_split(v0, h0, l0); bf16_split(v1, h1, l1);
        *reinterpret_cast<unsigned*>(&XTh[pp * SP + s0]) = pack2(h0, h1);
        *reinterpret_cast<unsigned*>(&XTl[pp * SP + s0]) = pack2(l0, l1);
    }
    __syncthreads();
    int lane = tid & 63, wid = tid >> 6;
    int wy = wid >> 1, wx = wid & 1;
    int l15 = lane & 15, g = lane >> 4;
    fv4 acc[2][4];
    #pragma unroll
    for (int mi = 0; mi < 2; mi++)
        #pragma unroll
        for (int ni = 0; ni < 4; ni++) acc[mi][ni] = (fv4){0.f,0.f,0.f,0.f};
    #pragma unroll
    for (int ks = 0; ks < 2; ks++){
        short8 ah[2], al[2], bh_[4], bl_[4];
        #pragma unroll
        for (int mi = 0; mi < 2; mi++){
            unsigned off = (wy * 32 + mi * 16 + l15) * SP + ks * 32 + g * 8;
            ah[mi] = *reinterpret_cast<const short8*>(&XTh[off]);
            al[mi] = *reinterpret_cast<const short8*>(&XTl[off]);
        }
        #pragma unroll
        for (int ni = 0; ni < 4; ni++){
            unsigned off = (wx * 64 + ni * 16 + l15) * SP + ks * 32 + g * 8;
            bh_[ni] = *reinterpret_cast<const short8*>(&BTh[off]);
            bl_[ni] = *reinterpret_cast<const short8*>(&BTl[off]);
        }
        #pragma unroll
        for (int mi = 0; mi < 2; mi++)
            #pragma unroll
            for (int ni = 0; ni < 4; ni++){
                acc[mi][ni] = __builtin_amdgcn_mfma_f32_16x16x32_bf16(ah[mi], bh_[ni], acc[mi][ni], 0, 0, 0);
                acc[mi][ni] = __builtin_amdgcn_mfma_f32_16x16x32_bf16(ah[mi], bl_[ni], acc[mi][ni], 0, 0, 0);
                acc[mi][ni] = __builtin_amdgcn_mfma_f32_16x16x32_bf16(al[mi], bh_[ni], acc[mi][ni], 0, 0, 0);
            }
    }
    size_t sb = (size_t)(c * 4 + h) * 8192;
    #pragma unroll
    for (int mi = 0; mi < 2; mi++)
        #pragma unroll
        for (int ni = 0; ni < 4; ni++)
            #pragma unroll
            for (int j = 0; j < 4; j++){
                int p = wy * 32 + mi * 16 + g * 4 + j;
                int n = wx * 64 + ni * 16 + l15;
                Sb[sb + p * 128 + n] = bf16rnd(acc[mi][ni][j]);
            }
}

// ---------------- SSD phase B: prefix over chunks (bf16 S, 512x64 grid) ------------
__global__ __launch_bounds__(64) void ssd_phaseB(unsigned short* __restrict__ Sb,
                                                 const float* __restrict__ chunkT){
    __shared__ float e[NCH];
    int tid = threadIdx.x;
    int idx = blockIdx.x * 64 + tid;
    int h = idx >> 13, pn = idx & 8191;
    for (int c = tid; c < NCH; c += 64) e[c] = __expf(chunkT[c * 4 + h]);
    __syncthreads();
    #define ADDR_(cc) Sb[((size_t)((cc) * 4 + h)) * 8192 + pn]
    unsigned short r0 = ADDR_(0), r1 = ADDR_(1), r2 = ADDR_(2), r3 = ADDR_(3);
    float s = 0.f;
    int c = 0;
    for (; c + 8 <= NCH; c += 4){
        unsigned short n0 = ADDR_(c + 4), n1 = ADDR_(c + 5), n2 = ADDR_(c + 6), n3 = ADDR_(c + 7);
        ADDR_(c) = bf16rnd(s);     s = fmaf(s, e[c],     bf16f(r0));
        ADDR_(c + 1) = bf16rnd(s); s = fmaf(s, e[c + 1], bf16f(r1));
        ADDR_(c + 2) = bf16rnd(s); s = fmaf(s, e[c + 2], bf16f(r2));
        ADDR_(c + 3) = bf16rnd(s); s = fmaf(s, e[c + 3], bf16f(r3));
        r0 = n0; r1 = n1; r2 = n2; r3 = n3;
    }
    for (; c < NCH; c++){
        unsigned short nx = (c + 4 < NCH) ? ADDR_(c + 4) : (unsigned short)0;
        float loc = bf16f(r0); r0 = r1; r1 = r2; r2 = r3; r3 = nx;
        ADDR_(c) = bf16rnd(s);
        s = fmaf(s, e[c], loc);
    }
    #undef ADDR_
}

// ---------------- SSD phase C (MFMA, bf16 S direct, bf16 P, fused z-gating) --------
__global__ __launch_bounds__(256) void ssd_phaseC(const unsigned* __restrict__ xbcp,
                                                  const float* __restrict__ zx,
                                                  const float* __restrict__ dtbT,
                                                  const float* __restrict__ A_log,
                                                  const float* __restrict__ Dvec,
                                                  const unsigned short* __restrict__ Sb,
                                                  float* __restrict__ y){
    __shared__ __align__(16) unsigned short U0[64 * SP];
    __shared__ __align__(16) unsigned short U1h[64 * SP], U1l[64 * SP];
    __shared__ float cum[64], dth[64];
    int c, h;
    if (!ssd_decode(blockIdx.x, c, h)) return;
    int t0 = c * QC, Q = min(QC, HW - t0);
    int tid = threadIdx.x;
    chunk_cumsum_t(dtbT, t0, Q, h, A_log, cum, dth);
    int lane = tid & 63, wid = tid >> 6;
    int wy = wid >> 1, wx = wid & 1;
    int l15 = lane & 15, g = lane >> 4;

    int trow[2], srow[2], prow[2];
    #pragma unroll
    for (int i = 0; i < 2; i++){
        trow[i] = min(t0 + wy * 32 + i * 16 + l15, HW - 1);
        srow[i] = min(t0 + wx * 32 + i * 16 + l15, HW - 1);
        prow[i] = wx * 32 + i * 16 + l15;
    }

    fv4 accG[2][2], accA[2][2];
    #pragma unroll
    for (int mi = 0; mi < 2; mi++)
        #pragma unroll
        for (int ni = 0; ni < 2; ni++){ accG[mi][ni] = (fv4){0.f,0.f,0.f,0.f}; accA[mi][ni] = (fv4){0.f,0.f,0.f,0.f}; }

    const unsigned short* Sbase = Sb + (size_t)(c * 4 + h) * 8192;
    #pragma unroll
    for (int k0 = 0; k0 < 128; k0 += 32){
        short8 ah[2], al[2], bh[2], bl[2], sh[2];
        #pragma unroll
        for (int mi = 0; mi < 2; mi++)
            unpack8(xbcp + (size_t)trow[mi] * 512 + 384 + k0 + g * 8, ah[mi], al[mi]);
        #pragma unroll
        for (int ni = 0; ni < 2; ni++){
            unpack8(xbcp + (size_t)srow[ni] * 512 + 256 + k0 + g * 8, bh[ni], bl[ni]);
            sh[ni] = *reinterpret_cast<const short8*>(Sbase + prow[ni] * 128 + k0 + g * 8);
        }
        #pragma unroll
        for (int mi = 0; mi < 2; mi++)
            #pragma unroll
            for (int ni = 0; ni < 2; ni++){
                accG[mi][ni] = __builtin_amdgcn_mfma_f32_16x16x32_bf16(ah[mi], bh[ni], accG[mi][ni], 0, 0, 0);
                accG[mi][ni] = __builtin_amdgcn_mfma_f32_16x16x32_bf16(ah[mi], bl[ni], accG[mi][ni], 0, 0, 0);
                accG[mi][ni] = __builtin_amdgcn_mfma_f32_16x16x32_bf16(al[mi], bh[ni], accG[mi][ni], 0, 0, 0);
                accA[mi][ni] = __builtin_amdgcn_mfma_f32_16x16x32_bf16(ah[mi], sh[ni], accA[mi][ni], 0, 0, 0);
                accA[mi][ni] = __builtin_amdgcn_mfma_f32_16x16x32_bf16(al[mi], sh[ni], accA[mi][ni], 0, 0, 0);
            }
    }
    #pragma unroll
    for (int mi = 0; mi < 2; mi++)
        #pragma unroll
        for (int ni = 0; ni < 2; ni++)
            #pragma unroll
            for (int j = 0; j < 4; j++){
                int t = wy * 32 + mi * 16 + g * 4 + j;
                int s = wx * 32 + ni * 16 + l15;
                float pv = 0.f;
                if (s <= t && s < Q)
                    pv = accG[mi][ni][j] * __expf(cum[t] - cum[s]) * dth[s];
                U0[t * SP + s] = bf16rnd(pv);
            }
    for (int e2 = tid; e2 < 2048; e2 += 256){
        int pp = e2 & 63, sp = e2 >> 6;
        int s0 = 2 * sp;
        unsigned v0 = (s0 < Q)     ? xbcp[(size_t)(t0 + s0) * 512 + h * 64 + pp] : 0u;
        unsigned v1 = (s0 + 1 < Q) ? xbcp[(size_t)(t0 + s0 + 1) * 512 + h * 64 + pp] : 0u;
        *reinterpret_cast<unsigned*>(&U1h[pp * SP + s0]) = pack2((unsigned short)(v0 >> 16), (unsigned short)(v1 >> 16));
        *reinterpret_cast<unsigned*>(&U1l[pp * SP + s0]) = pack2((unsigned short)(v0 & 0xFFFFu), (unsigned short)(v1 & 0xFFFFu));
    }
    __syncthreads();
    fv4 accY[2][2];
    #pragma unroll
    for (int mi = 0; mi < 2; mi++)
        #pragma unroll
        for (int ni = 0; ni < 2; ni++)
            #pragma unroll
            for (int j = 0; j < 4; j++){
                int t = wy * 32 + mi * 16 + g * 4 + j;
                accY[mi][ni][j] = __expf(cum[t]) * accA[mi][ni][j];
            }
    #pragma unroll
    for (int kk = 0; kk < 2; kk++){
        short8 ph[2], xh[2], xl[2];
        #pragma unroll
        for (int mi = 0; mi < 2; mi++){
            unsigned off = (wy * 32 + mi * 16 + l15) * SP + kk * 32 + g * 8;
            ph[mi] = *reinterpret_cast<const short8*>(&U0[off]);
        }
        #pragma unroll
        for (int ni = 0; ni < 2; ni++){
            unsigned off = (wx * 32 + ni * 16 + l15) * SP + kk * 32 + g * 8;
            xh[ni] = *reinterpret_cast<const short8*>(&U1h[off]);
            xl[ni] = *reinterpret_cast<const short8*>(&U1l[off]);
        }
        #pragma unroll
        for (int mi = 0; mi < 2; mi++)
            #pragma unroll
            for (int ni = 0; ni < 2; ni++){
                accY[mi][ni] = __builtin_amdgcn_mfma_f32_16x16x32_bf16(ph[mi], xh[ni], accY[mi][ni], 0, 0, 0);
                accY[mi][ni] = __builtin_amdgcn_mfma_f32_16x16x32_bf16(ph[mi], xl[ni], accY[mi][ni], 0, 0, 0);
            }
    }
    float Dh = Dvec[h];
    #pragma unroll
    for (int mi = 0; mi < 2; mi++)
        #pragma unroll
        for (int ni = 0; ni < 2; ni++)
            #pragma unroll
            for (int j = 0; j < 4; j++){
                int t = wy * 32 + mi * 16 + g * 4 + j;
                if (t >= Q) continue;
                int p = wx * 32 + ni * 16 + l15;
                float xv = unpackf(xbcp[(size_t)(t0 + t) * 512 + h * 64 + p]);
                float zv = zx[(size_t)(t0 + t) * 772 + h * 64 + p];
                y[(size_t)(t0 + t) * 256 + h * 64 + p] = (accY[mi][ni][j] + Dh * xv) * silu_f(zv);
            }
}

// ---------------- RMSNorm (gating already applied in phaseC) ----------------
__global__ void rms_kernel(float* __restrict__ y, const float* __restrict__ nw){
    int row = blockIdx.x, tid = threadIdx.x;
    float v = y[(size_t)row * 256 + tid];
    float s = v * v;
    __shared__ float r1[4];
    #pragma unroll
    for (int o = 32; o > 0; o >>= 1) s += __shfl_down(s, o);
    if ((tid & 63) == 0) r1[tid >> 6] = s;
    __syncthreads();
    float S = r1[0] + r1[1] + r1[2] + r1[3];
    float rs = rsqrtf(S / 256.f + 1e-5f);
    y[(size_t)row * 256 + tid] = v * rs * nw[tid];
}

extern "C" void kernel_launch(void* const* d_in, const int* in_sizes, int n_in,
                              void* d_out, int out_size, void* d_ws, size_t ws_size,
                              hipStream_t stream){
    (void)in_sizes; (void)n_in; (void)out_size; (void)ws_size;
    const float* x        = (const float*)d_in[0];
    const float* ln_pre_g = (const float*)d_in[1];
    const float* ln_pre_b = (const float*)d_in[2];
    const float* fe_w1    = (const float*)d_in[3];
    const float* fe_b1    = (const float*)d_in[4];
    const float* fe_w2    = (const float*)d_in[5];
    const float* fe_b2    = (const float*)d_in[6];
    const float* cv_w1    = (const float*)d_in[7];
    const float* cv_b1    = (const float*)d_in[8];
    const float* cv_w2    = (const float*)d_in[9];
    const float* cv_b2    = (const float*)d_in[10];
    const float* mp_w     = (const float*)d_in[11];
    const float* mp_b     = (const float*)d_in[12];
    const float* mp_ln_g  = (const float*)d_in[13];
    const float* mp_ln_b  = (const float*)d_in[14];
    const float* m_in_w   = (const float*)d_in[15];
    const float* m_conv_w = (const float*)d_in[16];
    const float* m_conv_b = (const float*)d_in[17];
    const float* m_dtb    = (const float*)d_in[18];
    const float* m_A_log  = (const float*)d_in[19];
    const float* m_D      = (const float*)d_in[20];
    const float* m_norm_w = (const float*)d_in[21];
    const float* m_out_w  = (const float*)d_in[22];
    const float* cls_ln_g = (const float*)d_in[23];
    const float* cls_ln_b = (const float*)d_in[24];
    const float* cls_w1   = (const float*)d_in[25];
    const float* cls_b1   = (const float*)d_in[26];
    const float* cls_w2   = (const float*)d_in[27];
    const float* cls_b2   = (const float*)d_in[28];
    const float* cls_w3   = (const float*)d_in[29];
    const float* cls_b3   = (const float*)d_in[30];

    float* ws   = (float*)d_ws;
    float* xn   = ws + OFF_XN;
    float* f1   = ws + OFF_F1;
    float* comb = ws + OFF_COMB;
    float* p    = ws + OFF_P;
    float* zx   = ws + OFF_ZX;
    unsigned* xbcp = (unsigned*)(ws + OFF_XBC);
    unsigned short* Sb = (unsigned short*)(ws + OFF_S);
    float* dtbT = ws + OFF_DT;
    float* chkT = ws + OFF_CT;
    float* c1h  = ws + OFF_XBC;                    // before xbcp live
    float* c2h  = ws + OFF_XBC + 691488;
    float* ybuf = ws + OFF_F1;
    float* cls0 = ws + OFF_XN;
    float* cls1 = ws + OFF_P;
    unsigned short* W1h = (unsigned short*)(ws + OFF_W);
    unsigned short* W1l = (unsigned short*)(ws + OFF_W + 32256);
    unsigned short* W2h = (unsigned short*)(ws + OFF_W + 64512);
    unsigned short* W2l = (unsigned short*)(ws + OFF_W + 73728);
    unsigned* Wg = (unsigned*)(ws + OFF_WG);
    const float* NUL = (const float*)nullptr;

    // 0. weight prepacks
    prep_w<200, 32, 7><<<(32 * 2016 + 255) / 256, 256, 0, stream>>>(cv_w1, W1h, W1l);
    prep_w<32, 64, 1><<<(64 * 288 + 255) / 256, 256, 0, stream>>>(cv_w2, W2h, W2l);
    prep_fc<<<WG_TOTAL / 256, 256, 0, stream>>>(fe_w1, fe_w2, mp_w, m_in_w, m_out_w, cls_w1, Wg);
    // 1. pre-LN
    ln_kernel<0><<<HW, 256, 0, stream>>>(x, ln_pre_g, ln_pre_b, xn, NBANDS);
    // 2-3. feature MLP (f -> comb[:, :128])
    gemm_direct<1, 2><<<gemm_grid(2, 165), 256, 0, stream>>>(xn, 200, Wg + WG_FE1, fe_b1,
        NUL, NUL, f1, 256, HW, 256, 200, 224, 2, 165);
    gemm_direct<1, 1><<<gemm_grid(1, 329), 256, 0, stream>>>(f1, 256, Wg + WG_FE2, fe_b2,
        NUL, NUL, comb, 192, HW, 128, 256, 256, 1, 329);
    // 4. conv1 (MFMA implicit-im2col): 200->32, pad 2
    conv_mfma<200, 32, 2, 7, 1><<<dim3(3, CONVH), 256, 0, stream>>>(xn, Hdim, Wdim, W1h, W1l, cv_b1, c1h);
    // 5. conv2 (MFMA): 32->64, pad 1
    conv_mfma<32, 64, 1, 1, 2><<<dim3(3, CONVH), 256, 0, stream>>>(c1h, CONVH, CONVH, W2h, W2l, cv_b2, c2h);
    // 6. adaptive pool -> comb[:, 128:192]
    pool_kernel<<<(HW * 64 + 255) / 256, 256, 0, stream>>>(c2h, comb);
    // 7. mid projection + fused LN + GELU -> p
    gemm_direct<3, 1><<<gemm_grid(1, 329), 256, 0, stream>>>(comb, 192, Wg + WG_MP, mp_b,
        mp_ln_g, mp_ln_b, p, 128, HW, 128, 192, 192, 1, 329);
    // 8. mamba in_proj (cols 0..768)
    gemm_direct<0, 2><<<gemm_grid(6, 165), 256, 0, stream>>>(p, 128, Wg + WG_IN, NUL,
        NUL, NUL, zx, 772, HW, 768, 128, 128, 6, 165);
    // 9. dt from p
    dt_from_p<<<(HW + 63) / 64, 256, 0, stream>>>(p, m_in_w, m_dtb, dtbT);
    // 10. depthwise causal conv + silu -> packed u32
    conv1d_tiled<<<dim3(4, NCH), 256, 0, stream>>>(zx, m_conv_w, m_conv_b, xbcp);
    // 11-13. SSD chunked scan
    ssd_phaseA<<<SSD_GRID, 256, 0, stream>>>(xbcp, dtbT, m_A_log, Sb, chkT);
    ssd_phaseB<<<512, 64, 0, stream>>>(Sb, chkT);
    ssd_phaseC<<<SSD_GRID, 256, 0, stream>>>(xbcp, zx, dtbT, m_A_log, m_D, Sb, ybuf);
    // 14. RMSNorm (gating fused into phaseC)
    rms_kernel<<<HW, 256, 0, stream>>>(ybuf, m_norm_w);
    // 15. out proj + fused cls LN -> cls0
    gemm_direct<2, 1><<<gemm_grid(1, 329), 256, 0, stream>>>(ybuf, 256, Wg + WG_OUT, NUL,
        cls_ln_g, cls_ln_b, cls0, 128, HW, 128, 256, 256, 1, 329);
    // 16. cls1
    gemm_direct<1, 1><<<gemm_grid(1, 329), 256, 0, stream>>>(cls0, 128, Wg + WG_CLS1, cls_b1,
        NUL, NUL, cls1, 128, HW, 128, 128, 128, 1, 329);
    // 17. fused cls2+cls3 -> d_out
    cls_tail<<<gemm_grid(1, 329), 256, 0, stream>>>(cls1, cls_w2, cls_b2, cls_w3, cls_b3,
        (float*)d_out, HW, 329);
}

// Round 14
// 451.821 us; speedup vs baseline: 1.1821x; 1.1821x over previous
//
#include <hip/hip_runtime.h>
#include <math.h>

#define HW 21025        // 145*145
#define Hdim 145
#define Wdim 145
#define NBANDS 200
#define CONVH 147
#define CONVHW 21609    // 147*147
#define QC 64
#define NCH 329         // ceil(21025/64)
#define DTP 21056       // padded L for transposed dt
#define SP 72           // short stride for [.][64-k] MFMA tiles
#define SSD_GRID 1344   // 8 * 4 * 42 (xcd-sibling swizzled, tail-guarded)

typedef __attribute__((ext_vector_type(4))) float fv4;
typedef __attribute__((ext_vector_type(8))) short short8;

// ---------------- workspace layout (float offsets) ----------------
#define OFF_XN   ((size_t)0)           // 4,205,000  xn; later cls0
#define OFF_F1   ((size_t)4205000)     // 5,382,400  f1; later y (L x 256)
#define OFF_COMB ((size_t)9587400)     // 4,036,800  comb L x 192
#define OFF_P    ((size_t)13624200)    // 2,691,200  p; later cls1
#define OFF_ZX   ((size_t)16315400)    // 16,231,300 zxbcdt L x 772
#define OFF_XBC  ((size_t)32546700)    // 10,764,800 c1h+c2h first, then xbc packed u32
#define OFF_S    ((size_t)43311500)    // S as bf16 ushort
#define OFF_DT   ((size_t)54092172)    // 84,224 (dt transposed [4][DTP])
#define OFF_CT   ((size_t)54176396)    // 1,316
#define OFF_W    ((size_t)54177712)    // 82,944: packed conv weights (bf16 hi/lo)

__device__ __forceinline__ float gelu_f(float x){
    return 0.5f * x * (1.0f + erff(x * 0.70710678118654752440f));
}
__device__ __forceinline__ float silu_f(float x){
    return x / (1.0f + expf(-x));
}

__device__ __forceinline__ void bf16_split(float x, unsigned short& hs, unsigned short& ls){
    unsigned u = __float_as_uint(x);
    hs = (unsigned short)(u >> 16);
    float hif = __uint_as_float(u & 0xFFFF0000u);
    float lof = x - hif;
    ls = (unsigned short)(__float_as_uint(lof) >> 16);
}
__device__ __forceinline__ unsigned pack2(unsigned short a, unsigned short b){
    return (unsigned)a | ((unsigned)b << 16);
}
__device__ __forceinline__ unsigned packsplit(float x){
    unsigned short hs, ls;
    bf16_split(x, hs, ls);
    return ((unsigned)hs << 16) | (unsigned)ls;
}
__device__ __forceinline__ float unpackf(unsigned u){
    return __uint_as_float(u & 0xFFFF0000u) + __uint_as_float(u << 16);
}
__device__ __forceinline__ unsigned short bf16rnd(float x){
    unsigned u = __float_as_uint(x);
    unsigned r = u + 0x7FFFu + ((u >> 16) & 1u);
    return (unsigned short)(r >> 16);
}
__device__ __forceinline__ float bf16f(unsigned short h){
    return __uint_as_float((unsigned)h << 16);
}
__device__ __forceinline__ void unpack8(const unsigned* p, short8& h8, short8& l8){
    uint4 a = *reinterpret_cast<const uint4*>(p);
    uint4 b = *reinterpret_cast<const uint4*>(p + 4);
    unsigned v0 = a.x, v1 = a.y, v2 = a.z, v3 = a.w;
    unsigned v4 = b.x, v5 = b.y, v6 = b.z, v7 = b.w;
    h8[0]=(short)(v0>>16); l8[0]=(short)(v0&0xFFFFu);
    h8[1]=(short)(v1>>16); l8[1]=(short)(v1&0xFFFFu);
    h8[2]=(short)(v2>>16); l8[2]=(short)(v2&0xFFFFu);
    h8[3]=(short)(v3>>16); l8[3]=(short)(v3&0xFFFFu);
    h8[4]=(short)(v4>>16); l8[4]=(short)(v4&0xFFFFu);
    h8[5]=(short)(v5>>16); l8[5]=(short)(v5&0xFFFFu);
    h8[6]=(short)(v6>>16); l8[6]=(short)(v6&0xFFFFu);
    h8[7]=(short)(v7>>16); l8[7]=(short)(v7&0xFFFFu);
}

// XCD-grouped decode
__device__ __forceinline__ bool gemm_decode(int bid, int NXB, int NYB, int& bx, int& by){
    int m = bid & 7;
    int r = bid >> 3;
    bx = r % NXB;
    by = (r / NXB) * 8 + m;
    return by < NYB;
}
__host__ __forceinline__ int gemm_grid(int NXB, int NYB){ return 8 * ((NYB + 7) / 8) * NXB; }

// ---------------- LayerNorm (pre-LN only) ----------------
template<int ACT>
__global__ void ln_kernel(const float* __restrict__ in, const float* __restrict__ g,
                          const float* __restrict__ b, float* __restrict__ out, int D){
    int row = blockIdx.x, tid = threadIdx.x;
    const float* r = in + (size_t)row * D;
    float s = 0.f, s2 = 0.f;
    for (int i = tid; i < D; i += 256){ float v = r[i]; s += v; s2 += v*v; }
    __shared__ float r1[4], r2[4];
    #pragma unroll
    for (int o = 32; o > 0; o >>= 1){ s += __shfl_down(s, o); s2 += __shfl_down(s2, o); }
    if ((tid & 63) == 0){ r1[tid >> 6] = s; r2[tid >> 6] = s2; }
    __syncthreads();
    float S = r1[0] + r1[1] + r1[2] + r1[3];
    float S2 = r2[0] + r2[1] + r2[2] + r2[3];
    float mean = S / (float)D;
    float var = S2 / (float)D - mean * mean;
    float rs = rsqrtf(fmaxf(var, 0.f) + 1e-5f);
    float* o_ = out + (size_t)row * D;
    for (int i = tid; i < D; i += 256){
        float v = (r[i] - mean) * rs * g[i] + b[i];
        if (ACT == 1) v = gelu_f(v);
        o_[i] = v;
    }
}

// ---------------- wide split-bf16 MFMA GEMM: BN=128, BM=MI*32 ----------------
// ACT: 0 none, 1 gelu, 2 LN, 3 LN+gelu (LN requires N==128, NXB==1)
template<int ACT, int MI>
__global__ __launch_bounds__(256) void gemm_mfma_w(const float* __restrict__ A, int lda,
                                                   const float* __restrict__ B, int ldb,
                                                   const float* __restrict__ bias,
                                                   const float* __restrict__ lng,
                                                   const float* __restrict__ lnb,
                                                   float* __restrict__ C, int ldc,
                                                   int M, int N, int K, int NXB, int NYB){
    const int SA = 40;
    const int BM = MI * 32;
    __shared__ __align__(16) unsigned short Ah[BM * SA], Al[BM * SA];
    __shared__ __align__(16) unsigned short Bh[128 * SA], Bl[128 * SA];
    __shared__ float rs1[2][BM], rs2_[2][BM];
    int bx, by;
    if (!gemm_decode(blockIdx.x, NXB, NYB, bx, by)) return;
    int tid = threadIdx.x;
    int lane = tid & 63, wid = tid >> 6;
    int wy = wid >> 1, wx = wid & 1;
    int bm = by * BM, bn = bx * 128;
    int l15 = lane & 15, g = lane >> 4;

    fv4 acc[MI][4];
    #pragma unroll
    for (int i = 0; i < MI; i++)
        #pragma unroll
        for (int j = 0; j < 4; j++) acc[i][j] = (fv4){0.f,0.f,0.f,0.f};

    int bcol = tid & 127;
    int bk16 = (tid >> 7) * 16;
    bool bcol_ok = (bn + bcol) < N;

    int nK = (K + 31) / 32;
    for (int ks = 0; ks < nK; ks++){
        int k0 = ks * 32;
        #pragma unroll
        for (int f = 0; f < MI; f++){
            int idx = tid * MI + f;
            int row = idx >> 3, qd = idx & 7;
            fv4 v = (fv4){0.f,0.f,0.f,0.f};
            if ((bm + row) < M && (k0 + qd * 4 + 4) <= K)
                v = *reinterpret_cast<const fv4*>(A + (size_t)(bm + row) * lda + k0 + qd * 4);
            unsigned short hs[4], ls[4];
            #pragma unroll
            for (int j = 0; j < 4; j++) bf16_split(v[j], hs[j], ls[j]);
            unsigned off = row * SA + qd * 4;
            *reinterpret_cast<uint2*>(&Ah[off]) = make_uint2(pack2(hs[0],hs[1]), pack2(hs[2],hs[3]));
            *reinterpret_cast<uint2*>(&Al[off]) = make_uint2(pack2(ls[0],ls[1]), pack2(ls[2],ls[3]));
        }
        {
            unsigned short hs[16], ls[16];
            #pragma unroll
            for (int j = 0; j < 16; j++){
                int kk = k0 + bk16 + j;
                float v = (bcol_ok && kk < K) ? B[(size_t)kk * ldb + bn + bcol] : 0.f;
                bf16_split(v, hs[j], ls[j]);
            }
            unsigned off = bcol * SA + bk16;
            *reinterpret_cast<uint4*>(&Bh[off]) = make_uint4(pack2(hs[0],hs[1]), pack2(hs[2],hs[3]),
                                                             pack2(hs[4],hs[5]), pack2(hs[6],hs[7]));
            *reinterpret_cast<uint4*>(&Bh[off + 8]) = make_uint4(pack2(hs[8],hs[9]), pack2(hs[10],hs[11]),
                                                                 pack2(hs[12],hs[13]), pack2(hs[14],hs[15]));
            *reinterpret_cast<uint4*>(&Bl[off]) = make_uint4(pack2(ls[0],ls[1]), pack2(ls[2],ls[3]),
                                                             pack2(ls[4],ls[5]), pack2(ls[6],ls[7]));
            *reinterpret_cast<uint4*>(&Bl[off + 8]) = make_uint4(pack2(ls[8],ls[9]), pack2(ls[10],ls[11]),
                                                                 pack2(ls[12],ls[13]), pack2(ls[14],ls[15]));
        }
        __syncthreads();
        short8 afh[MI], afl[MI], bfh[4], bfl[4];
        #pragma unroll
        for (int mi = 0; mi < MI; mi++){
            unsigned off = (wy * (MI * 16) + mi * 16 + l15) * SA + g * 8;
            afh[mi] = *reinterpret_cast<const short8*>(&Ah[off]);
            afl[mi] = *reinterpret_cast<const short8*>(&Al[off]);
        }
        #pragma unroll
        for (int ni = 0; ni < 4; ni++){
            unsigned off = (wx * 64 + ni * 16 + l15) * SA + g * 8;
            bfh[ni] = *reinterpret_cast<const short8*>(&Bh[off]);
            bfl[ni] = *reinterpret_cast<const short8*>(&Bl[off]);
        }
        #pragma unroll
        for (int mi = 0; mi < MI; mi++)
            #pragma unroll
            for (int ni = 0; ni < 4; ni++){
                acc[mi][ni] = __builtin_amdgcn_mfma_f32_16x16x32_bf16(afh[mi], bfh[ni], acc[mi][ni], 0, 0, 0);
                acc[mi][ni] = __builtin_amdgcn_mfma_f32_16x16x32_bf16(afh[mi], bfl[ni], acc[mi][ni], 0, 0, 0);
                acc[mi][ni] = __builtin_amdgcn_mfma_f32_16x16x32_bf16(afl[mi], bfh[ni], acc[mi][ni], 0, 0, 0);
            }
        __syncthreads();
    }
    float bv[4], lgv[4], lbv[4];
    #pragma unroll
    for (int ni = 0; ni < 4; ni++){
        int cc = bn + wx * 64 + ni * 16 + l15;
        bool ok = cc < N;
        bv[ni]  = (bias && ok) ? bias[cc] : 0.f;
        if (ACT >= 2){ lgv[ni] = ok ? lng[cc] : 1.f; lbv[ni] = ok ? lnb[cc] : 0.f; }
    }
    if (ACT >= 2){
        #pragma unroll
        for (int mi = 0; mi < MI; mi++)
            #pragma unroll
            for (int j = 0; j < 4; j++){
                float s = 0.f, s2 = 0.f;
                #pragma unroll
                for (int ni = 0; ni < 4; ni++){
                    float v = acc[mi][ni][j] + bv[ni];
                    s += v; s2 += v * v;
                }
                #pragma unroll
                for (int o = 1; o < 16; o <<= 1){
                    s += __shfl_xor(s, o); s2 += __shfl_xor(s2, o);
                }
                int row = wy * (MI * 16) + mi * 16 + g * 4 + j;
                if (l15 == 0){ rs1[wx][row] = s; rs2_[wx][row] = s2; }
            }
        __syncthreads();
        #pragma unroll
        for (int mi = 0; mi < MI; mi++)
            #pragma unroll
            for (int j = 0; j < 4; j++){
                int row = wy * (MI * 16) + mi * 16 + g * 4 + j;
                int rr = bm + row;
                if (rr >= M) continue;
                float S = rs1[0][row] + rs1[1][row];
                float S2 = rs2_[0][row] + rs2_[1][row];
                float mean = S / 128.f;
                float var = S2 / 128.f - mean * mean;
                float rsq = rsqrtf(fmaxf(var, 0.f) + 1e-5f);
                #pragma unroll
                for (int ni = 0; ni < 4; ni++){
                    int cc = bn + wx * 64 + ni * 16 + l15;
                    float v = acc[mi][ni][j] + bv[ni];
                    v = (v - mean) * rsq * lgv[ni] + lbv[ni];
                    if (ACT == 3) v = gelu_f(v);
                    C[(size_t)rr * ldc + cc] = v;
                }
            }
    } else {
        #pragma unroll
        for (int mi = 0; mi < MI; mi++)
            #pragma unroll
            for (int ni = 0; ni < 4; ni++){
                int cc = bn + wx * 64 + ni * 16 + l15;
                if (cc >= N) continue;
                #pragma unroll
                for (int j = 0; j < 4; j++){
                    int rr = bm + wy * (MI * 16) + mi * 16 + g * 4 + j;
                    if (rr >= M) continue;
                    float v = acc[mi][ni][j] + bv[ni];
                    if (ACT == 1) v = gelu_f(v);
                    C[(size_t)rr * ldc + cc] = v;
                }
            }
    }
}

// ---------------- fused classifier tail: out = (gelu(A@W2+b2))@W3 + b3 -------------
__global__ __launch_bounds__(256) void cls_tail(const float* __restrict__ A,
                                                const float* __restrict__ W2,
                                                const float* __restrict__ b2,
                                                const float* __restrict__ W3,
                                                const float* __restrict__ b3,
                                                float* __restrict__ out,
                                                int M, int NYB){
    const int SA = 40;
    __shared__ __align__(16) unsigned short Ah[64 * SA], Al[64 * SA];
    __shared__ __align__(16) unsigned short Bh[64 * SA], Bl[64 * SA];
    __shared__ __align__(16) unsigned short A2h[64 * 72], A2l[64 * 72];
    __shared__ __align__(16) unsigned short B3h[32 * 72], B3l[32 * 72];
    int bx, by;
    if (!gemm_decode(blockIdx.x, 1, NYB, bx, by)) return;
    int tid = threadIdx.x;
    int lane = tid & 63, wid = tid >> 6;
    int wy = wid >> 1, wx = wid & 1;
    int bm = by * 64;
    int l15 = lane & 15, g = lane >> 4;

    for (int e = tid; e < 2048; e += 256){
        int n = e >> 6, k = e & 63;
        float v = (n < 17) ? W3[(size_t)k * 17 + n] : 0.f;
        unsigned short hs, ls;
        bf16_split(v, hs, ls);
        B3h[n * 72 + k] = hs;
        B3l[n * 72 + k] = ls;
    }

    fv4 acc[2][2];
    #pragma unroll
    for (int mi = 0; mi < 2; mi++)
        #pragma unroll
        for (int ni = 0; ni < 2; ni++) acc[mi][ni] = (fv4){0.f,0.f,0.f,0.f};

    int bn_t = tid & 63;
    int bk8 = (tid >> 6) * 8;
    #pragma unroll
    for (int ks = 0; ks < 4; ks++){
        int k0 = ks * 32;
        #pragma unroll
        for (int f = 0; f < 2; f++){
            int idx = tid * 2 + f;
            int row = idx >> 3, qd = idx & 7;
            fv4 v = (fv4){0.f,0.f,0.f,0.f};
            if ((bm + row) < M)
                v = *reinterpret_cast<const fv4*>(A + (size_t)(bm + row) * 128 + k0 + qd * 4);
            unsigned short hs[4], ls[4];
            #pragma unroll
            for (int j = 0; j < 4; j++) bf16_split(v[j], hs[j], ls[j]);
            unsigned off = row * SA + qd * 4;
            *reinterpret_cast<uint2*>(&Ah[off]) = make_uint2(pack2(hs[0],hs[1]), pack2(hs[2],hs[3]));
            *reinterpret_cast<uint2*>(&Al[off]) = make_uint2(pack2(ls[0],ls[1]), pack2(ls[2],ls[3]));
        }
        {
            unsigned short hs[8], ls[8];
            #pragma unroll
            for (int j = 0; j < 8; j++){
                int kk = k0 + bk8 + j;
                float v = W2[(size_t)kk * 64 + bn_t];
                bf16_split(v, hs[j], ls[j]);
            }
            unsigned off = bn_t * SA + bk8;
            *reinterpret_cast<uint4*>(&Bh[off]) = make_uint4(pack2(hs[0],hs[1]), pack2(hs[2],hs[3]),
                                                             pack2(hs[4],hs[5]), pack2(hs[6],hs[7]));
            *reinterpret_cast<uint4*>(&Bl[off]) = make_uint4(pack2(ls[0],ls[1]), pack2(ls[2],ls[3]),
                                                             pack2(ls[4],ls[5]), pack2(ls[6],ls[7]));
        }
        __syncthreads();
        short8 afh[2], afl[2], bfh[2], bfl[2];
        #pragma unroll
        for (int mi = 0; mi < 2; mi++){
            unsigned off = (wy * 32 + mi * 16 + l15) * SA + g * 8;
            afh[mi] = *reinterpret_cast<const short8*>(&Ah[off]);
            afl[mi] = *reinterpret_cast<const short8*>(&Al[off]);
        }
        #pragma unroll
        for (int ni = 0; ni < 2; ni++){
            unsigned off = (wx * 32 + ni * 16 + l15) * SA + g * 8;
            bfh[ni] = *reinterpret_cast<const short8*>(&Bh[off]);
            bfl[ni] = *reinterpret_cast<const short8*>(&Bl[off]);
        }
        #pragma unroll
        for (int mi = 0; mi < 2; mi++)
            #pragma unroll
            for (int ni = 0; ni < 2; ni++){
                acc[mi][ni] = __builtin_amdgcn_mfma_f32_16x16x32_bf16(afh[mi], bfh[ni], acc[mi][ni], 0, 0, 0);
                acc[mi][ni] = __builtin_amdgcn_mfma_f32_16x16x32_bf16(afh[mi], bfl[ni], acc[mi][ni], 0, 0, 0);
                acc[mi][ni] = __builtin_amdgcn_mfma_f32_16x16x32_bf16(afl[mi], bfh[ni], acc[mi][ni], 0, 0, 0);
            }
        __syncthreads();
    }
    #pragma unroll
    for (int mi = 0; mi < 2; mi++)
        #pragma unroll
        for (int ni = 0; ni < 2; ni++){
            int col = wx * 32 + ni * 16 + l15;
            float bv = b2[col];
            #pragma unroll
            for (int j = 0; j < 4; j++){
                int row = wy * 32 + mi * 16 + g * 4 + j;
                float v = gelu_f(acc[mi][ni][j] + bv);
                unsigned short hs, ls;
                bf16_split(v, hs, ls);
                A2h[row * 72 + col] = hs;
                A2l[row * 72 + col] = ls;
            }
        }
    __syncthreads();
    fv4 acc3[2];
    acc3[0] = (fv4){0.f,0.f,0.f,0.f};
    acc3[1] = (fv4){0.f,0.f,0.f,0.f};
    #pragma unroll
    for (int ks = 0; ks < 2; ks++){
        unsigned aoff = (wid * 16 + l15) * 72 + ks * 32 + g * 8;
        short8 a2h = *reinterpret_cast<const short8*>(&A2h[aoff]);
        short8 a2l = *reinterpret_cast<const short8*>(&A2l[aoff]);
        #pragma unroll
        for (int ni = 0; ni < 2; ni++){
            unsigned boff = (ni * 16 + l15) * 72 + ks * 32 + g * 8;
            short8 b3h_ = *reinterpret_cast<const short8*>(&B3h[boff]);
            short8 b3l_ = *reinterpret_cast<const short8*>(&B3l[boff]);
            acc3[ni] = __builtin_amdgcn_mfma_f32_16x16x32_bf16(a2h, b3h_, acc3[ni], 0, 0, 0);
            acc3[ni] = __builtin_amdgcn_mfma_f32_16x16x32_bf16(a2h, b3l_, acc3[ni], 0, 0, 0);
            acc3[ni] = __builtin_amdgcn_mfma_f32_16x16x32_bf16(a2l, b3h_, acc3[ni], 0, 0, 0);
        }
    }
    #pragma unroll
    for (int ni = 0; ni < 2; ni++){
        int col = ni * 16 + l15;
        if (col >= 17) continue;
        float bv = b3[col];
        #pragma unroll
        for (int j = 0; j < 4; j++){
            int row = bm + wid * 16 + g * 4 + j;
            if (row >= M) continue;
            out[(size_t)row * 17 + col] = acc3[ni][j] + bv;
        }
    }
}

// ---------------- dt from p ----------------
__global__ __launch_bounds__(256) void dt_from_p(const float* __restrict__ p,
                                                 const float* __restrict__ w,
                                                 const float* __restrict__ dtb,
                                                 float* __restrict__ dtbT){
    __shared__ float wl[512];
    int tid = threadIdx.x;
    for (int i = tid; i < 512; i += 256){
        int k = i >> 2, h = i & 3;
        wl[i] = w[(size_t)k * 772 + 768 + h];
    }
    __syncthreads();
    int t = blockIdx.x * 64 + (tid >> 2);
    int h = tid & 3;
    if (t >= HW) return;
    const float* pr = p + (size_t)t * 128;
    float s = 0.f;
    for (int k = 0; k < 128; k += 4){
        fv4 v = *reinterpret_cast<const fv4*>(pr + k);
        s += v[0]*wl[k*4+h] + v[1]*wl[(k+1)*4+h] + v[2]*wl[(k+2)*4+h] + v[3]*wl[(k+3)*4+h];
    }
    s += dtb[h];
    dtbT[h * DTP + t] = (s > 20.f) ? s : log1pf(expf(s));
}

// ---------------- conv weight prepack ----------------
template<int IC, int OC, int NCHUNK>
__global__ void prep_w(const float* __restrict__ w, unsigned short* __restrict__ Wh,
                       unsigned short* __restrict__ Wl){
    const int KP = NCHUNK * 288;
    int idx = blockIdx.x * 256 + threadIdx.x;
    if (idx >= OC * KP) return;
    int o = idx / KP, k = idx % KP;
    int ch = k / 288, rest = k % 288, t = rest / 32, c = rest & 31;
    int ci = ch * 32 + c;
    float v = (ci < IC) ? w[((size_t)o * IC + ci) * 9 + t] : 0.f;
    unsigned short hs, ls;
    bf16_split(v, hs, ls);
    Wh[idx] = hs; Wl[idx] = ls;
}

// ---------------- MFMA direct conv 3x3 ----------------
template<int IC, int OC, int PAD, int NCHUNK, int NFRAG>
__global__ __launch_bounds__(256) void conv_mfma(const float* __restrict__ in,
                                                 int inH, int inW,
                                                 const unsigned short* __restrict__ Wh,
                                                 const unsigned short* __restrict__ Wl,
                                                 const float* __restrict__ bias,
                                                 float* __restrict__ out){
    const int KP = NCHUNK * 288;
    const int CST = 40;
    __shared__ __align__(16) unsigned short Xh[3 * 68 * CST], Xl[3 * 68 * CST];
    int y = blockIdx.y;
    int x0 = blockIdx.x * 64;
    int tid = threadIdx.x;
    int lane = tid & 63, wid = tid >> 6;
    int wy = wid >> 1, wx = wid & 1;
    int l15 = lane & 15, g = lane >> 4;

    fv4 acc[2][NFRAG];
    #pragma unroll
    for (int mi = 0; mi < 2; mi++)
        #pragma unroll
        for (int ni = 0; ni < NFRAG; ni++) acc[mi][ni] = (fv4){0.f,0.f,0.f,0.f};

    for (int ch = 0; ch < NCHUNK; ch++){
        int ci0 = ch * 32;
        if (ch > 0) __syncthreads();
        for (int e = tid; e < 3 * 68 * 8; e += 256){
            int qd = e & 7;
            int c  = (e >> 3) % 68;
            int r  = e / 544;
            int iy = y - PAD + r, ix = x0 - PAD + c;
            fv4 v = (fv4){0.f,0.f,0.f,0.f};
            if ((unsigned)iy < (unsigned)inH && (unsigned)ix < (unsigned)inW &&
                (ci0 + qd * 4 + 4) <= IC)
                v = *reinterpret_cast<const fv4*>(in + ((size_t)iy * inW + ix) * IC + ci0 + qd * 4);
            unsigned short hs[4], ls[4];
            #pragma unroll
            for (int j = 0; j < 4; j++) bf16_split(v[j], hs[j], ls[j]);
            unsigned off = (r * 68 + c) * CST + qd * 4;
            *reinterpret_cast<uint2*>(&Xh[off]) = make_uint2(pack2(hs[0],hs[1]), pack2(hs[2],hs[3]));
            *reinterpret_cast<uint2*>(&Xl[off]) = make_uint2(pack2(ls[0],ls[1]), pack2(ls[2],ls[3]));
        }
        __syncthreads();
        #pragma unroll
        for (int t = 0; t < 9; t++){
            int ky = t / 3, kx = t % 3;
            short8 ah[2], al[2], bh[NFRAG], bl[NFRAG];
            #pragma unroll
            for (int mi = 0; mi < 2; mi++){
                unsigned off = (ky * 68 + wy * 32 + mi * 16 + l15 + kx) * CST + g * 8;
                ah[mi] = *reinterpret_cast<const short8*>(&Xh[off]);
                al[mi] = *reinterpret_cast<const short8*>(&Xl[off]);
            }
            #pragma unroll
            for (int ni = 0; ni < NFRAG; ni++){
                int oc = wx * (16 * NFRAG) + ni * 16 + l15;
                size_t woff = (size_t)oc * KP + ch * 288 + t * 32 + g * 8;
                bh[ni] = *reinterpret_cast<const short8*>(&Wh[woff]);
                bl[ni] = *reinterpret_cast<const short8*>(&Wl[woff]);
            }
            #pragma unroll
            for (int mi = 0; mi < 2; mi++)
                #pragma unroll
                for (int ni = 0; ni < NFRAG; ni++){
                    acc[mi][ni] = __builtin_amdgcn_mfma_f32_16x16x32_bf16(ah[mi], bh[ni], acc[mi][ni], 0, 0, 0);
                    acc[mi][ni] = __builtin_amdgcn_mfma_f32_16x16x32_bf16(ah[mi], bl[ni], acc[mi][ni], 0, 0, 0);
                    acc[mi][ni] = __builtin_amdgcn_mfma_f32_16x16x32_bf16(al[mi], bh[ni], acc[mi][ni], 0, 0, 0);
                }
        }
    }
    #pragma unroll
    for (int mi = 0; mi < 2; mi++)
        #pragma unroll
        for (int ni = 0; ni < NFRAG; ni++){
            int oc = wx * (16 * NFRAG) + ni * 16 + l15;
            float bv = bias[oc];
            #pragma unroll
            for (int j = 0; j < 4; j++){
                int x = x0 + wy * 32 + mi * 16 + g * 4 + j;
                if (x >= CONVH) continue;
                out[((size_t)y * CONVH + x) * OC + oc] = gelu_f(acc[mi][ni][j] + bv);
            }
        }
}

// ---------------- adaptive pool ----------------
__global__ void pool_kernel(const float* __restrict__ c2, float* __restrict__ comb){
    int idx = blockIdx.x * 256 + threadIdx.x;
    if (idx >= HW * 64) return;
    int o = idx & 63;
    int pix = idx >> 6;
    int xo = pix % Wdim, yo = pix / Wdim;
    int ys = yo * CONVH / Hdim, ye = ((yo + 1) * CONVH + Hdim - 1) / Hdim;
    int xs = xo * CONVH / Wdim, xe = ((xo + 1) * CONVH + Wdim - 1) / Wdim;
    float s = 0.f;
    for (int yy = ys; yy < ye; yy++)
        for (int xx = xs; xx < xe; xx++)
            s += c2[((size_t)yy * CONVH + xx) * 64 + o];
    comb[(size_t)pix * 192 + 128 + o] = s / (float)((ye - ys) * (xe - xs));
}

// ---------------- conv1d + silu -> packed u32 ----------------
__global__ __launch_bounds__(256) void conv1d_tiled(const float* __restrict__ zx,
                                                    const float* __restrict__ w,
                                                    const float* __restrict__ b,
                                                    unsigned* __restrict__ xbcp){
    __shared__ float xs[67 * 128];
    __shared__ float wc[4 * 128];
    __shared__ float bc[128];
    int t0 = blockIdx.y * 64;
    int c0 = blockIdx.x * 128;
    int tid = threadIdx.x;
    for (int e = tid; e < 67 * 128; e += 256){
        int rr = e >> 7, cc = e & 127;
        int t = t0 - 3 + rr;
        xs[e] = (t >= 0 && t < HW) ? zx[(size_t)t * 772 + 256 + c0 + cc] : 0.f;
    }
    if (tid < 128){
        bc[tid] = b[c0 + tid];
        #pragma unroll
        for (int k = 0; k < 4; k++) wc[k * 128 + tid] = w[(c0 + tid) * 4 + k];
    }
    __syncthreads();
    for (int e = tid; e < 64 * 128; e += 256){
        int tt = e >> 7, cc = e & 127;
        if (t0 + tt >= HW) continue;
        float acc = bc[cc];
        #pragma unroll
        for (int k = 0; k < 4; k++) acc += xs[(tt + k) * 128 + cc] * wc[k * 128 + cc];
        xbcp[(size_t)(t0 + tt) * 512 + c0 + cc] = packsplit(silu_f(acc));
    }
}

// ---------------- chunk cumsum (wave 0) ----------------
__device__ __forceinline__ void chunk_cumsum_t(const float* __restrict__ dtbT, int t0, int Q,
                                               int h, const float* __restrict__ A_log,
                                               float* cum, float* dth){
    int tid = threadIdx.x;
    if (tid < 64){
        float d = (tid < Q) ? dtbT[h * DTP + t0 + tid] : 0.f;
        dth[tid] = d;
        float A = -expf(A_log[h]);
        float a = d * A;
        #pragma unroll
        for (int off = 1; off < 64; off <<= 1){
            float u = __shfl_up(a, off);
            if (tid >= off) a += u;
        }
        cum[tid] = a;
    }
    __syncthreads();
}

__device__ __forceinline__ bool ssd_decode(int bid, int& c, int& h){
    int m = bid & 7, rest = bid >> 3;
    h = rest & 3;
    c = (rest >> 2) * 8 + m;
    return c < NCH;
}

// ---------------- SSD phase A (MFMA, packed xbc in, bf16 S out) ----------------
__global__ __launch_bounds__(256) void ssd_phaseA(const unsigned* __restrict__ xbcp,
                                                  const float* __restrict__ dtbT,
                                                  const float* __restrict__ A_log,
                                                  unsigned short* __restrict__ Sb,
                                                  float* __restrict__ chunkT){
    __shared__ __align__(16) unsigned short BTh[128 * SP], BTl[128 * SP];
    __shared__ __align__(16) unsigned short XTh[64 * SP],  XTl[64 * SP];
    __shared__ float cum[64], dth[64], wln[64];
    int c, h;
    if (!ssd_decode(blockIdx.x, c, h)) return;
    int t0 = c * QC, Q = min(QC, HW - t0);
    int tid = threadIdx.x;
    chunk_cumsum_t(dtbT, t0, Q, h, A_log, cum, dth);
    float T = cum[Q - 1];
    if (tid == 0) chunkT[c * 4 + h] = T;
    if (tid < 64) wln[tid] = (tid < Q) ? __expf(T - cum[tid]) * dth[tid] : 0.f;
    __syncthreads();
    for (int e2 = tid; e2 < 4096; e2 += 256){
        int nn = e2 & 127, sp = e2 >> 7;
        int s0 = 2 * sp;
        unsigned v0 = (s0 < Q)     ? xbcp[(size_t)(t0 + s0) * 512 + 256 + nn] : 0u;
        unsigned v1 = (s0 + 1 < Q) ? xbcp[(size_t)(t0 + s0 + 1) * 512 + 256 + nn] : 0u;
        *reinterpret_cast<unsigned*>(&BTh[nn * SP + s0]) = pack2((unsigned short)(v0 >> 16), (unsigned short)(v1 >> 16));
        *reinterpret_cast<unsigned*>(&BTl[nn * SP + s0]) = pack2((unsigned short)(v0 & 0xFFFFu), (unsigned short)(v1 & 0xFFFFu));
    }
    for (int e2 = tid; e2 < 2048; e2 += 256){
        int pp = e2 & 63, sp = e2 >> 6;
        int s0 = 2 * sp;
        float v0 = (s0 < Q)     ? unpackf(xbcp[(size_t)(t0 + s0) * 512 + h * 64 + pp]) * wln[s0] : 0.f;
        float v1 = (s0 + 1 < Q) ? unpackf(xbcp[(size_t)(t0 + s0 + 1) * 512 + h * 64 + pp]) * wln[s0 + 1] : 0.f;
        unsigned short h0, l0, h1, l1;
        bf16_split(v0, h0, l0); bf16_split(v1, h1, l1);
        *reinterpret_cast<unsigned*>(&XTh[pp * SP + s0]) = pack2(h0, h1);
        *reinterpret_cast<unsigned*>(&XTl[pp * SP + s0]) = pack2(l0, l1);
    }
    __syncthreads();
    int lane = tid & 63, wid = tid >> 6;
    int wy = wid >> 1, wx = wid & 1;
    int l15 = lane & 15, g = lane >> 4;
    fv4 acc[2][4];
    #pragma unroll
    for (int mi = 0; mi < 2; mi++)
        #pragma unroll
        for (int ni = 0; ni < 4; ni++) acc[mi][ni] = (fv4){0.f,0.f,0.f,0.f};
    #pragma unroll
    for (int ks = 0; ks < 2; ks++){
        short8 ah[2], al[2], bh_[4], bl_[4];
        #pragma unroll
        for (int mi = 0; mi < 2; mi++){
            unsigned off = (wy * 32 + mi * 16 + l15) * SP + ks * 32 + g * 8;
            ah[mi] = *reinterpret_cast<const short8*>(&XTh[off]);
            al[mi] = *reinterpret_cast<const short8*>(&XTl[off]);
        }
        #pragma unroll
        for (int ni = 0; ni < 4; ni++){
            unsigned off = (wx * 64 + ni * 16 + l15) * SP + ks * 32 + g * 8;
            bh_[ni] = *reinterpret_cast<const short8*>(&BTh[off]);
            bl_[ni] = *reinterpret_cast<const short8*>(&BTl[off]);
        }
        #pragma unroll
        for (int mi = 0; mi < 2; mi++)
            #pragma unroll
            for (int ni = 0; ni < 4; ni++){
                acc[mi][ni] = __builtin_amdgcn_mfma_f32_16x16x32_bf16(ah[mi], bh_[ni], acc[mi][ni], 0, 0, 0);
                acc[mi][ni] = __builtin_amdgcn_mfma_f32_16x16x32_bf16(ah[mi], bl_[ni], acc[mi][ni], 0, 0, 0);
                acc[mi][ni] = __builtin_amdgcn_mfma_f32_16x16x32_bf16(al[mi], bh_[ni], acc[mi][ni], 0, 0, 0);
            }
    }
    size_t sb = (size_t)(c * 4 + h) * 8192;
    #pragma unroll
    for (int mi = 0; mi < 2; mi++)
        #pragma unroll
        for (int ni = 0; ni < 4; ni++)
            #pragma unroll
            for (int j = 0; j < 4; j++){
                int p = wy * 32 + mi * 16 + g * 4 + j;
                int n = wx * 64 + ni * 16 + l15;
                Sb[sb + p * 128 + n] = bf16rnd(acc[mi][ni][j]);
            }
}

// ---------------- SSD phase B: prefix over chunks (bf16 S, 512x64 grid) ------------
__global__ __launch_bounds__(64) void ssd_phaseB(unsigned short* __restrict__ Sb,
                                                 const float* __restrict__ chunkT){
    __shared__ float e[NCH];
    int tid = threadIdx.x;
    int idx = blockIdx.x * 64 + tid;
    int h = idx >> 13, pn = idx & 8191;
    for (int c = tid; c < NCH; c += 64) e[c] = __expf(chunkT[c * 4 + h]);
    __syncthreads();
    #define ADDR_(cc) Sb[((size_t)((cc) * 4 + h)) * 8192 + pn]
    unsigned short r0 = ADDR_(0), r1 = ADDR_(1), r2 = ADDR_(2), r3 = ADDR_(3);
    float s = 0.f;
    int c = 0;
    for (; c + 8 <= NCH; c += 4){
        unsigned short n0 = ADDR_(c + 4), n1 = ADDR_(c + 5), n2 = ADDR_(c + 6), n3 = ADDR_(c + 7);
        ADDR_(c) = bf16rnd(s);     s = fmaf(s, e[c],     bf16f(r0));
        ADDR_(c + 1) = bf16rnd(s); s = fmaf(s, e[c + 1], bf16f(r1));
        ADDR_(c + 2) = bf16rnd(s); s = fmaf(s, e[c + 2], bf16f(r2));
        ADDR_(c + 3) = bf16rnd(s); s = fmaf(s, e[c + 3], bf16f(r3));
        r0 = n0; r1 = n1; r2 = n2; r3 = n3;
    }
    for (; c < NCH; c++){
        unsigned short nx = (c + 4 < NCH) ? ADDR_(c + 4) : (unsigned short)0;
        float loc = bf16f(r0); r0 = r1; r1 = r2; r2 = r3; r3 = nx;
        ADDR_(c) = bf16rnd(s);
        s = fmaf(s, e[c], loc);
    }
    #undef ADDR_
}

// ---------------- SSD phase C (MFMA, bf16 S direct, bf16 P, fused z-gating) --------
__global__ __launch_bounds__(256) void ssd_phaseC(const unsigned* __restrict__ xbcp,
                                                  const float* __restrict__ zx,
                                                  const float* __restrict__ dtbT,
                                                  const float* __restrict__ A_log,
                                                  const float* __restrict__ Dvec,
                                                  const unsigned short* __restrict__ Sb,
                                                  float* __restrict__ y){
    __shared__ __align__(16) unsigned short U0[64 * SP];
    __shared__ __align__(16) unsigned short U1h[64 * SP], U1l[64 * SP];
    __shared__ float cum[64], dth[64];
    int c, h;
    if (!ssd_decode(blockIdx.x, c, h)) return;
    int t0 = c * QC, Q = min(QC, HW - t0);
    int tid = threadIdx.x;
    chunk_cumsum_t(dtbT, t0, Q, h, A_log, cum, dth);
    int lane = tid & 63, wid = tid >> 6;
    int wy = wid >> 1, wx = wid & 1;
    int l15 = lane & 15, g = lane >> 4;

    int trow[2], srow[2], prow[2];
    #pragma unroll
    for (int i = 0; i < 2; i++){
        trow[i] = min(t0 + wy * 32 + i * 16 + l15, HW - 1);
        srow[i] = min(t0 + wx * 32 + i * 16 + l15, HW - 1);
        prow[i] = wx * 32 + i * 16 + l15;
    }

    fv4 accG[2][2], accA[2][2];
    #pragma unroll
    for (int mi = 0; mi < 2; mi++)
        #pragma unroll
        for (int ni = 0; ni < 2; ni++){ accG[mi][ni] = (fv4){0.f,0.f,0.f,0.f}; accA[mi][ni] = (fv4){0.f,0.f,0.f,0.f}; }

    const unsigned short* Sbase = Sb + (size_t)(c * 4 + h) * 8192;
    #pragma unroll
    for (int k0 = 0; k0 < 128; k0 += 32){
        short8 ah[2], al[2], bh[2], bl[2], sh[2];
        #pragma unroll
        for (int mi = 0; mi < 2; mi++)
            unpack8(xbcp + (size_t)trow[mi] * 512 + 384 + k0 + g * 8, ah[mi], al[mi]);
        #pragma unroll
        for (int ni = 0; ni < 2; ni++){
            unpack8(xbcp + (size_t)srow[ni] * 512 + 256 + k0 + g * 8, bh[ni], bl[ni]);
            sh[ni] = *reinterpret_cast<const short8*>(Sbase + prow[ni] * 128 + k0 + g * 8);
        }
        #pragma unroll
        for (int mi = 0; mi < 2; mi++)
            #pragma unroll
            for (int ni = 0; ni < 2; ni++){
                accG[mi][ni] = __builtin_amdgcn_mfma_f32_16x16x32_bf16(ah[mi], bh[ni], accG[mi][ni], 0, 0, 0);
                accG[mi][ni] = __builtin_amdgcn_mfma_f32_16x16x32_bf16(ah[mi], bl[ni], accG[mi][ni], 0, 0, 0);
                accG[mi][ni] = __builtin_amdgcn_mfma_f32_16x16x32_bf16(al[mi], bh[ni], accG[mi][ni], 0, 0, 0);
                accA[mi][ni] = __builtin_amdgcn_mfma_f32_16x16x32_bf16(ah[mi], sh[ni], accA[mi][ni], 0, 0, 0);
                accA[mi][ni] = __builtin_amdgcn_mfma_f32_16x16x32_bf16(al[mi], sh[ni], accA[mi][ni], 0, 0, 0);
            }
    }
    #pragma unroll
    for (int mi = 0; mi < 2; mi++)
        #pragma unroll
        for (int ni = 0; ni < 2; ni++)
            #pragma unroll
            for (int j = 0; j < 4; j++){
                int t = wy * 32 + mi * 16 + g * 4 + j;
                int s = wx * 32 + ni * 16 + l15;
                float pv = 0.f;
                if (s <= t && s < Q)
                    pv = accG[mi][ni][j] * __expf(cum[t] - cum[s]) * dth[s];
                U0[t * SP + s] = bf16rnd(pv);
            }
    for (int e2 = tid; e2 < 2048; e2 += 256){
        int pp = e2 & 63, sp = e2 >> 6;
        int s0 = 2 * sp;
        unsigned v0 = (s0 < Q)     ? xbcp[(size_t)(t0 + s0) * 512 + h * 64 + pp] : 0u;
        unsigned v1 = (s0 + 1 < Q) ? xbcp[(size_t)(t0 + s0 + 1) * 512 + h * 64 + pp] : 0u;
        *reinterpret_cast<unsigned*>(&U1h[pp * SP + s0]) = pack2((unsigned short)(v0 >> 16), (unsigned short)(v1 >> 16));
        *reinterpret_cast<unsigned*>(&U1l[pp * SP + s0]) = pack2((unsigned short)(v0 & 0xFFFFu), (unsigned short)(v1 & 0xFFFFu));
    }
    __syncthreads();
    fv4 accY[2][2];
    #pragma unroll
    for (int mi = 0; mi < 2; mi++)
        #pragma unroll
        for (int ni = 0; ni < 2; ni++)
            #pragma unroll
            for (int j = 0; j < 4; j++){
                int t = wy * 32 + mi * 16 + g * 4 + j;
                accY[mi][ni][j] = __expf(cum[t]) * accA[mi][ni][j];
            }
    #pragma unroll
    for (int kk = 0; kk < 2; kk++){
        short8 ph[2], xh[2], xl[2];
        #pragma unroll
        for (int mi = 0; mi < 2; mi++){
            unsigned off = (wy * 32 + mi * 16 + l15) * SP + kk * 32 + g * 8;
            ph[mi] = *reinterpret_cast<const short8*>(&U0[off]);
        }
        #pragma unroll
        for (int ni = 0; ni < 2; ni++){
            unsigned off = (wx * 32 + ni * 16 + l15) * SP + kk * 32 + g * 8;
            xh[ni] = *reinterpret_cast<const short8*>(&U1h[off]);
            xl[ni] = *reinterpret_cast<const short8*>(&U1l[off]);
        }
        #pragma unroll
        for (int mi = 0; mi < 2; mi++)
            #pragma unroll
            for (int ni = 0; ni < 2; ni++){
                accY[mi][ni] = __builtin_amdgcn_mfma_f32_16x16x32_bf16(ph[mi], xh[ni], accY[mi][ni], 0, 0, 0);
                accY[mi][ni] = __builtin_amdgcn_mfma_f32_16x16x32_bf16(ph[mi], xl[ni], accY[mi][ni], 0, 0, 0);
            }
    }
    float Dh = Dvec[h];
    #pragma unroll
    for (int mi = 0; mi < 2; mi++)
        #pragma unroll
        for (int ni = 0; ni < 2; ni++)
            #pragma unroll
            for (int j = 0; j < 4; j++){
                int t = wy * 32 + mi * 16 + g * 4 + j;
                if (t >= Q) continue;
                int p = wx * 32 + ni * 16 + l15;
                float xv = unpackf(xbcp[(size_t)(t0 + t) * 512 + h * 64 + p]);
                float zv = zx[(size_t)(t0 + t) * 772 + h * 64 + p];
                y[(size_t)(t0 + t) * 256 + h * 64 + p] = (accY[mi][ni][j] + Dh * xv) * silu_f(zv);
            }
}

// ---------------- RMSNorm (gating already applied in phaseC) ----------------
__global__ void rms_kernel(float* __restrict__ y, const float* __restrict__ nw){
    int row = blockIdx.x, tid = threadIdx.x;
    float v = y[(size_t)row * 256 + tid];
    float s = v * v;
    __shared__ float r1[4];
    #pragma unroll
    for (int o = 32; o > 0; o >>= 1) s += __shfl_down(s, o);
    if ((tid & 63) == 0) r1[tid >> 6] = s;
    __syncthreads();
    float S = r1[0] + r1[1] + r1[2] + r1[3];
    float rs = rsqrtf(S / 256.f + 1e-5f);
    y[(size_t)row * 256 + tid] = v * rs * nw[tid];
}

extern "C" void kernel_launch(void* const* d_in, const int* in_sizes, int n_in,
                              void* d_out, int out_size, void* d_ws, size_t ws_size,
                              hipStream_t stream){
    (void)in_sizes; (void)n_in; (void)out_size; (void)ws_size;
    const float* x        = (const float*)d_in[0];
    const float* ln_pre_g = (const float*)d_in[1];
    const float* ln_pre_b = (const float*)d_in[2];
    const float* fe_w1    = (const float*)d_in[3];
    const float* fe_b1    = (const float*)d_in[4];
    const float* fe_w2    = (const float*)d_in[5];
    const float* fe_b2    = (const float*)d_in[6];
    const float* cv_w1    = (const float*)d_in[7];
    const float* cv_b1    = (const float*)d_in[8];
    const float* cv_w2    = (const float*)d_in[9];
    const float* cv_b2    = (const float*)d_in[10];
    const float* mp_w     = (const float*)d_in[11];
    const float* mp_b     = (const float*)d_in[12];
    const float* mp_ln_g  = (const float*)d_in[13];
    const float* mp_ln_b  = (const float*)d_in[14];
    const float* m_in_w   = (const float*)d_in[15];
    const float* m_conv_w = (const float*)d_in[16];
    const float* m_conv_b = (const float*)d_in[17];
    const float* m_dtb    = (const float*)d_in[18];
    const float* m_A_log  = (const float*)d_in[19];
    const float* m_D      = (const float*)d_in[20];
    const float* m_norm_w = (const float*)d_in[21];
    const float* m_out_w  = (const float*)d_in[22];
    const float* cls_ln_g = (const float*)d_in[23];
    const float* cls_ln_b = (const float*)d_in[24];
    const float* cls_w1   = (const float*)d_in[25];
    const float* cls_b1   = (const float*)d_in[26];
    const float* cls_w2   = (const float*)d_in[27];
    const float* cls_b2   = (const float*)d_in[28];
    const float* cls_w3   = (const float*)d_in[29];
    const float* cls_b3   = (const float*)d_in[30];

    float* ws   = (float*)d_ws;
    float* xn   = ws + OFF_XN;
    float* f1   = ws + OFF_F1;
    float* comb = ws + OFF_COMB;
    float* p    = ws + OFF_P;
    float* zx   = ws + OFF_ZX;
    unsigned* xbcp = (unsigned*)(ws + OFF_XBC);
    unsigned short* Sb = (unsigned short*)(ws + OFF_S);
    float* dtbT = ws + OFF_DT;
    float* chkT = ws + OFF_CT;
    float* c1h  = ws + OFF_XBC;                    // before xbcp live
    float* c2h  = ws + OFF_XBC + 691488;
    float* ybuf = ws + OFF_F1;
    float* cls0 = ws + OFF_XN;
    float* cls1 = ws + OFF_P;
    unsigned short* W1h = (unsigned short*)(ws + OFF_W);
    unsigned short* W1l = (unsigned short*)(ws + OFF_W + 32256);
    unsigned short* W2h = (unsigned short*)(ws + OFF_W + 64512);
    unsigned short* W2l = (unsigned short*)(ws + OFF_W + 73728);
    const float* NUL = (const float*)nullptr;

    // 0. conv weight prepack (tiny)
    prep_w<200, 32, 7><<<(32 * 2016 + 255) / 256, 256, 0, stream>>>(cv_w1, W1h, W1l);
    prep_w<32, 64, 1><<<(64 * 288 + 255) / 256, 256, 0, stream>>>(cv_w2, W2h, W2l);
    // 1. pre-LN
    ln_kernel<0><<<HW, 256, 0, stream>>>(x, ln_pre_g, ln_pre_b, xn, NBANDS);
    // 2-3. feature MLP (f -> comb[:, :128])
    gemm_mfma_w<1, 4><<<gemm_grid(2, 165), 256, 0, stream>>>(xn, 200, fe_w1, 256, fe_b1,
        NUL, NUL, f1, 256, HW, 256, 200, 2, 165);
    gemm_mfma_w<1, 2><<<gemm_grid(1, 329), 256, 0, stream>>>(f1, 256, fe_w2, 128, fe_b2,
        NUL, NUL, comb, 192, HW, 128, 256, 1, 329);
    // 4. conv1 (MFMA implicit-im2col): 200->32, pad 2
    conv_mfma<200, 32, 2, 7, 1><<<dim3(3, CONVH), 256, 0, stream>>>(xn, Hdim, Wdim, W1h, W1l, cv_b1, c1h);
    // 5. conv2 (MFMA): 32->64, pad 1
    conv_mfma<32, 64, 1, 1, 2><<<dim3(3, CONVH), 256, 0, stream>>>(c1h, CONVH, CONVH, W2h, W2l, cv_b2, c2h);
    // 6. adaptive pool -> comb[:, 128:192]
    pool_kernel<<<(HW * 64 + 255) / 256, 256, 0, stream>>>(c2h, comb);
    // 7. mid projection + fused LN + GELU -> p
    gemm_mfma_w<3, 2><<<gemm_grid(1, 329), 256, 0, stream>>>(comb, 192, mp_w, 128, mp_b,
        mp_ln_g, mp_ln_b, p, 128, HW, 128, 192, 1, 329);
    // 8. mamba in_proj (cols 0..768 only)
    gemm_mfma_w<0, 4><<<gemm_grid(6, 165), 256, 0, stream>>>(p, 128, m_in_w, 772,
        NUL, NUL, NUL, zx, 772, HW, 768, 128, 6, 165);
    // 9. dt from p
    dt_from_p<<<(HW + 63) / 64, 256, 0, stream>>>(p, m_in_w, m_dtb, dtbT);
    // 10. depthwise causal conv + silu -> packed u32
    conv1d_tiled<<<dim3(4, NCH), 256, 0, stream>>>(zx, m_conv_w, m_conv_b, xbcp);
    // 11-13. SSD chunked scan
    ssd_phaseA<<<SSD_GRID, 256, 0, stream>>>(xbcp, dtbT, m_A_log, Sb, chkT);
    ssd_phaseB<<<512, 64, 0, stream>>>(Sb, chkT);
    ssd_phaseC<<<SSD_GRID, 256, 0, stream>>>(xbcp, zx, dtbT, m_A_log, m_D, Sb, ybuf);
    // 14. RMSNorm (gating fused into phaseC)
    rms_kernel<<<HW, 256, 0, stream>>>(ybuf, m_norm_w);
    // 15. out proj + fused cls LN -> cls0
    gemm_mfma_w<2, 2><<<gemm_grid(1, 329), 256, 0, stream>>>(ybuf, 256, m_out_w, 128,
        NUL, cls_ln_g, cls_ln_b, cls0, 128, HW, 128, 256, 1, 329);
    // 16. cls1
    gemm_mfma_w<1, 2><<<gemm_grid(1, 329), 256, 0, stream>>>(cls0, 128, cls_w1, 128, cls_b1,
        NUL, NUL, cls1, 128, HW, 128, 128, 1, 329);
    // 17. fused cls2+cls3 -> d_out
    cls_tail<<<gemm_grid(1, 329), 256, 0, stream>>>(cls1, cls_w2, cls_b2, cls_w3, cls_b3,
        (float*)d_out, HW, 329);
}

// Round 15
// 450.633 us; speedup vs baseline: 1.1852x; 1.0026x over previous
//
#include <hip/hip_runtime.h>
#include <math.h>

#define HW 21025        // 145*145
#define Hdim 145
#define Wdim 145
#define NBANDS 200
#define CONVH 147
#define CONVHW 21609    // 147*147
#define QC 64
#define NCH 329         // ceil(21025/64)
#define DTP 21056       // padded L for transposed dt
#define SP 72           // short stride for [.][64-k] MFMA tiles
#define SSD_GRID 1344   // 8 * 4 * 42 (xcd-sibling swizzled, tail-guarded)

typedef __attribute__((ext_vector_type(4))) float fv4;
typedef __attribute__((ext_vector_type(8))) short short8;

// ---------------- workspace layout (float offsets) ----------------
#define OFF_XN   ((size_t)0)           // 4,205,000  xn; later cls0
#define OFF_F1   ((size_t)4205000)     // 5,382,400  f1; later y (L x 256)
#define OFF_COMB ((size_t)9587400)     // 4,036,800  comb L x 192
#define OFF_P    ((size_t)13624200)    // 2,691,200  p; later cls1
#define OFF_ZX   ((size_t)16315400)    // 16,231,300 zxbcdt L x 772
#define OFF_XBC  ((size_t)32546700)    // 10,764,800 c1h+c2h first, then xbc packed u32
#define OFF_S    ((size_t)43311500)    // S as bf16 ushort
#define OFF_DT   ((size_t)54092172)    // 84,224 (dt transposed [4][DTP])
#define OFF_CT   ((size_t)54176396)    // 1,316
#define OFF_W    ((size_t)54177712)    // 82,944: packed conv weights (bf16 hi/lo)

__device__ __forceinline__ float gelu_f(float x){
    return 0.5f * x * (1.0f + erff(x * 0.70710678118654752440f));
}
__device__ __forceinline__ float silu_f(float x){
    return x / (1.0f + expf(-x));
}

__device__ __forceinline__ void bf16_split(float x, unsigned short& hs, unsigned short& ls){
    unsigned u = __float_as_uint(x);
    hs = (unsigned short)(u >> 16);
    float hif = __uint_as_float(u & 0xFFFF0000u);
    float lof = x - hif;
    ls = (unsigned short)(__float_as_uint(lof) >> 16);
}
__device__ __forceinline__ unsigned pack2(unsigned short a, unsigned short b){
    return (unsigned)a | ((unsigned)b << 16);
}
__device__ __forceinline__ unsigned packsplit(float x){
    unsigned short hs, ls;
    bf16_split(x, hs, ls);
    return ((unsigned)hs << 16) | (unsigned)ls;
}
__device__ __forceinline__ float unpackf(unsigned u){
    return __uint_as_float(u & 0xFFFF0000u) + __uint_as_float(u << 16);
}
__device__ __forceinline__ unsigned short bf16rnd(float x){
    unsigned u = __float_as_uint(x);
    unsigned r = u + 0x7FFFu + ((u >> 16) & 1u);
    return (unsigned short)(r >> 16);
}
__device__ __forceinline__ float bf16f(unsigned short h){
    return __uint_as_float((unsigned)h << 16);
}
__device__ __forceinline__ void unpack8(const unsigned* p, short8& h8, short8& l8){
    uint4 a = *reinterpret_cast<const uint4*>(p);
    uint4 b = *reinterpret_cast<const uint4*>(p + 4);
    unsigned v0 = a.x, v1 = a.y, v2 = a.z, v3 = a.w;
    unsigned v4 = b.x, v5 = b.y, v6 = b.z, v7 = b.w;
    h8[0]=(short)(v0>>16); l8[0]=(short)(v0&0xFFFFu);
    h8[1]=(short)(v1>>16); l8[1]=(short)(v1&0xFFFFu);
    h8[2]=(short)(v2>>16); l8[2]=(short)(v2&0xFFFFu);
    h8[3]=(short)(v3>>16); l8[3]=(short)(v3&0xFFFFu);
    h8[4]=(short)(v4>>16); l8[4]=(short)(v4&0xFFFFu);
    h8[5]=(short)(v5>>16); l8[5]=(short)(v5&0xFFFFu);
    h8[6]=(short)(v6>>16); l8[6]=(short)(v6&0xFFFFu);
    h8[7]=(short)(v7>>16); l8[7]=(short)(v7&0xFFFFu);
}

// XCD-grouped decode
__device__ __forceinline__ bool gemm_decode(int bid, int NXB, int NYB, int& bx, int& by){
    int m = bid & 7;
    int r = bid >> 3;
    bx = r % NXB;
    by = (r / NXB) * 8 + m;
    return by < NYB;
}
__host__ __forceinline__ int gemm_grid(int NXB, int NYB){ return 8 * ((NYB + 7) / 8) * NXB; }

// ---------------- LayerNorm (pre-LN only) ----------------
template<int ACT>
__global__ void ln_kernel(const float* __restrict__ in, const float* __restrict__ g,
                          const float* __restrict__ b, float* __restrict__ out, int D){
    int row = blockIdx.x, tid = threadIdx.x;
    const float* r = in + (size_t)row * D;
    float s = 0.f, s2 = 0.f;
    for (int i = tid; i < D; i += 256){ float v = r[i]; s += v; s2 += v*v; }
    __shared__ float r1[4], r2[4];
    #pragma unroll
    for (int o = 32; o > 0; o >>= 1){ s += __shfl_down(s, o); s2 += __shfl_down(s2, o); }
    if ((tid & 63) == 0){ r1[tid >> 6] = s; r2[tid >> 6] = s2; }
    __syncthreads();
    float S = r1[0] + r1[1] + r1[2] + r1[3];
    float S2 = r2[0] + r2[1] + r2[2] + r2[3];
    float mean = S / (float)D;
    float var = S2 / (float)D - mean * mean;
    float rs = rsqrtf(fmaxf(var, 0.f) + 1e-5f);
    float* o_ = out + (size_t)row * D;
    for (int i = tid; i < D; i += 256){
        float v = (r[i] - mean) * rs * g[i] + b[i];
        if (ACT == 1) v = gelu_f(v);
        o_[i] = v;
    }
}

// ---------------- wide split-bf16 MFMA GEMM: BN=128, BM=MI*32 ----------------
// ACT: 0 none, 1 gelu, 2 LN, 3 LN+gelu (LN requires N==128, NXB==1)
template<int ACT, int MI>
__global__ __launch_bounds__(256) void gemm_mfma_w(const float* __restrict__ A, int lda,
                                                   const float* __restrict__ B, int ldb,
                                                   const float* __restrict__ bias,
                                                   const float* __restrict__ lng,
                                                   const float* __restrict__ lnb,
                                                   float* __restrict__ C, int ldc,
                                                   int M, int N, int K, int NXB, int NYB){
    const int SA = 40;
    const int BM = MI * 32;
    __shared__ __align__(16) unsigned short Ah[BM * SA], Al[BM * SA];
    __shared__ __align__(16) unsigned short Bh[128 * SA], Bl[128 * SA];
    __shared__ float rs1[2][BM], rs2_[2][BM];
    int bx, by;
    if (!gemm_decode(blockIdx.x, NXB, NYB, bx, by)) return;
    int tid = threadIdx.x;
    int lane = tid & 63, wid = tid >> 6;
    int wy = wid >> 1, wx = wid & 1;
    int bm = by * BM, bn = bx * 128;
    int l15 = lane & 15, g = lane >> 4;

    fv4 acc[MI][4];
    #pragma unroll
    for (int i = 0; i < MI; i++)
        #pragma unroll
        for (int j = 0; j < 4; j++) acc[i][j] = (fv4){0.f,0.f,0.f,0.f};

    int bcol = tid & 127;
    int bk16 = (tid >> 7) * 16;
    bool bcol_ok = (bn + bcol) < N;

    int nK = (K + 31) / 32;
    for (int ks = 0; ks < nK; ks++){
        int k0 = ks * 32;
        #pragma unroll
        for (int f = 0; f < MI; f++){
            int idx = tid * MI + f;
            int row = idx >> 3, qd = idx & 7;
            fv4 v = (fv4){0.f,0.f,0.f,0.f};
            if ((bm + row) < M && (k0 + qd * 4 + 4) <= K)
                v = *reinterpret_cast<const fv4*>(A + (size_t)(bm + row) * lda + k0 + qd * 4);
            unsigned short hs[4], ls[4];
            #pragma unroll
            for (int j = 0; j < 4; j++) bf16_split(v[j], hs[j], ls[j]);
            unsigned off = row * SA + qd * 4;
            *reinterpret_cast<uint2*>(&Ah[off]) = make_uint2(pack2(hs[0],hs[1]), pack2(hs[2],hs[3]));
            *reinterpret_cast<uint2*>(&Al[off]) = make_uint2(pack2(ls[0],ls[1]), pack2(ls[2],ls[3]));
        }
        {
            unsigned short hs[16], ls[16];
            #pragma unroll
            for (int j = 0; j < 16; j++){
                int kk = k0 + bk16 + j;
                float v = (bcol_ok && kk < K) ? B[(size_t)kk * ldb + bn + bcol] : 0.f;
                bf16_split(v, hs[j], ls[j]);
            }
            unsigned off = bcol * SA + bk16;
            *reinterpret_cast<uint4*>(&Bh[off]) = make_uint4(pack2(hs[0],hs[1]), pack2(hs[2],hs[3]),
                                                             pack2(hs[4],hs[5]), pack2(hs[6],hs[7]));
            *reinterpret_cast<uint4*>(&Bh[off + 8]) = make_uint4(pack2(hs[8],hs[9]), pack2(hs[10],hs[11]),
                                                                 pack2(hs[12],hs[13]), pack2(hs[14],hs[15]));
            *reinterpret_cast<uint4*>(&Bl[off]) = make_uint4(pack2(ls[0],ls[1]), pack2(ls[2],ls[3]),
                                                             pack2(ls[4],ls[5]), pack2(ls[6],ls[7]));
            *reinterpret_cast<uint4*>(&Bl[off + 8]) = make_uint4(pack2(ls[8],ls[9]), pack2(ls[10],ls[11]),
                                                                 pack2(ls[12],ls[13]), pack2(ls[14],ls[15]));
        }
        __syncthreads();
        short8 afh[MI], afl[MI], bfh[4], bfl[4];
        #pragma unroll
        for (int mi = 0; mi < MI; mi++){
            unsigned off = (wy * (MI * 16) + mi * 16 + l15) * SA + g * 8;
            afh[mi] = *reinterpret_cast<const short8*>(&Ah[off]);
            afl[mi] = *reinterpret_cast<const short8*>(&Al[off]);
        }
        #pragma unroll
        for (int ni = 0; ni < 4; ni++){
            unsigned off = (wx * 64 + ni * 16 + l15) * SA + g * 8;
            bfh[ni] = *reinterpret_cast<const short8*>(&Bh[off]);
            bfl[ni] = *reinterpret_cast<const short8*>(&Bl[off]);
        }
        #pragma unroll
        for (int mi = 0; mi < MI; mi++)
            #pragma unroll
            for (int ni = 0; ni < 4; ni++){
                acc[mi][ni] = __builtin_amdgcn_mfma_f32_16x16x32_bf16(afh[mi], bfh[ni], acc[mi][ni], 0, 0, 0);
                acc[mi][ni] = __builtin_amdgcn_mfma_f32_16x16x32_bf16(afh[mi], bfl[ni], acc[mi][ni], 0, 0, 0);
                acc[mi][ni] = __builtin_amdgcn_mfma_f32_16x16x32_bf16(afl[mi], bfh[ni], acc[mi][ni], 0, 0, 0);
            }
        __syncthreads();
    }
    float bv[4], lgv[4], lbv[4];
    #pragma unroll
    for (int ni = 0; ni < 4; ni++){
        int cc = bn + wx * 64 + ni * 16 + l15;
        bool ok = cc < N;
        bv[ni]  = (bias && ok) ? bias[cc] : 0.f;
        if (ACT >= 2){ lgv[ni] = ok ? lng[cc] : 1.f; lbv[ni] = ok ? lnb[cc] : 0.f; }
    }
    if (ACT >= 2){
        #pragma unroll
        for (int mi = 0; mi < MI; mi++)
            #pragma unroll
            for (int j = 0; j < 4; j++){
                float s = 0.f, s2 = 0.f;
                #pragma unroll
                for (int ni = 0; ni < 4; ni++){
                    float v = acc[mi][ni][j] + bv[ni];
                    s += v; s2 += v * v;
                }
                #pragma unroll
                for (int o = 1; o < 16; o <<= 1){
                    s += __shfl_xor(s, o); s2 += __shfl_xor(s2, o);
                }
                int row = wy * (MI * 16) + mi * 16 + g * 4 + j;
                if (l15 == 0){ rs1[wx][row] = s; rs2_[wx][row] = s2; }
            }
        __syncthreads();
        #pragma unroll
        for (int mi = 0; mi < MI; mi++)
            #pragma unroll
            for (int j = 0; j < 4; j++){
                int row = wy * (MI * 16) + mi * 16 + g * 4 + j;
                int rr = bm + row;
                if (rr >= M) continue;
                float S = rs1[0][row] + rs1[1][row];
                float S2 = rs2_[0][row] + rs2_[1][row];
                float mean = S / 128.f;
                float var = S2 / 128.f - mean * mean;
                float rsq = rsqrtf(fmaxf(var, 0.f) + 1e-5f);
                #pragma unroll
                for (int ni = 0; ni < 4; ni++){
                    int cc = bn + wx * 64 + ni * 16 + l15;
                    float v = acc[mi][ni][j] + bv[ni];
                    v = (v - mean) * rsq * lgv[ni] + lbv[ni];
                    if (ACT == 3) v = gelu_f(v);
                    C[(size_t)rr * ldc + cc] = v;
                }
            }
    } else {
        #pragma unroll
        for (int mi = 0; mi < MI; mi++)
            #pragma unroll
            for (int ni = 0; ni < 4; ni++){
                int cc = bn + wx * 64 + ni * 16 + l15;
                if (cc >= N) continue;
                #pragma unroll
                for (int j = 0; j < 4; j++){
                    int rr = bm + wy * (MI * 16) + mi * 16 + g * 4 + j;
                    if (rr >= M) continue;
                    float v = acc[mi][ni][j] + bv[ni];
                    if (ACT == 1) v = gelu_f(v);
                    C[(size_t)rr * ldc + cc] = v;
                }
            }
    }
}

// ---------------- fused classifier tail: out = (gelu(A@W2+b2))@W3 + b3 -------------
__global__ __launch_bounds__(256) void cls_tail(const float* __restrict__ A,
                                                const float* __restrict__ W2,
                                                const float* __restrict__ b2,
                                                const float* __restrict__ W3,
                                                const float* __restrict__ b3,
                                                float* __restrict__ out,
                                                int M, int NYB){
    const int SA = 40;
    __shared__ __align__(16) unsigned short Ah[64 * SA], Al[64 * SA];
    __shared__ __align__(16) unsigned short Bh[64 * SA], Bl[64 * SA];
    __shared__ __align__(16) unsigned short A2h[64 * 72], A2l[64 * 72];
    __shared__ __align__(16) unsigned short B3h[32 * 72], B3l[32 * 72];
    int bx, by;
    if (!gemm_decode(blockIdx.x, 1, NYB, bx, by)) return;
    int tid = threadIdx.x;
    int lane = tid & 63, wid = tid >> 6;
    int wy = wid >> 1, wx = wid & 1;
    int bm = by * 64;
    int l15 = lane & 15, g = lane >> 4;

    for (int e = tid; e < 2048; e += 256){
        int n = e >> 6, k = e & 63;
        float v = (n < 17) ? W3[(size_t)k * 17 + n] : 0.f;
        unsigned short hs, ls;
        bf16_split(v, hs, ls);
        B3h[n * 72 + k] = hs;
        B3l[n * 72 + k] = ls;
    }

    fv4 acc[2][2];
    #pragma unroll
    for (int mi = 0; mi < 2; mi++)
        #pragma unroll
        for (int ni = 0; ni < 2; ni++) acc[mi][ni] = (fv4){0.f,0.f,0.f,0.f};

    int bn_t = tid & 63;
    int bk8 = (tid >> 6) * 8;
    #pragma unroll
    for (int ks = 0; ks < 4; ks++){
        int k0 = ks * 32;
        #pragma unroll
        for (int f = 0; f < 2; f++){
            int idx = tid * 2 + f;
            int row = idx >> 3, qd = idx & 7;
            fv4 v = (fv4){0.f,0.f,0.f,0.f};
            if ((bm + row) < M)
                v = *reinterpret_cast<const fv4*>(A + (size_t)(bm + row) * 128 + k0 + qd * 4);
            unsigned short hs[4], ls[4];
            #pragma unroll
            for (int j = 0; j < 4; j++) bf16_split(v[j], hs[j], ls[j]);
            unsigned off = row * SA + qd * 4;
            *reinterpret_cast<uint2*>(&Ah[off]) = make_uint2(pack2(hs[0],hs[1]), pack2(hs[2],hs[3]));
            *reinterpret_cast<uint2*>(&Al[off]) = make_uint2(pack2(ls[0],ls[1]), pack2(ls[2],ls[3]));
        }
        {
            unsigned short hs[8], ls[8];
            #pragma unroll
            for (int j = 0; j < 8; j++){
                int kk = k0 + bk8 + j;
                float v = W2[(size_t)kk * 64 + bn_t];
                bf16_split(v, hs[j], ls[j]);
            }
            unsigned off = bn_t * SA + bk8;
            *reinterpret_cast<uint4*>(&Bh[off]) = make_uint4(pack2(hs[0],hs[1]), pack2(hs[2],hs[3]),
                                                             pack2(hs[4],hs[5]), pack2(hs[6],hs[7]));
            *reinterpret_cast<uint4*>(&Bl[off]) = make_uint4(pack2(ls[0],ls[1]), pack2(ls[2],ls[3]),
                                                             pack2(ls[4],ls[5]), pack2(ls[6],ls[7]));
        }
        __syncthreads();
        short8 afh[2], afl[2], bfh[2], bfl[2];
        #pragma unroll
        for (int mi = 0; mi < 2; mi++){
            unsigned off = (wy * 32 + mi * 16 + l15) * SA + g * 8;
            afh[mi] = *reinterpret_cast<const short8*>(&Ah[off]);
            afl[mi] = *reinterpret_cast<const short8*>(&Al[off]);
        }
        #pragma unroll
        for (int ni = 0; ni < 2; ni++){
            unsigned off = (wx * 32 + ni * 16 + l15) * SA + g * 8;
            bfh[ni] = *reinterpret_cast<const short8*>(&Bh[off]);
            bfl[ni] = *reinterpret_cast<const short8*>(&Bl[off]);
        }
        #pragma unroll
        for (int mi = 0; mi < 2; mi++)
            #pragma unroll
            for (int ni = 0; ni < 2; ni++){
                acc[mi][ni] = __builtin_amdgcn_mfma_f32_16x16x32_bf16(afh[mi], bfh[ni], acc[mi][ni], 0, 0, 0);
                acc[mi][ni] = __builtin_amdgcn_mfma_f32_16x16x32_bf16(afh[mi], bfl[ni], acc[mi][ni], 0, 0, 0);
                acc[mi][ni] = __builtin_amdgcn_mfma_f32_16x16x32_bf16(afl[mi], bfh[ni], acc[mi][ni], 0, 0, 0);
            }
        __syncthreads();
    }
    #pragma unroll
    for (int mi = 0; mi < 2; mi++)
        #pragma unroll
        for (int ni = 0; ni < 2; ni++){
            int col = wx * 32 + ni * 16 + l15;
            float bv = b2[col];
            #pragma unroll
            for (int j = 0; j < 4; j++){
                int row = wy * 32 + mi * 16 + g * 4 + j;
                float v = gelu_f(acc[mi][ni][j] + bv);
                unsigned short hs, ls;
                bf16_split(v, hs, ls);
                A2h[row * 72 + col] = hs;
                A2l[row * 72 + col] = ls;
            }
        }
    __syncthreads();
    fv4 acc3[2];
    acc3[0] = (fv4){0.f,0.f,0.f,0.f};
    acc3[1] = (fv4){0.f,0.f,0.f,0.f};
    #pragma unroll
    for (int ks = 0; ks < 2; ks++){
        unsigned aoff = (wid * 16 + l15) * 72 + ks * 32 + g * 8;
        short8 a2h = *reinterpret_cast<const short8*>(&A2h[aoff]);
        short8 a2l = *reinterpret_cast<const short8*>(&A2l[aoff]);
        #pragma unroll
        for (int ni = 0; ni < 2; ni++){
            unsigned boff = (ni * 16 + l15) * 72 + ks * 32 + g * 8;
            short8 b3h_ = *reinterpret_cast<const short8*>(&B3h[boff]);
            short8 b3l_ = *reinterpret_cast<const short8*>(&B3l[boff]);
            acc3[ni] = __builtin_amdgcn_mfma_f32_16x16x32_bf16(a2h, b3h_, acc3[ni], 0, 0, 0);
            acc3[ni] = __builtin_amdgcn_mfma_f32_16x16x32_bf16(a2h, b3l_, acc3[ni], 0, 0, 0);
            acc3[ni] = __builtin_amdgcn_mfma_f32_16x16x32_bf16(a2l, b3h_, acc3[ni], 0, 0, 0);
        }
    }
    #pragma unroll
    for (int ni = 0; ni < 2; ni++){
        int col = ni * 16 + l15;
        if (col >= 17) continue;
        float bv = b3[col];
        #pragma unroll
        for (int j = 0; j < 4; j++){
            int row = bm + wid * 16 + g * 4 + j;
            if (row >= M) continue;
            out[(size_t)row * 17 + col] = acc3[ni][j] + bv;
        }
    }
}

// ---------------- dt from p ----------------
__global__ __launch_bounds__(256) void dt_from_p(const float* __restrict__ p,
                                                 const float* __restrict__ w,
                                                 const float* __restrict__ dtb,
                                                 float* __restrict__ dtbT){
    __shared__ float wl[512];
    int tid = threadIdx.x;
    for (int i = tid; i < 512; i += 256){
        int k = i >> 2, h = i & 3;
        wl[i] = w[(size_t)k * 772 + 768 + h];
    }
    __syncthreads();
    int t = blockIdx.x * 64 + (tid >> 2);
    int h = tid & 3;
    if (t >= HW) return;
    const float* pr = p + (size_t)t * 128;
    float s = 0.f;
    for (int k = 0; k < 128; k += 4){
        fv4 v = *reinterpret_cast<const fv4*>(pr + k);
        s += v[0]*wl[k*4+h] + v[1]*wl[(k+1)*4+h] + v[2]*wl[(k+2)*4+h] + v[3]*wl[(k+3)*4+h];
    }
    s += dtb[h];
    dtbT[h * DTP + t] = (s > 20.f) ? s : log1pf(expf(s));
}

// ---------------- conv weight prepack ----------------
template<int IC, int OC, int NCHUNK>
__global__ void prep_w(const float* __restrict__ w, unsigned short* __restrict__ Wh,
                       unsigned short* __restrict__ Wl){
    const int KP = NCHUNK * 288;
    int idx = blockIdx.x * 256 + threadIdx.x;
    if (idx >= OC * KP) return;
    int o = idx / KP, k = idx % KP;
    int ch = k / 288, rest = k % 288, t = rest / 32, c = rest & 31;
    int ci = ch * 32 + c;
    float v = (ci < IC) ? w[((size_t)o * IC + ci) * 9 + t] : 0.f;
    unsigned short hs, ls;
    bf16_split(v, hs, ls);
    Wh[idx] = hs; Wl[idx] = ls;
}

// ---------------- MFMA direct conv 3x3 ----------------
template<int IC, int OC, int PAD, int NCHUNK, int NFRAG>
__global__ __launch_bounds__(256) void conv_mfma(const float* __restrict__ in,
                                                 int inH, int inW,
                                                 const unsigned short* __restrict__ Wh,
                                                 const unsigned short* __restrict__ Wl,
                                                 const float* __restrict__ bias,
                                                 float* __restrict__ out){
    const int KP = NCHUNK * 288;
    const int CST = 40;
    __shared__ __align__(16) unsigned short Xh[3 * 68 * CST], Xl[3 * 68 * CST];
    int y = blockIdx.y;
    int x0 = blockIdx.x * 64;
    int tid = threadIdx.x;
    int lane = tid & 63, wid = tid >> 6;
    int wy = wid >> 1, wx = wid & 1;
    int l15 = lane & 15, g = lane >> 4;

    fv4 acc[2][NFRAG];
    #pragma unroll
    for (int mi = 0; mi < 2; mi++)
        #pragma unroll
        for (int ni = 0; ni < NFRAG; ni++) acc[mi][ni] = (fv4){0.f,0.f,0.f,0.f};

    for (int ch = 0; ch < NCHUNK; ch++){
        int ci0 = ch * 32;
        if (ch > 0) __syncthreads();
        for (int e = tid; e < 3 * 68 * 8; e += 256){
            int qd = e & 7;
            int c  = (e >> 3) % 68;
            int r  = e / 544;
            int iy = y - PAD + r, ix = x0 - PAD + c;
            fv4 v = (fv4){0.f,0.f,0.f,0.f};
            if ((unsigned)iy < (unsigned)inH && (unsigned)ix < (unsigned)inW &&
                (ci0 + qd * 4 + 4) <= IC)
                v = *reinterpret_cast<const fv4*>(in + ((size_t)iy * inW + ix) * IC + ci0 + qd * 4);
            unsigned short hs[4], ls[4];
            #pragma unroll
            for (int j = 0; j < 4; j++) bf16_split(v[j], hs[j], ls[j]);
            unsigned off = (r * 68 + c) * CST + qd * 4;
            *reinterpret_cast<uint2*>(&Xh[off]) = make_uint2(pack2(hs[0],hs[1]), pack2(hs[2],hs[3]));
            *reinterpret_cast<uint2*>(&Xl[off]) = make_uint2(pack2(ls[0],ls[1]), pack2(ls[2],ls[3]));
        }
        __syncthreads();
        #pragma unroll
        for (int t = 0; t < 9; t++){
            int ky = t / 3, kx = t % 3;
            short8 ah[2], al[2], bh[NFRAG], bl[NFRAG];
            #pragma unroll
            for (int mi = 0; mi < 2; mi++){
                unsigned off = (ky * 68 + wy * 32 + mi * 16 + l15 + kx) * CST + g * 8;
                ah[mi] = *reinterpret_cast<const short8*>(&Xh[off]);
                al[mi] = *reinterpret_cast<const short8*>(&Xl[off]);
            }
            #pragma unroll
            for (int ni = 0; ni < NFRAG; ni++){
                int oc = wx * (16 * NFRAG) + ni * 16 + l15;
                size_t woff = (size_t)oc * KP + ch * 288 + t * 32 + g * 8;
                bh[ni] = *reinterpret_cast<const short8*>(&Wh[woff]);
                bl[ni] = *reinterpret_cast<const short8*>(&Wl[woff]);
            }
            #pragma unroll
            for (int mi = 0; mi < 2; mi++)
                #pragma unroll
                for (int ni = 0; ni < NFRAG; ni++){
                    acc[mi][ni] = __builtin_amdgcn_mfma_f32_16x16x32_bf16(ah[mi], bh[ni], acc[mi][ni], 0, 0, 0);
                    acc[mi][ni] = __builtin_amdgcn_mfma_f32_16x16x32_bf16(ah[mi], bl[ni], acc[mi][ni], 0, 0, 0);
                    acc[mi][ni] = __builtin_amdgcn_mfma_f32_16x16x32_bf16(al[mi], bh[ni], acc[mi][ni], 0, 0, 0);
                }
        }
    }
    #pragma unroll
    for (int mi = 0; mi < 2; mi++)
        #pragma unroll
        for (int ni = 0; ni < NFRAG; ni++){
            int oc = wx * (16 * NFRAG) + ni * 16 + l15;
            float bv = bias[oc];
            #pragma unroll
            for (int j = 0; j < 4; j++){
                int x = x0 + wy * 32 + mi * 16 + g * 4 + j;
                if (x >= CONVH) continue;
                out[((size_t)y * CONVH + x) * OC + oc] = gelu_f(acc[mi][ni][j] + bv);
            }
        }
}

// ---------------- adaptive pool ----------------
__global__ void pool_kernel(const float* __restrict__ c2, float* __restrict__ comb){
    int idx = blockIdx.x * 256 + threadIdx.x;
    if (idx >= HW * 64) return;
    int o = idx & 63;
    int pix = idx >> 6;
    int xo = pix % Wdim, yo = pix / Wdim;
    int ys = yo * CONVH / Hdim, ye = ((yo + 1) * CONVH + Hdim - 1) / Hdim;
    int xs = xo * CONVH / Wdim, xe = ((xo + 1) * CONVH + Wdim - 1) / Wdim;
    float s = 0.f;
    for (int yy = ys; yy < ye; yy++)
        for (int xx = xs; xx < xe; xx++)
            s += c2[((size_t)yy * CONVH + xx) * 64 + o];
    comb[(size_t)pix * 192 + 128 + o] = s / (float)((ye - ys) * (xe - xs));
}

// ---------------- conv1d + silu -> packed u32 ----------------
__global__ __launch_bounds__(256) void conv1d_tiled(const float* __restrict__ zx,
                                                    const float* __restrict__ w,
                                                    const float* __restrict__ b,
                                                    unsigned* __restrict__ xbcp){
    __shared__ float xs[67 * 128];
    __shared__ float wc[4 * 128];
    __shared__ float bc[128];
    int t0 = blockIdx.y * 64;
    int c0 = blockIdx.x * 128;
    int tid = threadIdx.x;
    for (int e = tid; e < 67 * 128; e += 256){
        int rr = e >> 7, cc = e & 127;
        int t = t0 - 3 + rr;
        xs[e] = (t >= 0 && t < HW) ? zx[(size_t)t * 772 + 256 + c0 + cc] : 0.f;
    }
    if (tid < 128){
        bc[tid] = b[c0 + tid];
        #pragma unroll
        for (int k = 0; k < 4; k++) wc[k * 128 + tid] = w[(c0 + tid) * 4 + k];
    }
    __syncthreads();
    for (int e = tid; e < 64 * 128; e += 256){
        int tt = e >> 7, cc = e & 127;
        if (t0 + tt >= HW) continue;
        float acc = bc[cc];
        #pragma unroll
        for (int k = 0; k < 4; k++) acc += xs[(tt + k) * 128 + cc] * wc[k * 128 + cc];
        xbcp[(size_t)(t0 + tt) * 512 + c0 + cc] = packsplit(silu_f(acc));
    }
}

// ---------------- chunk cumsum (wave 0) ----------------
__device__ __forceinline__ void chunk_cumsum_t(const float* __restrict__ dtbT, int t0, int Q,
                                               int h, const float* __restrict__ A_log,
                                               float* cum, float* dth){
    int tid = threadIdx.x;
    if (tid < 64){
        float d = (tid < Q) ? dtbT[h * DTP + t0 + tid] : 0.f;
        dth[tid] = d;
        float A = -expf(A_log[h]);
        float a = d * A;
        #pragma unroll
        for (int off = 1; off < 64; off <<= 1){
            float u = __shfl_up(a, off);
            if (tid >= off) a += u;
        }
        cum[tid] = a;
    }
    __syncthreads();
}

__device__ __forceinline__ bool ssd_decode(int bid, int& c, int& h){
    int m = bid & 7, rest = bid >> 3;
    h = rest & 3;
    c = (rest >> 2) * 8 + m;
    return c < NCH;
}

// ---------------- SSD phase A (MFMA; B as bf16-hi only — S is bf16 anyway) ---------
__global__ __launch_bounds__(256) void ssd_phaseA(const unsigned* __restrict__ xbcp,
                                                  const float* __restrict__ dtbT,
                                                  const float* __restrict__ A_log,
                                                  unsigned short* __restrict__ Sb,
                                                  float* __restrict__ chunkT){
    __shared__ __align__(16) unsigned short BTh[128 * SP];                // B^T hi [n][s]
    __shared__ __align__(16) unsigned short XTh[64 * SP],  XTl[64 * SP];  // (Xw)^T [p][s]
    __shared__ float cum[64], dth[64], wln[64];
    int c, h;
    if (!ssd_decode(blockIdx.x, c, h)) return;
    int t0 = c * QC, Q = min(QC, HW - t0);
    int tid = threadIdx.x;
    chunk_cumsum_t(dtbT, t0, Q, h, A_log, cum, dth);
    float T = cum[Q - 1];
    if (tid == 0) chunkT[c * 4 + h] = T;
    if (tid < 64) wln[tid] = (tid < Q) ? __expf(T - cum[tid]) * dth[tid] : 0.f;
    __syncthreads();
    for (int e2 = tid; e2 < 4096; e2 += 256){
        int nn = e2 & 127, sp = e2 >> 7;
        int s0 = 2 * sp;
        unsigned v0 = (s0 < Q)     ? xbcp[(size_t)(t0 + s0) * 512 + 256 + nn] : 0u;
        unsigned v1 = (s0 + 1 < Q) ? xbcp[(size_t)(t0 + s0 + 1) * 512 + 256 + nn] : 0u;
        *reinterpret_cast<unsigned*>(&BTh[nn * SP + s0]) = pack2((unsigned short)(v0 >> 16), (unsigned short)(v1 >> 16));
    }
    for (int e2 = tid; e2 < 2048; e2 += 256){
        int pp = e2 & 63, sp = e2 >> 6;
        int s0 = 2 * sp;
        float v0 = (s0 < Q)     ? unpackf(xbcp[(size_t)(t0 + s0) * 512 + h * 64 + pp]) * wln[s0] : 0.f;
        float v1 = (s0 + 1 < Q) ? unpackf(xbcp[(size_t)(t0 + s0 + 1) * 512 + h * 64 + pp]) * wln[s0 + 1] : 0.f;
        unsigned short h0, l0, h1, l1;
        bf16_split(v0, h0, l0); bf16_split(v1, h1, l1);
        *reinterpret_cast<unsigned*>(&XTh[pp * SP + s0]) = pack2(h0, h1);
        *reinterpret_cast<unsigned*>(&XTl[pp * SP + s0]) = pack2(l0, l1);
    }
    __syncthreads();
    int lane = tid & 63, wid = tid >> 6;
    int wy = wid >> 1, wx = wid & 1;
    int l15 = lane & 15, g = lane >> 4;
    fv4 acc[2][4];
    #pragma unroll
    for (int mi = 0; mi < 2; mi++)
        #pragma unroll
        for (int ni = 0; ni < 4; ni++) acc[mi][ni] = (fv4){0.f,0.f,0.f,0.f};
    #pragma unroll
    for (int ks = 0; ks < 2; ks++){
        short8 ah[2], al[2], bh_[4];
        #pragma unroll
        for (int mi = 0; mi < 2; mi++){
            unsigned off = (wy * 32 + mi * 16 + l15) * SP + ks * 32 + g * 8;
            ah[mi] = *reinterpret_cast<const short8*>(&XTh[off]);
            al[mi] = *reinterpret_cast<const short8*>(&XTl[off]);
        }
        #pragma unroll
        for (int ni = 0; ni < 4; ni++){
            unsigned off = (wx * 64 + ni * 16 + l15) * SP + ks * 32 + g * 8;
            bh_[ni] = *reinterpret_cast<const short8*>(&BTh[off]);
        }
        #pragma unroll
        for (int mi = 0; mi < 2; mi++)
            #pragma unroll
            for (int ni = 0; ni < 4; ni++){
                acc[mi][ni] = __builtin_amdgcn_mfma_f32_16x16x32_bf16(ah[mi], bh_[ni], acc[mi][ni], 0, 0, 0);
                acc[mi][ni] = __builtin_amdgcn_mfma_f32_16x16x32_bf16(al[mi], bh_[ni], acc[mi][ni], 0, 0, 0);
            }
    }
    size_t sb = (size_t)(c * 4 + h) * 8192;
    #pragma unroll
    for (int mi = 0; mi < 2; mi++)
        #pragma unroll
        for (int ni = 0; ni < 4; ni++)
            #pragma unroll
            for (int j = 0; j < 4; j++){
                int p = wy * 32 + mi * 16 + g * 4 + j;
                int n = wx * 64 + ni * 16 + l15;
                Sb[sb + p * 128 + n] = bf16rnd(acc[mi][ni][j]);
            }
}

// ---------------- SSD phase B: prefix over chunks (bf16 S, 512x64 grid) ------------
__global__ __launch_bounds__(64) void ssd_phaseB(unsigned short* __restrict__ Sb,
                                                 const float* __restrict__ chunkT){
    __shared__ float e[NCH];
    int tid = threadIdx.x;
    int idx = blockIdx.x * 64 + tid;
    int h = idx >> 13, pn = idx & 8191;
    for (int c = tid; c < NCH; c += 64) e[c] = __expf(chunkT[c * 4 + h]);
    __syncthreads();
    #define ADDR_(cc) Sb[((size_t)((cc) * 4 + h)) * 8192 + pn]
    unsigned short r0 = ADDR_(0), r1 = ADDR_(1), r2 = ADDR_(2), r3 = ADDR_(3);
    float s = 0.f;
    int c = 0;
    for (; c + 8 <= NCH; c += 4){
        unsigned short n0 = ADDR_(c + 4), n1 = ADDR_(c + 5), n2 = ADDR_(c + 6), n3 = ADDR_(c + 7);
        ADDR_(c) = bf16rnd(s);     s = fmaf(s, e[c],     bf16f(r0));
        ADDR_(c + 1) = bf16rnd(s); s = fmaf(s, e[c + 1], bf16f(r1));
        ADDR_(c + 2) = bf16rnd(s); s = fmaf(s, e[c + 2], bf16f(r2));
        ADDR_(c + 3) = bf16rnd(s); s = fmaf(s, e[c + 3], bf16f(r3));
        r0 = n0; r1 = n1; r2 = n2; r3 = n3;
    }
    for (; c < NCH; c++){
        unsigned short nx = (c + 4 < NCH) ? ADDR_(c + 4) : (unsigned short)0;
        float loc = bf16f(r0); r0 = r1; r1 = r2; r2 = r3; r3 = nx;
        ADDR_(c) = bf16rnd(s);
        s = fmaf(s, e[c], loc);
    }
    #undef ADDR_
}

// ---------------- SSD phase C (MFMA; PV X as bf16-hi only; fused z-gating) ---------
__global__ __launch_bounds__(256) void ssd_phaseC(const unsigned* __restrict__ xbcp,
                                                  const float* __restrict__ zx,
                                                  const float* __restrict__ dtbT,
                                                  const float* __restrict__ A_log,
                                                  const float* __restrict__ Dvec,
                                                  const unsigned short* __restrict__ Sb,
                                                  float* __restrict__ y){
    __shared__ __align__(16) unsigned short U0[64 * SP];   // P bf16 [t][s]
    __shared__ __align__(16) unsigned short U1h[64 * SP];  // X^T hi [p][s]
    __shared__ float cum[64], dth[64];
    int c, h;
    if (!ssd_decode(blockIdx.x, c, h)) return;
    int t0 = c * QC, Q = min(QC, HW - t0);
    int tid = threadIdx.x;
    chunk_cumsum_t(dtbT, t0, Q, h, A_log, cum, dth);
    int lane = tid & 63, wid = tid >> 6;
    int wy = wid >> 1, wx = wid & 1;
    int l15 = lane & 15, g = lane >> 4;

    int trow[2], srow[2], prow[2];
    #pragma unroll
    for (int i = 0; i < 2; i++){
        trow[i] = min(t0 + wy * 32 + i * 16 + l15, HW - 1);
        srow[i] = min(t0 + wx * 32 + i * 16 + l15, HW - 1);
        prow[i] = wx * 32 + i * 16 + l15;
    }

    fv4 accG[2][2], accA[2][2];
    #pragma unroll
    for (int mi = 0; mi < 2; mi++)
        #pragma unroll
        for (int ni = 0; ni < 2; ni++){ accG[mi][ni] = (fv4){0.f,0.f,0.f,0.f}; accA[mi][ni] = (fv4){0.f,0.f,0.f,0.f}; }

    const unsigned short* Sbase = Sb + (size_t)(c * 4 + h) * 8192;
    #pragma unroll
    for (int k0 = 0; k0 < 128; k0 += 32){
        short8 ah[2], al[2], bh[2], bl[2], sh[2];
        #pragma unroll
        for (int mi = 0; mi < 2; mi++)
            unpack8(xbcp + (size_t)trow[mi] * 512 + 384 + k0 + g * 8, ah[mi], al[mi]);
        #pragma unroll
        for (int ni = 0; ni < 2; ni++){
            unpack8(xbcp + (size_t)srow[ni] * 512 + 256 + k0 + g * 8, bh[ni], bl[ni]);
            sh[ni] = *reinterpret_cast<const short8*>(Sbase + prow[ni] * 128 + k0 + g * 8);
        }
        #pragma unroll
        for (int mi = 0; mi < 2; mi++)
            #pragma unroll
            for (int ni = 0; ni < 2; ni++){
                accG[mi][ni] = __builtin_amdgcn_mfma_f32_16x16x32_bf16(ah[mi], bh[ni], accG[mi][ni], 0, 0, 0);
                accG[mi][ni] = __builtin_amdgcn_mfma_f32_16x16x32_bf16(ah[mi], bl[ni], accG[mi][ni], 0, 0, 0);
                accG[mi][ni] = __builtin_amdgcn_mfma_f32_16x16x32_bf16(al[mi], bh[ni], accG[mi][ni], 0, 0, 0);
                accA[mi][ni] = __builtin_amdgcn_mfma_f32_16x16x32_bf16(ah[mi], sh[ni], accA[mi][ni], 0, 0, 0);
                accA[mi][ni] = __builtin_amdgcn_mfma_f32_16x16x32_bf16(al[mi], sh[ni], accA[mi][ni], 0, 0, 0);
            }
    }
    #pragma unroll
    for (int mi = 0; mi < 2; mi++)
        #pragma unroll
        for (int ni = 0; ni < 2; ni++)
            #pragma unroll
            for (int j = 0; j < 4; j++){
                int t = wy * 32 + mi * 16 + g * 4 + j;
                int s = wx * 32 + ni * 16 + l15;
                float pv = 0.f;
                if (s <= t && s < Q)
                    pv = accG[mi][ni][j] * __expf(cum[t] - cum[s]) * dth[s];
                U0[t * SP + s] = bf16rnd(pv);
            }
    for (int e2 = tid; e2 < 2048; e2 += 256){
        int pp = e2 & 63, sp = e2 >> 6;
        int s0 = 2 * sp;
        unsigned v0 = (s0 < Q)     ? xbcp[(size_t)(t0 + s0) * 512 + h * 64 + pp] : 0u;
        unsigned v1 = (s0 + 1 < Q) ? xbcp[(size_t)(t0 + s0 + 1) * 512 + h * 64 + pp] : 0u;
        *reinterpret_cast<unsigned*>(&U1h[pp * SP + s0]) = pack2((unsigned short)(v0 >> 16), (unsigned short)(v1 >> 16));
    }
    __syncthreads();
    fv4 accY[2][2];
    #pragma unroll
    for (int mi = 0; mi < 2; mi++)
        #pragma unroll
        for (int ni = 0; ni < 2; ni++)
            #pragma unroll
            for (int j = 0; j < 4; j++){
                int t = wy * 32 + mi * 16 + g * 4 + j;
                accY[mi][ni][j] = __expf(cum[t]) * accA[mi][ni][j];
            }
    #pragma unroll
    for (int kk = 0; kk < 2; kk++){
        short8 ph[2], xh[2];
        #pragma unroll
        for (int mi = 0; mi < 2; mi++){
            unsigned off = (wy * 32 + mi * 16 + l15) * SP + kk * 32 + g * 8;
            ph[mi] = *reinterpret_cast<const short8*>(&U0[off]);
        }
        #pragma unroll
        for (int ni = 0; ni < 2; ni++){
            unsigned off = (wx * 32 + ni * 16 + l15) * SP + kk * 32 + g * 8;
            xh[ni] = *reinterpret_cast<const short8*>(&U1h[off]);
        }
        #pragma unroll
        for (int mi = 0; mi < 2; mi++)
            #pragma unroll
            for (int ni = 0; ni < 2; ni++)
                accY[mi][ni] = __builtin_amdgcn_mfma_f32_16x16x32_bf16(ph[mi], xh[ni], accY[mi][ni], 0, 0, 0);
    }
    float Dh = Dvec[h];
    #pragma unroll
    for (int mi = 0; mi < 2; mi++)
        #pragma unroll
        for (int ni = 0; ni < 2; ni++)
            #pragma unroll
            for (int j = 0; j < 4; j++){
                int t = wy * 32 + mi * 16 + g * 4 + j;
                if (t >= Q) continue;
                int p = wx * 32 + ni * 16 + l15;
                float xv = unpackf(xbcp[(size_t)(t0 + t) * 512 + h * 64 + p]);
                float zv = zx[(size_t)(t0 + t) * 772 + h * 64 + p];
                y[(size_t)(t0 + t) * 256 + h * 64 + p] = (accY[mi][ni][j] + Dh * xv) * silu_f(zv);
            }
}

// ---------------- RMSNorm (gating already applied in phaseC) ----------------
__global__ void rms_kernel(float* __restrict__ y, const float* __restrict__ nw){
    int row = blockIdx.x, tid = threadIdx.x;
    float v = y[(size_t)row * 256 + tid];
    float s = v * v;
    __shared__ float r1[4];
    #pragma unroll
    for (int o = 32; o > 0; o >>= 1) s += __shfl_down(s, o);
    if ((tid & 63) == 0) r1[tid >> 6] = s;
    __syncthreads();
    float S = r1[0] + r1[1] + r1[2] + r1[3];
    float rs = rsqrtf(S / 256.f + 1e-5f);
    y[(size_t)row * 256 + tid] = v * rs * nw[tid];
}

extern "C" void kernel_launch(void* const* d_in, const int* in_sizes, int n_in,
                              void* d_out, int out_size, void* d_ws, size_t ws_size,
                              hipStream_t stream){
    (void)in_sizes; (void)n_in; (void)out_size; (void)ws_size;
    const float* x        = (const float*)d_in[0];
    const float* ln_pre_g = (const float*)d_in[1];
    const float* ln_pre_b = (const float*)d_in[2];
    const float* fe_w1    = (const float*)d_in[3];
    const float* fe_b1    = (const float*)d_in[4];
    const float* fe_w2    = (const float*)d_in[5];
    const float* fe_b2    = (const float*)d_in[6];
    const float* cv_w1    = (const float*)d_in[7];
    const float* cv_b1    = (const float*)d_in[8];
    const float* cv_w2    = (const float*)d_in[9];
    const float* cv_b2    = (const float*)d_in[10];
    const float* mp_w     = (const float*)d_in[11];
    const float* mp_b     = (const float*)d_in[12];
    const float* mp_ln_g  = (const float*)d_in[13];
    const float* mp_ln_b  = (const float*)d_in[14];
    const float* m_in_w   = (const float*)d_in[15];
    const float* m_conv_w = (const float*)d_in[16];
    const float* m_conv_b = (const float*)d_in[17];
    const float* m_dtb    = (const float*)d_in[18];
    const float* m_A_log  = (const float*)d_in[19];
    const float* m_D      = (const float*)d_in[20];
    const float* m_norm_w = (const float*)d_in[21];
    const float* m_out_w  = (const float*)d_in[22];
    const float* cls_ln_g = (const float*)d_in[23];
    const float* cls_ln_b = (const float*)d_in[24];
    const float* cls_w1   = (const float*)d_in[25];
    const float* cls_b1   = (const float*)d_in[26];
    const float* cls_w2   = (const float*)d_in[27];
    const float* cls_b2   = (const float*)d_in[28];
    const float* cls_w3   = (const float*)d_in[29];
    const float* cls_b3   = (const float*)d_in[30];

    float* ws   = (float*)d_ws;
    float* xn   = ws + OFF_XN;
    float* f1   = ws + OFF_F1;
    float* comb = ws + OFF_COMB;
    float* p    = ws + OFF_P;
    float* zx   = ws + OFF_ZX;
    unsigned* xbcp = (unsigned*)(ws + OFF_XBC);
    unsigned short* Sb = (unsigned short*)(ws + OFF_S);
    float* dtbT = ws + OFF_DT;
    float* chkT = ws + OFF_CT;
    float* c1h  = ws + OFF_XBC;                    // before xbcp live
    float* c2h  = ws + OFF_XBC + 691488;
    float* ybuf = ws + OFF_F1;
    float* cls0 = ws + OFF_XN;
    float* cls1 = ws + OFF_P;
    unsigned short* W1h = (unsigned short*)(ws + OFF_W);
    unsigned short* W1l = (unsigned short*)(ws + OFF_W + 32256);
    unsigned short* W2h = (unsigned short*)(ws + OFF_W + 64512);
    unsigned short* W2l = (unsigned short*)(ws + OFF_W + 73728);
    const float* NUL = (const float*)nullptr;

    // 0. conv weight prepack (tiny)
    prep_w<200, 32, 7><<<(32 * 2016 + 255) / 256, 256, 0, stream>>>(cv_w1, W1h, W1l);
    prep_w<32, 64, 1><<<(64 * 288 + 255) / 256, 256, 0, stream>>>(cv_w2, W2h, W2l);
    // 1. pre-LN
    ln_kernel<0><<<HW, 256, 0, stream>>>(x, ln_pre_g, ln_pre_b, xn, NBANDS);
    // 2-3. feature MLP (f -> comb[:, :128])
    gemm_mfma_w<1, 4><<<gemm_grid(2, 165), 256, 0, stream>>>(xn, 200, fe_w1, 256, fe_b1,
        NUL, NUL, f1, 256, HW, 256, 200, 2, 165);
    gemm_mfma_w<1, 2><<<gemm_grid(1, 329), 256, 0, stream>>>(f1, 256, fe_w2, 128, fe_b2,
        NUL, NUL, comb, 192, HW, 128, 256, 1, 329);
    // 4. conv1 (MFMA implicit-im2col): 200->32, pad 2
    conv_mfma<200, 32, 2, 7, 1><<<dim3(3, CONVH), 256, 0, stream>>>(xn, Hdim, Wdim, W1h, W1l, cv_b1, c1h);
    // 5. conv2 (MFMA): 32->64, pad 1
    conv_mfma<32, 64, 1, 1, 2><<<dim3(3, CONVH), 256, 0, stream>>>(c1h, CONVH, CONVH, W2h, W2l, cv_b2, c2h);
    // 6. adaptive pool -> comb[:, 128:192]
    pool_kernel<<<(HW * 64 + 255) / 256, 256, 0, stream>>>(c2h, comb);
    // 7. mid projection + fused LN + GELU -> p
    gemm_mfma_w<3, 2><<<gemm_grid(1, 329), 256, 0, stream>>>(comb, 192, mp_w, 128, mp_b,
        mp_ln_g, mp_ln_b, p, 128, HW, 128, 192, 1, 329);
    // 8. mamba in_proj (cols 0..768 only)
    gemm_mfma_w<0, 4><<<gemm_grid(6, 165), 256, 0, stream>>>(p, 128, m_in_w, 772,
        NUL, NUL, NUL, zx, 772, HW, 768, 128, 6, 165);
    // 9. dt from p
    dt_from_p<<<(HW + 63) / 64, 256, 0, stream>>>(p, m_in_w, m_dtb, dtbT);
    // 10. depthwise causal conv + silu -> packed u32
    conv1d_tiled<<<dim3(4, NCH), 256, 0, stream>>>(zx, m_conv_w, m_conv_b, xbcp);
    // 11-13. SSD chunked scan
    ssd_phaseA<<<SSD_GRID, 256, 0, stream>>>(xbcp, dtbT, m_A_log, Sb, chkT);
    ssd_phaseB<<<512, 64, 0, stream>>>(Sb, chkT);
    ssd_phaseC<<<SSD_GRID, 256, 0, stream>>>(xbcp, zx, dtbT, m_A_log, m_D, Sb, ybuf);
    // 14. RMSNorm (gating fused into phaseC)
    rms_kernel<<<HW, 256, 0, stream>>>(ybuf, m_norm_w);
    // 15. out proj + fused cls LN -> cls0
    gemm_mfma_w<2, 2><<<gemm_grid(1, 329), 256, 0, stream>>>(ybuf, 256, m_out_w, 128,
        NUL, cls_ln_g, cls_ln_b, cls0, 128, HW, 128, 256, 1, 329);
    // 16. cls1
    gemm_mfma_w<1, 2><<<gemm_grid(1, 329), 256, 0, stream>>>(cls0, 128, cls_w1, 128, cls_b1,
        NUL, NUL, cls1, 128, HW, 128, 128, 1, 329);
    // 17. fused cls2+cls3 -> d_out
    cls_tail<<<gemm_grid(1, 329), 256, 0, stream>>>(cls1, cls_w2, cls_b2, cls_w3, cls_b3,
        (float*)d_out, HW, 329);
}

// Round 16
// 421.104 us; speedup vs baseline: 1.2683x; 1.0701x over previous
//
#include <hip/hip_runtime.h>
#include <math.h>

#define HW 21025        // 145*145
#define Hdim 145
#define Wdim 145
#define NBANDS 200
#define CONVH 147
#define CONVHW 21609    // 147*147
#define QC 64
#define NCH 329         // ceil(21025/64)
#define DTP 21056       // padded L for transposed dt
#define SP 72           // short stride for [.][64-k] MFMA tiles
#define SSD_GRID 1344   // 8 * 4 * 42 (xcd-sibling swizzled, tail-guarded)

typedef __attribute__((ext_vector_type(4))) float fv4;
typedef __attribute__((ext_vector_type(8))) short short8;

// ---------------- workspace layout (float offsets) ----------------
#define OFF_XN   ((size_t)0)           // 4,205,000  xn; later cls0
#define OFF_F1   ((size_t)4205000)     // 5,382,400  f1; later y (L x 256)
#define OFF_COMB ((size_t)9587400)     // 4,036,800  comb L x 192
#define OFF_P    ((size_t)13624200)    // 2,691,200  p; later cls1
#define OFF_ZX   ((size_t)16315400)    // 16,231,300 zxbcdt L x 772
#define OFF_XBC  ((size_t)32546700)    // 10,764,800 c1h+c2h first, then xbc packed u32
#define OFF_S    ((size_t)43311500)    // S as bf16 ushort
#define OFF_DT   ((size_t)54092172)    // 84,224 (dt transposed [4][DTP])
#define OFF_CT   ((size_t)54176396)    // 1,316
#define OFF_W    ((size_t)54177712)    // 82,944: packed conv weights (bf16 hi/lo)

__device__ __forceinline__ float gelu_f(float x){
    return 0.5f * x * (1.0f + erff(x * 0.70710678118654752440f));
}
__device__ __forceinline__ float silu_f(float x){
    return x / (1.0f + expf(-x));
}

__device__ __forceinline__ void bf16_split(float x, unsigned short& hs, unsigned short& ls){
    unsigned u = __float_as_uint(x);
    hs = (unsigned short)(u >> 16);
    float hif = __uint_as_float(u & 0xFFFF0000u);
    float lof = x - hif;
    ls = (unsigned short)(__float_as_uint(lof) >> 16);
}
__device__ __forceinline__ unsigned pack2(unsigned short a, unsigned short b){
    return (unsigned)a | ((unsigned)b << 16);
}
__device__ __forceinline__ unsigned packsplit(float x){
    unsigned short hs, ls;
    bf16_split(x, hs, ls);
    return ((unsigned)hs << 16) | (unsigned)ls;
}
__device__ __forceinline__ float unpackf(unsigned u){
    return __uint_as_float(u & 0xFFFF0000u) + __uint_as_float(u << 16);
}
__device__ __forceinline__ unsigned short bf16rnd(float x){
    unsigned u = __float_as_uint(x);
    unsigned r = u + 0x7FFFu + ((u >> 16) & 1u);
    return (unsigned short)(r >> 16);
}
__device__ __forceinline__ float bf16f(unsigned short h){
    return __uint_as_float((unsigned)h << 16);
}
__device__ __forceinline__ void unpack8(const unsigned* p, short8& h8, short8& l8){
    uint4 a = *reinterpret_cast<const uint4*>(p);
    uint4 b = *reinterpret_cast<const uint4*>(p + 4);
    unsigned v0 = a.x, v1 = a.y, v2 = a.z, v3 = a.w;
    unsigned v4 = b.x, v5 = b.y, v6 = b.z, v7 = b.w;
    h8[0]=(short)(v0>>16); l8[0]=(short)(v0&0xFFFFu);
    h8[1]=(short)(v1>>16); l8[1]=(short)(v1&0xFFFFu);
    h8[2]=(short)(v2>>16); l8[2]=(short)(v2&0xFFFFu);
    h8[3]=(short)(v3>>16); l8[3]=(short)(v3&0xFFFFu);
    h8[4]=(short)(v4>>16); l8[4]=(short)(v4&0xFFFFu);
    h8[5]=(short)(v5>>16); l8[5]=(short)(v5&0xFFFFu);
    h8[6]=(short)(v6>>16); l8[6]=(short)(v6&0xFFFFu);
    h8[7]=(short)(v7>>16); l8[7]=(short)(v7&0xFFFFu);
}

// XCD-grouped decode
__device__ __forceinline__ bool gemm_decode(int bid, int NXB, int NYB, int& bx, int& by){
    int m = bid & 7;
    int r = bid >> 3;
    bx = r % NXB;
    by = (r / NXB) * 8 + m;
    return by < NYB;
}
__host__ __forceinline__ int gemm_grid(int NXB, int NYB){ return 8 * ((NYB + 7) / 8) * NXB; }

// ---------------- LayerNorm (pre-LN only) ----------------
template<int ACT>
__global__ void ln_kernel(const float* __restrict__ in, const float* __restrict__ g,
                          const float* __restrict__ b, float* __restrict__ out, int D){
    int row = blockIdx.x, tid = threadIdx.x;
    const float* r = in + (size_t)row * D;
    float s = 0.f, s2 = 0.f;
    for (int i = tid; i < D; i += 256){ float v = r[i]; s += v; s2 += v*v; }
    __shared__ float r1[4], r2[4];
    #pragma unroll
    for (int o = 32; o > 0; o >>= 1){ s += __shfl_down(s, o); s2 += __shfl_down(s2, o); }
    if ((tid & 63) == 0){ r1[tid >> 6] = s; r2[tid >> 6] = s2; }
    __syncthreads();
    float S = r1[0] + r1[1] + r1[2] + r1[3];
    float S2 = r2[0] + r2[1] + r2[2] + r2[3];
    float mean = S / (float)D;
    float var = S2 / (float)D - mean * mean;
    float rs = rsqrtf(fmaxf(var, 0.f) + 1e-5f);
    float* o_ = out + (size_t)row * D;
    for (int i = tid; i < D; i += 256){
        float v = (r[i] - mean) * rs * g[i] + b[i];
        if (ACT == 1) v = gelu_f(v);
        o_[i] = v;
    }
}

// ---------------- wide split-bf16 MFMA GEMM: BN=128, BM=MI*32 ----------------
// ACT: 0 none, 1 gelu, 2 LN, 3 LN+gelu (LN requires N==128, NXB==1)
template<int ACT, int MI>
__global__ __launch_bounds__(256) void gemm_mfma_w(const float* __restrict__ A, int lda,
                                                   const float* __restrict__ B, int ldb,
                                                   const float* __restrict__ bias,
                                                   const float* __restrict__ lng,
                                                   const float* __restrict__ lnb,
                                                   float* __restrict__ C, int ldc,
                                                   int M, int N, int K, int NXB, int NYB){
    const int SA = 40;
    const int BM = MI * 32;
    __shared__ __align__(16) unsigned short Ah[BM * SA], Al[BM * SA];
    __shared__ __align__(16) unsigned short Bh[128 * SA], Bl[128 * SA];
    __shared__ float rs1[2][BM], rs2_[2][BM];
    int bx, by;
    if (!gemm_decode(blockIdx.x, NXB, NYB, bx, by)) return;
    int tid = threadIdx.x;
    int lane = tid & 63, wid = tid >> 6;
    int wy = wid >> 1, wx = wid & 1;
    int bm = by * BM, bn = bx * 128;
    int l15 = lane & 15, g = lane >> 4;

    fv4 acc[MI][4];
    #pragma unroll
    for (int i = 0; i < MI; i++)
        #pragma unroll
        for (int j = 0; j < 4; j++) acc[i][j] = (fv4){0.f,0.f,0.f,0.f};

    int bcol = tid & 127;
    int bk16 = (tid >> 7) * 16;
    bool bcol_ok = (bn + bcol) < N;

    int nK = (K + 31) / 32;
    for (int ks = 0; ks < nK; ks++){
        int k0 = ks * 32;
        #pragma unroll
        for (int f = 0; f < MI; f++){
            int idx = tid * MI + f;
            int row = idx >> 3, qd = idx & 7;
            fv4 v = (fv4){0.f,0.f,0.f,0.f};
            if ((bm + row) < M && (k0 + qd * 4 + 4) <= K)
                v = *reinterpret_cast<const fv4*>(A + (size_t)(bm + row) * lda + k0 + qd * 4);
            unsigned short hs[4], ls[4];
            #pragma unroll
            for (int j = 0; j < 4; j++) bf16_split(v[j], hs[j], ls[j]);
            unsigned off = row * SA + qd * 4;
            *reinterpret_cast<uint2*>(&Ah[off]) = make_uint2(pack2(hs[0],hs[1]), pack2(hs[2],hs[3]));
            *reinterpret_cast<uint2*>(&Al[off]) = make_uint2(pack2(ls[0],ls[1]), pack2(ls[2],ls[3]));
        }
        {
            unsigned short hs[16], ls[16];
            #pragma unroll
            for (int j = 0; j < 16; j++){
                int kk = k0 + bk16 + j;
                float v = (bcol_ok && kk < K) ? B[(size_t)kk * ldb + bn + bcol] : 0.f;
                bf16_split(v, hs[j], ls[j]);
            }
            unsigned off = bcol * SA + bk16;
            *reinterpret_cast<uint4*>(&Bh[off]) = make_uint4(pack2(hs[0],hs[1]), pack2(hs[2],hs[3]),
                                                             pack2(hs[4],hs[5]), pack2(hs[6],hs[7]));
            *reinterpret_cast<uint4*>(&Bh[off + 8]) = make_uint4(pack2(hs[8],hs[9]), pack2(hs[10],hs[11]),
                                                                 pack2(hs[12],hs[13]), pack2(hs[14],hs[15]));
            *reinterpret_cast<uint4*>(&Bl[off]) = make_uint4(pack2(ls[0],ls[1]), pack2(ls[2],ls[3]),
                                                             pack2(ls[4],ls[5]), pack2(ls[6],ls[7]));
            *reinterpret_cast<uint4*>(&Bl[off + 8]) = make_uint4(pack2(ls[8],ls[9]), pack2(ls[10],ls[11]),
                                                                 pack2(ls[12],ls[13]), pack2(ls[14],ls[15]));
        }
        __syncthreads();
        short8 afh[MI], afl[MI], bfh[4], bfl[4];
        #pragma unroll
        for (int mi = 0; mi < MI; mi++){
            unsigned off = (wy * (MI * 16) + mi * 16 + l15) * SA + g * 8;
            afh[mi] = *reinterpret_cast<const short8*>(&Ah[off]);
            afl[mi] = *reinterpret_cast<const short8*>(&Al[off]);
        }
        #pragma unroll
        for (int ni = 0; ni < 4; ni++){
            unsigned off = (wx * 64 + ni * 16 + l15) * SA + g * 8;
            bfh[ni] = *reinterpret_cast<const short8*>(&Bh[off]);
            bfl[ni] = *reinterpret_cast<const short8*>(&Bl[off]);
        }
        #pragma unroll
        for (int mi = 0; mi < MI; mi++)
            #pragma unroll
            for (int ni = 0; ni < 4; ni++){
                acc[mi][ni] = __builtin_amdgcn_mfma_f32_16x16x32_bf16(afh[mi], bfh[ni], acc[mi][ni], 0, 0, 0);
                acc[mi][ni] = __builtin_amdgcn_mfma_f32_16x16x32_bf16(afh[mi], bfl[ni], acc[mi][ni], 0, 0, 0);
                acc[mi][ni] = __builtin_amdgcn_mfma_f32_16x16x32_bf16(afl[mi], bfh[ni], acc[mi][ni], 0, 0, 0);
            }
        __syncthreads();
    }
    float bv[4], lgv[4], lbv[4];
    #pragma unroll
    for (int ni = 0; ni < 4; ni++){
        int cc = bn + wx * 64 + ni * 16 + l15;
        bool ok = cc < N;
        bv[ni]  = (bias && ok) ? bias[cc] : 0.f;
        if (ACT >= 2){ lgv[ni] = ok ? lng[cc] : 1.f; lbv[ni] = ok ? lnb[cc] : 0.f; }
    }
    if (ACT >= 2){
        #pragma unroll
        for (int mi = 0; mi < MI; mi++)
            #pragma unroll
            for (int j = 0; j < 4; j++){
                float s = 0.f, s2 = 0.f;
                #pragma unroll
                for (int ni = 0; ni < 4; ni++){
                    float v = acc[mi][ni][j] + bv[ni];
                    s += v; s2 += v * v;
                }
                #pragma unroll
                for (int o = 1; o < 16; o <<= 1){
                    s += __shfl_xor(s, o); s2 += __shfl_xor(s2, o);
                }
                int row = wy * (MI * 16) + mi * 16 + g * 4 + j;
                if (l15 == 0){ rs1[wx][row] = s; rs2_[wx][row] = s2; }
            }
        __syncthreads();
        #pragma unroll
        for (int mi = 0; mi < MI; mi++)
            #pragma unroll
            for (int j = 0; j < 4; j++){
                int row = wy * (MI * 16) + mi * 16 + g * 4 + j;
                int rr = bm + row;
                if (rr >= M) continue;
                float S = rs1[0][row] + rs1[1][row];
                float S2 = rs2_[0][row] + rs2_[1][row];
                float mean = S / 128.f;
                float var = S2 / 128.f - mean * mean;
                float rsq = rsqrtf(fmaxf(var, 0.f) + 1e-5f);
                #pragma unroll
                for (int ni = 0; ni < 4; ni++){
                    int cc = bn + wx * 64 + ni * 16 + l15;
                    float v = acc[mi][ni][j] + bv[ni];
                    v = (v - mean) * rsq * lgv[ni] + lbv[ni];
                    if (ACT == 3) v = gelu_f(v);
                    C[(size_t)rr * ldc + cc] = v;
                }
            }
    } else {
        #pragma unroll
        for (int mi = 0; mi < MI; mi++)
            #pragma unroll
            for (int ni = 0; ni < 4; ni++){
                int cc = bn + wx * 64 + ni * 16 + l15;
                if (cc >= N) continue;
                #pragma unroll
                for (int j = 0; j < 4; j++){
                    int rr = bm + wy * (MI * 16) + mi * 16 + g * 4 + j;
                    if (rr >= M) continue;
                    float v = acc[mi][ni][j] + bv[ni];
                    if (ACT == 1) v = gelu_f(v);
                    C[(size_t)rr * ldc + cc] = v;
                }
            }
    }
}

// ---------------- fused classifier tail: out = (gelu(A@W2+b2))@W3 + b3 -------------
__global__ __launch_bounds__(256) void cls_tail(const float* __restrict__ A,
                                                const float* __restrict__ W2,
                                                const float* __restrict__ b2,
                                                const float* __restrict__ W3,
                                                const float* __restrict__ b3,
                                                float* __restrict__ out,
                                                int M, int NYB){
    const int SA = 40;
    __shared__ __align__(16) unsigned short Ah[64 * SA], Al[64 * SA];
    __shared__ __align__(16) unsigned short Bh[64 * SA], Bl[64 * SA];
    __shared__ __align__(16) unsigned short A2h[64 * 72], A2l[64 * 72];
    __shared__ __align__(16) unsigned short B3h[32 * 72], B3l[32 * 72];
    int bx, by;
    if (!gemm_decode(blockIdx.x, 1, NYB, bx, by)) return;
    int tid = threadIdx.x;
    int lane = tid & 63, wid = tid >> 6;
    int wy = wid >> 1, wx = wid & 1;
    int bm = by * 64;
    int l15 = lane & 15, g = lane >> 4;

    for (int e = tid; e < 2048; e += 256){
        int n = e >> 6, k = e & 63;
        float v = (n < 17) ? W3[(size_t)k * 17 + n] : 0.f;
        unsigned short hs, ls;
        bf16_split(v, hs, ls);
        B3h[n * 72 + k] = hs;
        B3l[n * 72 + k] = ls;
    }

    fv4 acc[2][2];
    #pragma unroll
    for (int mi = 0; mi < 2; mi++)
        #pragma unroll
        for (int ni = 0; ni < 2; ni++) acc[mi][ni] = (fv4){0.f,0.f,0.f,0.f};

    int bn_t = tid & 63;
    int bk8 = (tid >> 6) * 8;
    #pragma unroll
    for (int ks = 0; ks < 4; ks++){
        int k0 = ks * 32;
        #pragma unroll
        for (int f = 0; f < 2; f++){
            int idx = tid * 2 + f;
            int row = idx >> 3, qd = idx & 7;
            fv4 v = (fv4){0.f,0.f,0.f,0.f};
            if ((bm + row) < M)
                v = *reinterpret_cast<const fv4*>(A + (size_t)(bm + row) * 128 + k0 + qd * 4);
            unsigned short hs[4], ls[4];
            #pragma unroll
            for (int j = 0; j < 4; j++) bf16_split(v[j], hs[j], ls[j]);
            unsigned off = row * SA + qd * 4;
            *reinterpret_cast<uint2*>(&Ah[off]) = make_uint2(pack2(hs[0],hs[1]), pack2(hs[2],hs[3]));
            *reinterpret_cast<uint2*>(&Al[off]) = make_uint2(pack2(ls[0],ls[1]), pack2(ls[2],ls[3]));
        }
        {
            unsigned short hs[8], ls[8];
            #pragma unroll
            for (int j = 0; j < 8; j++){
                int kk = k0 + bk8 + j;
                float v = W2[(size_t)kk * 64 + bn_t];
                bf16_split(v, hs[j], ls[j]);
            }
            unsigned off = bn_t * SA + bk8;
            *reinterpret_cast<uint4*>(&Bh[off]) = make_uint4(pack2(hs[0],hs[1]), pack2(hs[2],hs[3]),
                                                             pack2(hs[4],hs[5]), pack2(hs[6],hs[7]));
            *reinterpret_cast<uint4*>(&Bl[off]) = make_uint4(pack2(ls[0],ls[1]), pack2(ls[2],ls[3]),
                                                             pack2(ls[4],ls[5]), pack2(ls[6],ls[7]));
        }
        __syncthreads();
        short8 afh[2], afl[2], bfh[2], bfl[2];
        #pragma unroll
        for (int mi = 0; mi < 2; mi++){
            unsigned off = (wy * 32 + mi * 16 + l15) * SA + g * 8;
            afh[mi] = *reinterpret_cast<const short8*>(&Ah[off]);
            afl[mi] = *reinterpret_cast<const short8*>(&Al[off]);
        }
        #pragma unroll
        for (int ni = 0; ni < 2; ni++){
            unsigned off = (wx * 32 + ni * 16 + l15) * SA + g * 8;
            bfh[ni] = *reinterpret_cast<const short8*>(&Bh[off]);
            bfl[ni] = *reinterpret_cast<const short8*>(&Bl[off]);
        }
        #pragma unroll
        for (int mi = 0; mi < 2; mi++)
            #pragma unroll
            for (int ni = 0; ni < 2; ni++){
                acc[mi][ni] = __builtin_amdgcn_mfma_f32_16x16x32_bf16(afh[mi], bfh[ni], acc[mi][ni], 0, 0, 0);
                acc[mi][ni] = __builtin_amdgcn_mfma_f32_16x16x32_bf16(afh[mi], bfl[ni], acc[mi][ni], 0, 0, 0);
                acc[mi][ni] = __builtin_amdgcn_mfma_f32_16x16x32_bf16(afl[mi], bfh[ni], acc[mi][ni], 0, 0, 0);
            }
        __syncthreads();
    }
    #pragma unroll
    for (int mi = 0; mi < 2; mi++)
        #pragma unroll
        for (int ni = 0; ni < 2; ni++){
            int col = wx * 32 + ni * 16 + l15;
            float bv = b2[col];
            #pragma unroll
            for (int j = 0; j < 4; j++){
                int row = wy * 32 + mi * 16 + g * 4 + j;
                float v = gelu_f(acc[mi][ni][j] + bv);
                unsigned short hs, ls;
                bf16_split(v, hs, ls);
                A2h[row * 72 + col] = hs;
                A2l[row * 72 + col] = ls;
            }
        }
    __syncthreads();
    fv4 acc3[2];
    acc3[0] = (fv4){0.f,0.f,0.f,0.f};
    acc3[1] = (fv4){0.f,0.f,0.f,0.f};
    #pragma unroll
    for (int ks = 0; ks < 2; ks++){
        unsigned aoff = (wid * 16 + l15) * 72 + ks * 32 + g * 8;
        short8 a2h = *reinterpret_cast<const short8*>(&A2h[aoff]);
        short8 a2l = *reinterpret_cast<const short8*>(&A2l[aoff]);
        #pragma unroll
        for (int ni = 0; ni < 2; ni++){
            unsigned boff = (ni * 16 + l15) * 72 + ks * 32 + g * 8;
            short8 b3h_ = *reinterpret_cast<const short8*>(&B3h[boff]);
            short8 b3l_ = *reinterpret_cast<const short8*>(&B3l[boff]);
            acc3[ni] = __builtin_amdgcn_mfma_f32_16x16x32_bf16(a2h, b3h_, acc3[ni], 0, 0, 0);
            acc3[ni] = __builtin_amdgcn_mfma_f32_16x16x32_bf16(a2h, b3l_, acc3[ni], 0, 0, 0);
            acc3[ni] = __builtin_amdgcn_mfma_f32_16x16x32_bf16(a2l, b3h_, acc3[ni], 0, 0, 0);
        }
    }
    #pragma unroll
    for (int ni = 0; ni < 2; ni++){
        int col = ni * 16 + l15;
        if (col >= 17) continue;
        float bv = b3[col];
        #pragma unroll
        for (int j = 0; j < 4; j++){
            int row = bm + wid * 16 + g * 4 + j;
            if (row >= M) continue;
            out[(size_t)row * 17 + col] = acc3[ni][j] + bv;
        }
    }
}

// ---------------- dt from p ----------------
__global__ __launch_bounds__(256) void dt_from_p(const float* __restrict__ p,
                                                 const float* __restrict__ w,
                                                 const float* __restrict__ dtb,
                                                 float* __restrict__ dtbT){
    __shared__ float wl[512];
    int tid = threadIdx.x;
    for (int i = tid; i < 512; i += 256){
        int k = i >> 2, h = i & 3;
        wl[i] = w[(size_t)k * 772 + 768 + h];
    }
    __syncthreads();
    int t = blockIdx.x * 64 + (tid >> 2);
    int h = tid & 3;
    if (t >= HW) return;
    const float* pr = p + (size_t)t * 128;
    float s = 0.f;
    for (int k = 0; k < 128; k += 4){
        fv4 v = *reinterpret_cast<const fv4*>(pr + k);
        s += v[0]*wl[k*4+h] + v[1]*wl[(k+1)*4+h] + v[2]*wl[(k+2)*4+h] + v[3]*wl[(k+3)*4+h];
    }
    s += dtb[h];
    dtbT[h * DTP + t] = (s > 20.f) ? s : log1pf(expf(s));
}

// ---------------- conv weight prepack ----------------
template<int IC, int OC, int NCHUNK>
__global__ void prep_w(const float* __restrict__ w, unsigned short* __restrict__ Wh,
                       unsigned short* __restrict__ Wl){
    const int KP = NCHUNK * 288;
    int idx = blockIdx.x * 256 + threadIdx.x;
    if (idx >= OC * KP) return;
    int o = idx / KP, k = idx % KP;
    int ch = k / 288, rest = k % 288, t = rest / 32, c = rest & 31;
    int ci = ch * 32 + c;
    float v = (ci < IC) ? w[((size_t)o * IC + ci) * 9 + t] : 0.f;
    unsigned short hs, ls;
    bf16_split(v, hs, ls);
    Wh[idx] = hs; Wl[idx] = ls;
}

// ---------------- MFMA direct conv 3x3 ----------------
template<int IC, int OC, int PAD, int NCHUNK, int NFRAG>
__global__ __launch_bounds__(256) void conv_mfma(const float* __restrict__ in,
                                                 int inH, int inW,
                                                 const unsigned short* __restrict__ Wh,
                                                 const unsigned short* __restrict__ Wl,
                                                 const float* __restrict__ bias,
                                                 float* __restrict__ out){
    const int KP = NCHUNK * 288;
    const int CST = 40;
    __shared__ __align__(16) unsigned short Xh[3 * 68 * CST], Xl[3 * 68 * CST];
    int y = blockIdx.y;
    int x0 = blockIdx.x * 64;
    int tid = threadIdx.x;
    int lane = tid & 63, wid = tid >> 6;
    int wy = wid >> 1, wx = wid & 1;
    int l15 = lane & 15, g = lane >> 4;

    fv4 acc[2][NFRAG];
    #pragma unroll
    for (int mi = 0; mi < 2; mi++)
        #pragma unroll
        for (int ni = 0; ni < NFRAG; ni++) acc[mi][ni] = (fv4){0.f,0.f,0.f,0.f};

    for (int ch = 0; ch < NCHUNK; ch++){
        int ci0 = ch * 32;
        if (ch > 0) __syncthreads();
        for (int e = tid; e < 3 * 68 * 8; e += 256){
            int qd = e & 7;
            int c  = (e >> 3) % 68;
            int r  = e / 544;
            int iy = y - PAD + r, ix = x0 - PAD + c;
            fv4 v = (fv4){0.f,0.f,0.f,0.f};
            if ((unsigned)iy < (unsigned)inH && (unsigned)ix < (unsigned)inW &&
                (ci0 + qd * 4 + 4) <= IC)
                v = *reinterpret_cast<const fv4*>(in + ((size_t)iy * inW + ix) * IC + ci0 + qd * 4);
            unsigned short hs[4], ls[4];
            #pragma unroll
            for (int j = 0; j < 4; j++) bf16_split(v[j], hs[j], ls[j]);
            unsigned off = (r * 68 + c) * CST + qd * 4;
            *reinterpret_cast<uint2*>(&Xh[off]) = make_uint2(pack2(hs[0],hs[1]), pack2(hs[2],hs[3]));
            *reinterpret_cast<uint2*>(&Xl[off]) = make_uint2(pack2(ls[0],ls[1]), pack2(ls[2],ls[3]));
        }
        __syncthreads();
        #pragma unroll
        for (int t = 0; t < 9; t++){
            int ky = t / 3, kx = t % 3;
            short8 ah[2], al[2], bh[NFRAG], bl[NFRAG];
            #pragma unroll
            for (int mi = 0; mi < 2; mi++){
                unsigned off = (ky * 68 + wy * 32 + mi * 16 + l15 + kx) * CST + g * 8;
                ah[mi] = *reinterpret_cast<const short8*>(&Xh[off]);
                al[mi] = *reinterpret_cast<const short8*>(&Xl[off]);
            }
            #pragma unroll
            for (int ni = 0; ni < NFRAG; ni++){
                int oc = wx * (16 * NFRAG) + ni * 16 + l15;
                size_t woff = (size_t)oc * KP + ch * 288 + t * 32 + g * 8;
                bh[ni] = *reinterpret_cast<const short8*>(&Wh[woff]);
                bl[ni] = *reinterpret_cast<const short8*>(&Wl[woff]);
            }
            #pragma unroll
            for (int mi = 0; mi < 2; mi++)
                #pragma unroll
                for (int ni = 0; ni < NFRAG; ni++){
                    acc[mi][ni] = __builtin_amdgcn_mfma_f32_16x16x32_bf16(ah[mi], bh[ni], acc[mi][ni], 0, 0, 0);
                    acc[mi][ni] = __builtin_amdgcn_mfma_f32_16x16x32_bf16(ah[mi], bl[ni], acc[mi][ni], 0, 0, 0);
                    acc[mi][ni] = __builtin_amdgcn_mfma_f32_16x16x32_bf16(al[mi], bh[ni], acc[mi][ni], 0, 0, 0);
                }
        }
    }
    #pragma unroll
    for (int mi = 0; mi < 2; mi++)
        #pragma unroll
        for (int ni = 0; ni < NFRAG; ni++){
            int oc = wx * (16 * NFRAG) + ni * 16 + l15;
            float bv = bias[oc];
            #pragma unroll
            for (int j = 0; j < 4; j++){
                int x = x0 + wy * 32 + mi * 16 + g * 4 + j;
                if (x >= CONVH) continue;
                out[((size_t)y * CONVH + x) * OC + oc] = gelu_f(acc[mi][ni][j] + bv);
            }
        }
}

// ---------------- adaptive pool ----------------
__global__ void pool_kernel(const float* __restrict__ c2, float* __restrict__ comb){
    int idx = blockIdx.x * 256 + threadIdx.x;
    if (idx >= HW * 64) return;
    int o = idx & 63;
    int pix = idx >> 6;
    int xo = pix % Wdim, yo = pix / Wdim;
    int ys = yo * CONVH / Hdim, ye = ((yo + 1) * CONVH + Hdim - 1) / Hdim;
    int xs = xo * CONVH / Wdim, xe = ((xo + 1) * CONVH + Wdim - 1) / Wdim;
    float s = 0.f;
    for (int yy = ys; yy < ye; yy++)
        for (int xx = xs; xx < xe; xx++)
            s += c2[((size_t)yy * CONVH + xx) * 64 + o];
    comb[(size_t)pix * 192 + 128 + o] = s / (float)((ye - ys) * (xe - xs));
}

// ---------------- conv1d + silu -> packed u32 ----------------
__global__ __launch_bounds__(256) void conv1d_tiled(const float* __restrict__ zx,
                                                    const float* __restrict__ w,
                                                    const float* __restrict__ b,
                                                    unsigned* __restrict__ xbcp){
    __shared__ float xs[67 * 128];
    __shared__ float wc[4 * 128];
    __shared__ float bc[128];
    int t0 = blockIdx.y * 64;
    int c0 = blockIdx.x * 128;
    int tid = threadIdx.x;
    for (int e = tid; e < 67 * 128; e += 256){
        int rr = e >> 7, cc = e & 127;
        int t = t0 - 3 + rr;
        xs[e] = (t >= 0 && t < HW) ? zx[(size_t)t * 772 + 256 + c0 + cc] : 0.f;
    }
    if (tid < 128){
        bc[tid] = b[c0 + tid];
        #pragma unroll
        for (int k = 0; k < 4; k++) wc[k * 128 + tid] = w[(c0 + tid) * 4 + k];
    }
    __syncthreads();
    for (int e = tid; e < 64 * 128; e += 256){
        int tt = e >> 7, cc = e & 127;
        if (t0 + tt >= HW) continue;
        float acc = bc[cc];
        #pragma unroll
        for (int k = 0; k < 4; k++) acc += xs[(tt + k) * 128 + cc] * wc[k * 128 + cc];
        xbcp[(size_t)(t0 + tt) * 512 + c0 + cc] = packsplit(silu_f(acc));
    }
}

// ---------------- chunk cumsum (wave 0) ----------------
__device__ __forceinline__ void chunk_cumsum_t(const float* __restrict__ dtbT, int t0, int Q,
                                               int h, const float* __restrict__ A_log,
                                               float* cum, float* dth){
    int tid = threadIdx.x;
    if (tid < 64){
        float d = (tid < Q) ? dtbT[h * DTP + t0 + tid] : 0.f;
        dth[tid] = d;
        float A = -expf(A_log[h]);
        float a = d * A;
        #pragma unroll
        for (int off = 1; off < 64; off <<= 1){
            float u = __shfl_up(a, off);
            if (tid >= off) a += u;
        }
        cum[tid] = a;
    }
    __syncthreads();
}

__device__ __forceinline__ bool ssd_decode(int bid, int& c, int& h){
    int m = bid & 7, rest = bid >> 3;
    h = rest & 3;
    c = (rest >> 2) * 8 + m;
    return c < NCH;
}

// ---------------- SSD phase A (MFMA; B as bf16-hi only — S is bf16 anyway) ---------
__global__ __launch_bounds__(256) void ssd_phaseA(const unsigned* __restrict__ xbcp,
                                                  const float* __restrict__ dtbT,
                                                  const float* __restrict__ A_log,
                                                  unsigned short* __restrict__ Sb,
                                                  float* __restrict__ chunkT){
    __shared__ __align__(16) unsigned short BTh[128 * SP];                // B^T hi [n][s]
    __shared__ __align__(16) unsigned short XTh[64 * SP],  XTl[64 * SP];  // (Xw)^T [p][s]
    __shared__ float cum[64], dth[64], wln[64];
    int c, h;
    if (!ssd_decode(blockIdx.x, c, h)) return;
    int t0 = c * QC, Q = min(QC, HW - t0);
    int tid = threadIdx.x;
    chunk_cumsum_t(dtbT, t0, Q, h, A_log, cum, dth);
    float T = cum[Q - 1];
    if (tid == 0) chunkT[c * 4 + h] = T;
    if (tid < 64) wln[tid] = (tid < Q) ? __expf(T - cum[tid]) * dth[tid] : 0.f;
    __syncthreads();
    for (int e2 = tid; e2 < 4096; e2 += 256){
        int nn = e2 & 127, sp = e2 >> 7;
        int s0 = 2 * sp;
        unsigned v0 = (s0 < Q)     ? xbcp[(size_t)(t0 + s0) * 512 + 256 + nn] : 0u;
        unsigned v1 = (s0 + 1 < Q) ? xbcp[(size_t)(t0 + s0 + 1) * 512 + 256 + nn] : 0u;
        *reinterpret_cast<unsigned*>(&BTh[nn * SP + s0]) = pack2((unsigned short)(v0 >> 16), (unsigned short)(v1 >> 16));
    }
    for (int e2 = tid; e2 < 2048; e2 += 256){
        int pp = e2 & 63, sp = e2 >> 6;
        int s0 = 2 * sp;
        float v0 = (s0 < Q)     ? unpackf(xbcp[(size_t)(t0 + s0) * 512 + h * 64 + pp]) * wln[s0] : 0.f;
        float v1 = (s0 + 1 < Q) ? unpackf(xbcp[(size_t)(t0 + s0 + 1) * 512 + h * 64 + pp]) * wln[s0 + 1] : 0.f;
        unsigned short h0, l0, h1, l1;
        bf16_split(v0, h0, l0); bf16_split(v1, h1, l1);
        *reinterpret_cast<unsigned*>(&XTh[pp * SP + s0]) = pack2(h0, h1);
        *reinterpret_cast<unsigned*>(&XTl[pp * SP + s0]) = pack2(l0, l1);
    }
    __syncthreads();
    int lane = tid & 63, wid = tid >> 6;
    int wy = wid >> 1, wx = wid & 1;
    int l15 = lane & 15, g = lane >> 4;
    fv4 acc[2][4];
    #pragma unroll
    for (int mi = 0; mi < 2; mi++)
        #pragma unroll
        for (int ni = 0; ni < 4; ni++) acc[mi][ni] = (fv4){0.f,0.f,0.f,0.f};
    #pragma unroll
    for (int ks = 0; ks < 2; ks++){
        short8 ah[2], al[2], bh_[4];
        #pragma unroll
        for (int mi = 0; mi < 2; mi++){
            unsigned off = (wy * 32 + mi * 16 + l15) * SP + ks * 32 + g * 8;
            ah[mi] = *reinterpret_cast<const short8*>(&XTh[off]);
            al[mi] = *reinterpret_cast<const short8*>(&XTl[off]);
        }
        #pragma unroll
        for (int ni = 0; ni < 4; ni++){
            unsigned off = (wx * 64 + ni * 16 + l15) * SP + ks * 32 + g * 8;
            bh_[ni] = *reinterpret_cast<const short8*>(&BTh[off]);
        }
        #pragma unroll
        for (int mi = 0; mi < 2; mi++)
            #pragma unroll
            for (int ni = 0; ni < 4; ni++){
                acc[mi][ni] = __builtin_amdgcn_mfma_f32_16x16x32_bf16(ah[mi], bh_[ni], acc[mi][ni], 0, 0, 0);
                acc[mi][ni] = __builtin_amdgcn_mfma_f32_16x16x32_bf16(al[mi], bh_[ni], acc[mi][ni], 0, 0, 0);
            }
    }
    size_t sb = (size_t)(c * 4 + h) * 8192;
    #pragma unroll
    for (int mi = 0; mi < 2; mi++)
        #pragma unroll
        for (int ni = 0; ni < 4; ni++)
            #pragma unroll
            for (int j = 0; j < 4; j++){
                int p = wy * 32 + mi * 16 + g * 4 + j;
                int n = wx * 64 + ni * 16 + l15;
                Sb[sb + p * 128 + n] = bf16rnd(acc[mi][ni][j]);
            }
}

// ---------------- SSD phase B: prefix over chunks (bf16 S, 512x64 grid) ------------
__global__ __launch_bounds__(64) void ssd_phaseB(unsigned short* __restrict__ Sb,
                                                 const float* __restrict__ chunkT){
    __shared__ float e[NCH];
    int tid = threadIdx.x;
    int idx = blockIdx.x * 64 + tid;
    int h = idx >> 13, pn = idx & 8191;
    for (int c = tid; c < NCH; c += 64) e[c] = __expf(chunkT[c * 4 + h]);
    __syncthreads();
    #define ADDR_(cc) Sb[((size_t)((cc) * 4 + h)) * 8192 + pn]
    unsigned short r0 = ADDR_(0), r1 = ADDR_(1), r2 = ADDR_(2), r3 = ADDR_(3);
    float s = 0.f;
    int c = 0;
    for (; c + 8 <= NCH; c += 4){
        unsigned short n0 = ADDR_(c + 4), n1 = ADDR_(c + 5), n2 = ADDR_(c + 6), n3 = ADDR_(c + 7);
        ADDR_(c) = bf16rnd(s);     s = fmaf(s, e[c],     bf16f(r0));
        ADDR_(c + 1) = bf16rnd(s); s = fmaf(s, e[c + 1], bf16f(r1));
        ADDR_(c + 2) = bf16rnd(s); s = fmaf(s, e[c + 2], bf16f(r2));
        ADDR_(c + 3) = bf16rnd(s); s = fmaf(s, e[c + 3], bf16f(r3));
        r0 = n0; r1 = n1; r2 = n2; r3 = n3;
    }
    for (; c < NCH; c++){
        unsigned short nx = (c + 4 < NCH) ? ADDR_(c + 4) : (unsigned short)0;
        float loc = bf16f(r0); r0 = r1; r1 = r2; r2 = r3; r3 = nx;
        ADDR_(c) = bf16rnd(s);
        s = fmaf(s, e[c], loc);
    }
    #undef ADDR_
}

// ---------------- SSD phase C (MFMA, bf16 S direct, bf16 P, fused z-gating) --------
__global__ __launch_bounds__(256) void ssd_phaseC(const unsigned* __restrict__ xbcp,
                                                  const float* __restrict__ zx,
                                                  const float* __restrict__ dtbT,
                                                  const float* __restrict__ A_log,
                                                  const float* __restrict__ Dvec,
                                                  const unsigned short* __restrict__ Sb,
                                                  float* __restrict__ y){
    __shared__ __align__(16) unsigned short U0[64 * SP];                 // P bf16 [t][s]
    __shared__ __align__(16) unsigned short U1h[64 * SP], U1l[64 * SP];  // X^T [p][s]
    __shared__ float cum[64], dth[64];
    int c, h;
    if (!ssd_decode(blockIdx.x, c, h)) return;
    int t0 = c * QC, Q = min(QC, HW - t0);
    int tid = threadIdx.x;
    chunk_cumsum_t(dtbT, t0, Q, h, A_log, cum, dth);
    int lane = tid & 63, wid = tid >> 6;
    int wy = wid >> 1, wx = wid & 1;
    int l15 = lane & 15, g = lane >> 4;

    int trow[2], srow[2], prow[2];
    #pragma unroll
    for (int i = 0; i < 2; i++){
        trow[i] = min(t0 + wy * 32 + i * 16 + l15, HW - 1);
        srow[i] = min(t0 + wx * 32 + i * 16 + l15, HW - 1);
        prow[i] = wx * 32 + i * 16 + l15;
    }

    fv4 accG[2][2], accA[2][2];
    #pragma unroll
    for (int mi = 0; mi < 2; mi++)
        #pragma unroll
        for (int ni = 0; ni < 2; ni++){ accG[mi][ni] = (fv4){0.f,0.f,0.f,0.f}; accA[mi][ni] = (fv4){0.f,0.f,0.f,0.f}; }

    const unsigned short* Sbase = Sb + (size_t)(c * 4 + h) * 8192;
    #pragma unroll
    for (int k0 = 0; k0 < 128; k0 += 32){
        short8 ah[2], al[2], bh[2], bl[2], sh[2];
        #pragma unroll
        for (int mi = 0; mi < 2; mi++)
            unpack8(xbcp + (size_t)trow[mi] * 512 + 384 + k0 + g * 8, ah[mi], al[mi]);
        #pragma unroll
        for (int ni = 0; ni < 2; ni++){
            unpack8(xbcp + (size_t)srow[ni] * 512 + 256 + k0 + g * 8, bh[ni], bl[ni]);
            sh[ni] = *reinterpret_cast<const short8*>(Sbase + prow[ni] * 128 + k0 + g * 8);
        }
        #pragma unroll
        for (int mi = 0; mi < 2; mi++)
            #pragma unroll
            for (int ni = 0; ni < 2; ni++){
                accG[mi][ni] = __builtin_amdgcn_mfma_f32_16x16x32_bf16(ah[mi], bh[ni], accG[mi][ni], 0, 0, 0);
                accG[mi][ni] = __builtin_amdgcn_mfma_f32_16x16x32_bf16(ah[mi], bl[ni], accG[mi][ni], 0, 0, 0);
                accG[mi][ni] = __builtin_amdgcn_mfma_f32_16x16x32_bf16(al[mi], bh[ni], accG[mi][ni], 0, 0, 0);
                accA[mi][ni] = __builtin_amdgcn_mfma_f32_16x16x32_bf16(ah[mi], sh[ni], accA[mi][ni], 0, 0, 0);
                accA[mi][ni] = __builtin_amdgcn_mfma_f32_16x16x32_bf16(al[mi], sh[ni], accA[mi][ni], 0, 0, 0);
            }
    }
    #pragma unroll
    for (int mi = 0; mi < 2; mi++)
        #pragma unroll
        for (int ni = 0; ni < 2; ni++)
            #pragma unroll
            for (int j = 0; j < 4; j++){
                int t = wy * 32 + mi * 16 + g * 4 + j;
                int s = wx * 32 + ni * 16 + l15;
                float pv = 0.f;
                if (s <= t && s < Q)
                    pv = accG[mi][ni][j] * __expf(cum[t] - cum[s]) * dth[s];
                U0[t * SP + s] = bf16rnd(pv);
            }
    for (int e2 = tid; e2 < 2048; e2 += 256){
        int pp = e2 & 63, sp = e2 >> 6;
        int s0 = 2 * sp;
        unsigned v0 = (s0 < Q)     ? xbcp[(size_t)(t0 + s0) * 512 + h * 64 + pp] : 0u;
        unsigned v1 = (s0 + 1 < Q) ? xbcp[(size_t)(t0 + s0 + 1) * 512 + h * 64 + pp] : 0u;
        *reinterpret_cast<unsigned*>(&U1h[pp * SP + s0]) = pack2((unsigned short)(v0 >> 16), (unsigned short)(v1 >> 16));
        *reinterpret_cast<unsigned*>(&U1l[pp * SP + s0]) = pack2((unsigned short)(v0 & 0xFFFFu), (unsigned short)(v1 & 0xFFFFu));
    }
    __syncthreads();
    fv4 accY[2][2];
    #pragma unroll
    for (int mi = 0; mi < 2; mi++)
        #pragma unroll
        for (int ni = 0; ni < 2; ni++)
            #pragma unroll
            for (int j = 0; j < 4; j++){
                int t = wy * 32 + mi * 16 + g * 4 + j;
                accY[mi][ni][j] = __expf(cum[t]) * accA[mi][ni][j];
            }
    #pragma unroll
    for (int kk = 0; kk < 2; kk++){
        short8 ph[2], xh[2], xl[2];
        #pragma unroll
        for (int mi = 0; mi < 2; mi++){
            unsigned off = (wy * 32 + mi * 16 + l15) * SP + kk * 32 + g * 8;
            ph[mi] = *reinterpret_cast<const short8*>(&U0[off]);
        }
        #pragma unroll
        for (int ni = 0; ni < 2; ni++){
            unsigned off = (wx * 32 + ni * 16 + l15) * SP + kk * 32 + g * 8;
            xh[ni] = *reinterpret_cast<const short8*>(&U1h[off]);
            xl[ni] = *reinterpret_cast<const short8*>(&U1l[off]);
        }
        #pragma unroll
        for (int mi = 0; mi < 2; mi++)
            #pragma unroll
            for (int ni = 0; ni < 2; ni++){
                accY[mi][ni] = __builtin_amdgcn_mfma_f32_16x16x32_bf16(ph[mi], xh[ni], accY[mi][ni], 0, 0, 0);
                accY[mi][ni] = __builtin_amdgcn_mfma_f32_16x16x32_bf16(ph[mi], xl[ni], accY[mi][ni], 0, 0, 0);
            }
    }
    float Dh = Dvec[h];
    #pragma unroll
    for (int mi = 0; mi < 2; mi++)
        #pragma unroll
        for (int ni = 0; ni < 2; ni++)
            #pragma unroll
            for (int j = 0; j < 4; j++){
                int t = wy * 32 + mi * 16 + g * 4 + j;
                if (t >= Q) continue;
                int p = wx * 32 + ni * 16 + l15;
                float xv = unpackf(xbcp[(size_t)(t0 + t) * 512 + h * 64 + p]);
                float zv = zx[(size_t)(t0 + t) * 772 + h * 64 + p];
                y[(size_t)(t0 + t) * 256 + h * 64 + p] = (accY[mi][ni][j] + Dh * xv) * silu_f(zv);
            }
}

// ---------------- RMSNorm (gating already applied in phaseC) ----------------
__global__ void rms_kernel(float* __restrict__ y, const float* __restrict__ nw){
    int row = blockIdx.x, tid = threadIdx.x;
    float v = y[(size_t)row * 256 + tid];
    float s = v * v;
    __shared__ float r1[4];
    #pragma unroll
    for (int o = 32; o > 0; o >>= 1) s += __shfl_down(s, o);
    if ((tid & 63) == 0) r1[tid >> 6] = s;
    __syncthreads();
    float S = r1[0] + r1[1] + r1[2] + r1[3];
    float rs = rsqrtf(S / 256.f + 1e-5f);
    y[(size_t)row * 256 + tid] = v * rs * nw[tid];
}

extern "C" void kernel_launch(void* const* d_in, const int* in_sizes, int n_in,
                              void* d_out, int out_size, void* d_ws, size_t ws_size,
                              hipStream_t stream){
    (void)in_sizes; (void)n_in; (void)out_size; (void)ws_size;
    const float* x        = (const float*)d_in[0];
    const float* ln_pre_g = (const float*)d_in[1];
    const float* ln_pre_b = (const float*)d_in[2];
    const float* fe_w1    = (const float*)d_in[3];
    const float* fe_b1    = (const float*)d_in[4];
    const float* fe_w2    = (const float*)d_in[5];
    const float* fe_b2    = (const float*)d_in[6];
    const float* cv_w1    = (const float*)d_in[7];
    const float* cv_b1    = (const float*)d_in[8];
    const float* cv_w2    = (const float*)d_in[9];
    const float* cv_b2    = (const float*)d_in[10];
    const float* mp_w     = (const float*)d_in[11];
    const float* mp_b     = (const float*)d_in[12];
    const float* mp_ln_g  = (const float*)d_in[13];
    const float* mp_ln_b  = (const float*)d_in[14];
    const float* m_in_w   = (const float*)d_in[15];
    const float* m_conv_w = (const float*)d_in[16];
    const float* m_conv_b = (const float*)d_in[17];
    const float* m_dtb    = (const float*)d_in[18];
    const float* m_A_log  = (const float*)d_in[19];
    const float* m_D      = (const float*)d_in[20];
    const float* m_norm_w = (const float*)d_in[21];
    const float* m_out_w  = (const float*)d_in[22];
    const float* cls_ln_g = (const float*)d_in[23];
    const float* cls_ln_b = (const float*)d_in[24];
    const float* cls_w1   = (const float*)d_in[25];
    const float* cls_b1   = (const float*)d_in[26];
    const float* cls_w2   = (const float*)d_in[27];
    const float* cls_b2   = (const float*)d_in[28];
    const float* cls_w3   = (const float*)d_in[29];
    const float* cls_b3   = (const float*)d_in[30];

    float* ws   = (float*)d_ws;
    float* xn   = ws + OFF_XN;
    float* f1   = ws + OFF_F1;
    float* comb = ws + OFF_COMB;
    float* p    = ws + OFF_P;
    float* zx   = ws + OFF_ZX;
    unsigned* xbcp = (unsigned*)(ws + OFF_XBC);
    unsigned short* Sb = (unsigned short*)(ws + OFF_S);
    float* dtbT = ws + OFF_DT;
    float* chkT = ws + OFF_CT;
    float* c1h  = ws + OFF_XBC;                    // before xbcp live
    float* c2h  = ws + OFF_XBC + 691488;
    float* ybuf = ws + OFF_F1;
    float* cls0 = ws + OFF_XN;
    float* cls1 = ws + OFF_P;
    unsigned short* W1h = (unsigned short*)(ws + OFF_W);
    unsigned short* W1l = (unsigned short*)(ws + OFF_W + 32256);
    unsigned short* W2h = (unsigned short*)(ws + OFF_W + 64512);
    unsigned short* W2l = (unsigned short*)(ws + OFF_W + 73728);
    const float* NUL = (const float*)nullptr;

    // 0. conv weight prepack (tiny)
    prep_w<200, 32, 7><<<(32 * 2016 + 255) / 256, 256, 0, stream>>>(cv_w1, W1h, W1l);
    prep_w<32, 64, 1><<<(64 * 288 + 255) / 256, 256, 0, stream>>>(cv_w2, W2h, W2l);
    // 1. pre-LN
    ln_kernel<0><<<HW, 256, 0, stream>>>(x, ln_pre_g, ln_pre_b, xn, NBANDS);
    // 2-3. feature MLP (f -> comb[:, :128])  — BM reduced for occupancy
    gemm_mfma_w<1, 2><<<gemm_grid(2, 329), 256, 0, stream>>>(xn, 200, fe_w1, 256, fe_b1,
        NUL, NUL, f1, 256, HW, 256, 200, 2, 329);
    gemm_mfma_w<1, 1><<<gemm_grid(1, 658), 256, 0, stream>>>(f1, 256, fe_w2, 128, fe_b2,
        NUL, NUL, comb, 192, HW, 128, 256, 1, 658);
    // 4. conv1 (MFMA implicit-im2col): 200->32, pad 2
    conv_mfma<200, 32, 2, 7, 1><<<dim3(3, CONVH), 256, 0, stream>>>(xn, Hdim, Wdim, W1h, W1l, cv_b1, c1h);
    // 5. conv2 (MFMA): 32->64, pad 1
    conv_mfma<32, 64, 1, 1, 2><<<dim3(3, CONVH), 256, 0, stream>>>(c1h, CONVH, CONVH, W2h, W2l, cv_b2, c2h);
    // 6. adaptive pool -> comb[:, 128:192]
    pool_kernel<<<(HW * 64 + 255) / 256, 256, 0, stream>>>(c2h, comb);
    // 7. mid projection + fused LN + GELU -> p
    gemm_mfma_w<3, 1><<<gemm_grid(1, 658), 256, 0, stream>>>(comb, 192, mp_w, 128, mp_b,
        mp_ln_g, mp_ln_b, p, 128, HW, 128, 192, 1, 658);
    // 8. mamba in_proj (cols 0..768 only)
    gemm_mfma_w<0, 4><<<gemm_grid(6, 165), 256, 0, stream>>>(p, 128, m_in_w, 772,
        NUL, NUL, NUL, zx, 772, HW, 768, 128, 6, 165);
    // 9. dt from p
    dt_from_p<<<(HW + 63) / 64, 256, 0, stream>>>(p, m_in_w, m_dtb, dtbT);
    // 10. depthwise causal conv + silu -> packed u32
    conv1d_tiled<<<dim3(4, NCH), 256, 0, stream>>>(zx, m_conv_w, m_conv_b, xbcp);
    // 11-13. SSD chunked scan
    ssd_phaseA<<<SSD_GRID, 256, 0, stream>>>(xbcp, dtbT, m_A_log, Sb, chkT);
    ssd_phaseB<<<512, 64, 0, stream>>>(Sb, chkT);
    ssd_phaseC<<<SSD_GRID, 256, 0, stream>>>(xbcp, zx, dtbT, m_A_log, m_D, Sb, ybuf);
    // 14. RMSNorm (gating fused into phaseC)
    rms_kernel<<<HW, 256, 0, stream>>>(ybuf, m_norm_w);
    // 15. out proj + fused cls LN -> cls0
    gemm_mfma_w<2, 1><<<gemm_grid(1, 658), 256, 0, stream>>>(ybuf, 256, m_out_w, 128,
        NUL, cls_ln_g, cls_ln_b, cls0, 128, HW, 128, 256, 1, 658);
    // 16. cls1
    gemm_mfma_w<1, 1><<<gemm_grid(1, 658), 256, 0, stream>>>(cls0, 128, cls_w1, 128, cls_b1,
        NUL, NUL, cls1, 128, HW, 128, 128, 1, 658);
    // 17. fused cls2+cls3 -> d_out
    cls_tail<<<gemm_grid(1, 329), 256, 0, stream>>>(cls1, cls_w2, cls_b2, cls_w3, cls_b3,
        (float*)d_out, HW, 329);
}

// Round 17
// 420.327 us; speedup vs baseline: 1.2707x; 1.0018x over previous
//
#include <hip/hip_runtime.h>
#include <math.h>

#define HW 21025        // 145*145
#define Hdim 145
#define Wdim 145
#define NBANDS 200
#define CONVH 147
#define CONVHW 21609    // 147*147
#define QC 64
#define NCH 329         // ceil(21025/64)
#define DTP 21056       // padded L for transposed dt
#define SP 72           // short stride for [.][64-k] MFMA tiles
#define SSD_GRID 1344   // 8 * 4 * 42 (xcd-sibling swizzled, tail-guarded)

typedef __attribute__((ext_vector_type(4))) float fv4;
typedef __attribute__((ext_vector_type(8))) short short8;

// ---------------- workspace layout (float offsets) ----------------
#define OFF_XN   ((size_t)0)           // 4,205,000  xn; later cls0
#define OFF_F1   ((size_t)4205000)     // 5,382,400  f1; later y (L x 256)
#define OFF_COMB ((size_t)9587400)     // 4,036,800  comb L x 192
#define OFF_P    ((size_t)13624200)    // 2,691,200  p; later cls1
#define OFF_ZX   ((size_t)16315400)    // 16,231,300 zxbcdt L x 772
#define OFF_XBC  ((size_t)32546700)    // 10,764,800 c1h+c2h first, then xbc packed u32
#define OFF_S    ((size_t)43311500)    // S as bf16 ushort
#define OFF_DT   ((size_t)54092172)    // 84,224 (dt transposed [4][DTP])
#define OFF_CT   ((size_t)54176396)    // 1,316
#define OFF_W    ((size_t)54177712)    // 82,944: packed conv weights (bf16 hi/lo)

__device__ __forceinline__ float gelu_f(float x){
    return 0.5f * x * (1.0f + erff(x * 0.70710678118654752440f));
}
__device__ __forceinline__ float silu_f(float x){
    return x / (1.0f + expf(-x));
}

__device__ __forceinline__ void bf16_split(float x, unsigned short& hs, unsigned short& ls){
    unsigned u = __float_as_uint(x);
    hs = (unsigned short)(u >> 16);
    float hif = __uint_as_float(u & 0xFFFF0000u);
    float lof = x - hif;
    ls = (unsigned short)(__float_as_uint(lof) >> 16);
}
__device__ __forceinline__ unsigned pack2(unsigned short a, unsigned short b){
    return (unsigned)a | ((unsigned)b << 16);
}
__device__ __forceinline__ unsigned packsplit(float x){
    unsigned short hs, ls;
    bf16_split(x, hs, ls);
    return ((unsigned)hs << 16) | (unsigned)ls;
}
__device__ __forceinline__ float unpackf(unsigned u){
    return __uint_as_float(u & 0xFFFF0000u) + __uint_as_float(u << 16);
}
__device__ __forceinline__ unsigned short bf16rnd(float x){
    unsigned u = __float_as_uint(x);
    unsigned r = u + 0x7FFFu + ((u >> 16) & 1u);
    return (unsigned short)(r >> 16);
}
__device__ __forceinline__ float bf16f(unsigned short h){
    return __uint_as_float((unsigned)h << 16);
}
__device__ __forceinline__ void unpack8(const unsigned* p, short8& h8, short8& l8){
    uint4 a = *reinterpret_cast<const uint4*>(p);
    uint4 b = *reinterpret_cast<const uint4*>(p + 4);
    unsigned v0 = a.x, v1 = a.y, v2 = a.z, v3 = a.w;
    unsigned v4 = b.x, v5 = b.y, v6 = b.z, v7 = b.w;
    h8[0]=(short)(v0>>16); l8[0]=(short)(v0&0xFFFFu);
    h8[1]=(short)(v1>>16); l8[1]=(short)(v1&0xFFFFu);
    h8[2]=(short)(v2>>16); l8[2]=(short)(v2&0xFFFFu);
    h8[3]=(short)(v3>>16); l8[3]=(short)(v3&0xFFFFu);
    h8[4]=(short)(v4>>16); l8[4]=(short)(v4&0xFFFFu);
    h8[5]=(short)(v5>>16); l8[5]=(short)(v5&0xFFFFu);
    h8[6]=(short)(v6>>16); l8[6]=(short)(v6&0xFFFFu);
    h8[7]=(short)(v7>>16); l8[7]=(short)(v7&0xFFFFu);
}

// XCD-grouped decode
__device__ __forceinline__ bool gemm_decode(int bid, int NXB, int NYB, int& bx, int& by){
    int m = bid & 7;
    int r = bid >> 3;
    bx = r % NXB;
    by = (r / NXB) * 8 + m;
    return by < NYB;
}
__host__ __forceinline__ int gemm_grid(int NXB, int NYB){ return 8 * ((NYB + 7) / 8) * NXB; }

// ---------------- LayerNorm (pre-LN only) ----------------
template<int ACT>
__global__ void ln_kernel(const float* __restrict__ in, const float* __restrict__ g,
                          const float* __restrict__ b, float* __restrict__ out, int D){
    int row = blockIdx.x, tid = threadIdx.x;
    const float* r = in + (size_t)row * D;
    float s = 0.f, s2 = 0.f;
    for (int i = tid; i < D; i += 256){ float v = r[i]; s += v; s2 += v*v; }
    __shared__ float r1[4], r2[4];
    #pragma unroll
    for (int o = 32; o > 0; o >>= 1){ s += __shfl_down(s, o); s2 += __shfl_down(s2, o); }
    if ((tid & 63) == 0){ r1[tid >> 6] = s; r2[tid >> 6] = s2; }
    __syncthreads();
    float S = r1[0] + r1[1] + r1[2] + r1[3];
    float S2 = r2[0] + r2[1] + r2[2] + r2[3];
    float mean = S / (float)D;
    float var = S2 / (float)D - mean * mean;
    float rs = rsqrtf(fmaxf(var, 0.f) + 1e-5f);
    float* o_ = out + (size_t)row * D;
    for (int i = tid; i < D; i += 256){
        float v = (r[i] - mean) * rs * g[i] + b[i];
        if (ACT == 1) v = gelu_f(v);
        o_[i] = v;
    }
}

// ---------------- wide split-bf16 MFMA GEMM: BN=128, BM=MI*32 ----------------
// ACT: 0 none, 1 gelu, 2 LN, 3 LN+gelu (LN requires N==128, NXB==1)
template<int ACT, int MI>
__global__ __launch_bounds__(256) void gemm_mfma_w(const float* __restrict__ A, int lda,
                                                   const float* __restrict__ B, int ldb,
                                                   const float* __restrict__ bias,
                                                   const float* __restrict__ lng,
                                                   const float* __restrict__ lnb,
                                                   float* __restrict__ C, int ldc,
                                                   int M, int N, int K, int NXB, int NYB){
    const int SA = 40;
    const int BM = MI * 32;
    __shared__ __align__(16) unsigned short Ah[BM * SA], Al[BM * SA];
    __shared__ __align__(16) unsigned short Bh[128 * SA], Bl[128 * SA];
    __shared__ float rs1[2][BM], rs2_[2][BM];
    int bx, by;
    if (!gemm_decode(blockIdx.x, NXB, NYB, bx, by)) return;
    int tid = threadIdx.x;
    int lane = tid & 63, wid = tid >> 6;
    int wy = wid >> 1, wx = wid & 1;
    int bm = by * BM, bn = bx * 128;
    int l15 = lane & 15, g = lane >> 4;

    fv4 acc[MI][4];
    #pragma unroll
    for (int i = 0; i < MI; i++)
        #pragma unroll
        for (int j = 0; j < 4; j++) acc[i][j] = (fv4){0.f,0.f,0.f,0.f};

    int bcol = tid & 127;
    int bk16 = (tid >> 7) * 16;
    bool bcol_ok = (bn + bcol) < N;

    int nK = (K + 31) / 32;
    for (int ks = 0; ks < nK; ks++){
        int k0 = ks * 32;
        #pragma unroll
        for (int f = 0; f < MI; f++){
            int idx = tid * MI + f;
            int row = idx >> 3, qd = idx & 7;
            fv4 v = (fv4){0.f,0.f,0.f,0.f};
            if ((bm + row) < M && (k0 + qd * 4 + 4) <= K)
                v = *reinterpret_cast<const fv4*>(A + (size_t)(bm + row) * lda + k0 + qd * 4);
            unsigned short hs[4], ls[4];
            #pragma unroll
            for (int j = 0; j < 4; j++) bf16_split(v[j], hs[j], ls[j]);
            unsigned off = row * SA + qd * 4;
            *reinterpret_cast<uint2*>(&Ah[off]) = make_uint2(pack2(hs[0],hs[1]), pack2(hs[2],hs[3]));
            *reinterpret_cast<uint2*>(&Al[off]) = make_uint2(pack2(ls[0],ls[1]), pack2(ls[2],ls[3]));
        }
        {
            unsigned short hs[16], ls[16];
            #pragma unroll
            for (int j = 0; j < 16; j++){
                int kk = k0 + bk16 + j;
                float v = (bcol_ok && kk < K) ? B[(size_t)kk * ldb + bn + bcol] : 0.f;
                bf16_split(v, hs[j], ls[j]);
            }
            unsigned off = bcol * SA + bk16;
            *reinterpret_cast<uint4*>(&Bh[off]) = make_uint4(pack2(hs[0],hs[1]), pack2(hs[2],hs[3]),
                                                             pack2(hs[4],hs[5]), pack2(hs[6],hs[7]));
            *reinterpret_cast<uint4*>(&Bh[off + 8]) = make_uint4(pack2(hs[8],hs[9]), pack2(hs[10],hs[11]),
                                                                 pack2(hs[12],hs[13]), pack2(hs[14],hs[15]));
            *reinterpret_cast<uint4*>(&Bl[off]) = make_uint4(pack2(ls[0],ls[1]), pack2(ls[2],ls[3]),
                                                             pack2(ls[4],ls[5]), pack2(ls[6],ls[7]));
            *reinterpret_cast<uint4*>(&Bl[off + 8]) = make_uint4(pack2(ls[8],ls[9]), pack2(ls[10],ls[11]),
                                                                 pack2(ls[12],ls[13]), pack2(ls[14],ls[15]));
        }
        __syncthreads();
        short8 afh[MI], afl[MI], bfh[4], bfl[4];
        #pragma unroll
        for (int mi = 0; mi < MI; mi++){
            unsigned off = (wy * (MI * 16) + mi * 16 + l15) * SA + g * 8;
            afh[mi] = *reinterpret_cast<const short8*>(&Ah[off]);
            afl[mi] = *reinterpret_cast<const short8*>(&Al[off]);
        }
        #pragma unroll
        for (int ni = 0; ni < 4; ni++){
            unsigned off = (wx * 64 + ni * 16 + l15) * SA + g * 8;
            bfh[ni] = *reinterpret_cast<const short8*>(&Bh[off]);
            bfl[ni] = *reinterpret_cast<const short8*>(&Bl[off]);
        }
        #pragma unroll
        for (int mi = 0; mi < MI; mi++)
            #pragma unroll
            for (int ni = 0; ni < 4; ni++){
                acc[mi][ni] = __builtin_amdgcn_mfma_f32_16x16x32_bf16(afh[mi], bfh[ni], acc[mi][ni], 0, 0, 0);
                acc[mi][ni] = __builtin_amdgcn_mfma_f32_16x16x32_bf16(afh[mi], bfl[ni], acc[mi][ni], 0, 0, 0);
                acc[mi][ni] = __builtin_amdgcn_mfma_f32_16x16x32_bf16(afl[mi], bfh[ni], acc[mi][ni], 0, 0, 0);
            }
        __syncthreads();
    }
    float bv[4], lgv[4], lbv[4];
    #pragma unroll
    for (int ni = 0; ni < 4; ni++){
        int cc = bn + wx * 64 + ni * 16 + l15;
        bool ok = cc < N;
        bv[ni]  = (bias && ok) ? bias[cc] : 0.f;
        if (ACT >= 2){ lgv[ni] = ok ? lng[cc] : 1.f; lbv[ni] = ok ? lnb[cc] : 0.f; }
    }
    if (ACT >= 2){
        #pragma unroll
        for (int mi = 0; mi < MI; mi++)
            #pragma unroll
            for (int j = 0; j < 4; j++){
                float s = 0.f, s2 = 0.f;
                #pragma unroll
                for (int ni = 0; ni < 4; ni++){
                    float v = acc[mi][ni][j] + bv[ni];
                    s += v; s2 += v * v;
                }
                #pragma unroll
                for (int o = 1; o < 16; o <<= 1){
                    s += __shfl_xor(s, o); s2 += __shfl_xor(s2, o);
                }
                int row = wy * (MI * 16) + mi * 16 + g * 4 + j;
                if (l15 == 0){ rs1[wx][row] = s; rs2_[wx][row] = s2; }
            }
        __syncthreads();
        #pragma unroll
        for (int mi = 0; mi < MI; mi++)
            #pragma unroll
            for (int j = 0; j < 4; j++){
                int row = wy * (MI * 16) + mi * 16 + g * 4 + j;
                int rr = bm + row;
                if (rr >= M) continue;
                float S = rs1[0][row] + rs1[1][row];
                float S2 = rs2_[0][row] + rs2_[1][row];
                float mean = S / 128.f;
                float var = S2 / 128.f - mean * mean;
                float rsq = rsqrtf(fmaxf(var, 0.f) + 1e-5f);
                #pragma unroll
                for (int ni = 0; ni < 4; ni++){
                    int cc = bn + wx * 64 + ni * 16 + l15;
                    float v = acc[mi][ni][j] + bv[ni];
                    v = (v - mean) * rsq * lgv[ni] + lbv[ni];
                    if (ACT == 3) v = gelu_f(v);
                    C[(size_t)rr * ldc + cc] = v;
                }
            }
    } else {
        #pragma unroll
        for (int mi = 0; mi < MI; mi++)
            #pragma unroll
            for (int ni = 0; ni < 4; ni++){
                int cc = bn + wx * 64 + ni * 16 + l15;
                if (cc >= N) continue;
                #pragma unroll
                for (int j = 0; j < 4; j++){
                    int rr = bm + wy * (MI * 16) + mi * 16 + g * 4 + j;
                    if (rr >= M) continue;
                    float v = acc[mi][ni][j] + bv[ni];
                    if (ACT == 1) v = gelu_f(v);
                    C[(size_t)rr * ldc + cc] = v;
                }
            }
    }
}

// ---------------- fused classifier tail: out = (gelu(A@W2+b2))@W3 + b3 -------------
__global__ __launch_bounds__(256) void cls_tail(const float* __restrict__ A,
                                                const float* __restrict__ W2,
                                                const float* __restrict__ b2,
                                                const float* __restrict__ W3,
                                                const float* __restrict__ b3,
                                                float* __restrict__ out,
                                                int M, int NYB){
    const int SA = 40;
    __shared__ __align__(16) unsigned short Ah[64 * SA], Al[64 * SA];
    __shared__ __align__(16) unsigned short Bh[64 * SA], Bl[64 * SA];
    __shared__ __align__(16) unsigned short A2h[64 * 72], A2l[64 * 72];
    __shared__ __align__(16) unsigned short B3h[32 * 72], B3l[32 * 72];
    int bx, by;
    if (!gemm_decode(blockIdx.x, 1, NYB, bx, by)) return;
    int tid = threadIdx.x;
    int lane = tid & 63, wid = tid >> 6;
    int wy = wid >> 1, wx = wid & 1;
    int bm = by * 64;
    int l15 = lane & 15, g = lane >> 4;

    for (int e = tid; e < 2048; e += 256){
        int n = e >> 6, k = e & 63;
        float v = (n < 17) ? W3[(size_t)k * 17 + n] : 0.f;
        unsigned short hs, ls;
        bf16_split(v, hs, ls);
        B3h[n * 72 + k] = hs;
        B3l[n * 72 + k] = ls;
    }

    fv4 acc[2][2];
    #pragma unroll
    for (int mi = 0; mi < 2; mi++)
        #pragma unroll
        for (int ni = 0; ni < 2; ni++) acc[mi][ni] = (fv4){0.f,0.f,0.f,0.f};

    int bn_t = tid & 63;
    int bk8 = (tid >> 6) * 8;
    #pragma unroll
    for (int ks = 0; ks < 4; ks++){
        int k0 = ks * 32;
        #pragma unroll
        for (int f = 0; f < 2; f++){
            int idx = tid * 2 + f;
            int row = idx >> 3, qd = idx & 7;
            fv4 v = (fv4){0.f,0.f,0.f,0.f};
            if ((bm + row) < M)
                v = *reinterpret_cast<const fv4*>(A + (size_t)(bm + row) * 128 + k0 + qd * 4);
            unsigned short hs[4], ls[4];
            #pragma unroll
            for (int j = 0; j < 4; j++) bf16_split(v[j], hs[j], ls[j]);
            unsigned off = row * SA + qd * 4;
            *reinterpret_cast<uint2*>(&Ah[off]) = make_uint2(pack2(hs[0],hs[1]), pack2(hs[2],hs[3]));
            *reinterpret_cast<uint2*>(&Al[off]) = make_uint2(pack2(ls[0],ls[1]), pack2(ls[2],ls[3]));
        }
        {
            unsigned short hs[8], ls[8];
            #pragma unroll
            for (int j = 0; j < 8; j++){
                int kk = k0 + bk8 + j;
                float v = W2[(size_t)kk * 64 + bn_t];
                bf16_split(v, hs[j], ls[j]);
            }
            unsigned off = bn_t * SA + bk8;
            *reinterpret_cast<uint4*>(&Bh[off]) = make_uint4(pack2(hs[0],hs[1]), pack2(hs[2],hs[3]),
                                                             pack2(hs[4],hs[5]), pack2(hs[6],hs[7]));
            *reinterpret_cast<uint4*>(&Bl[off]) = make_uint4(pack2(ls[0],ls[1]), pack2(ls[2],ls[3]),
                                                             pack2(ls[4],ls[5]), pack2(ls[6],ls[7]));
        }
        __syncthreads();
        short8 afh[2], afl[2], bfh[2], bfl[2];
        #pragma unroll
        for (int mi = 0; mi < 2; mi++){
            unsigned off = (wy * 32 + mi * 16 + l15) * SA + g * 8;
            afh[mi] = *reinterpret_cast<const short8*>(&Ah[off]);
            afl[mi] = *reinterpret_cast<const short8*>(&Al[off]);
        }
        #pragma unroll
        for (int ni = 0; ni < 2; ni++){
            unsigned off = (wx * 32 + ni * 16 + l15) * SA + g * 8;
            bfh[ni] = *reinterpret_cast<const short8*>(&Bh[off]);
            bfl[ni] = *reinterpret_cast<const short8*>(&Bl[off]);
        }
        #pragma unroll
        for (int mi = 0; mi < 2; mi++)
            #pragma unroll
            for (int ni = 0; ni < 2; ni++){
                acc[mi][ni] = __builtin_amdgcn_mfma_f32_16x16x32_bf16(afh[mi], bfh[ni], acc[mi][ni], 0, 0, 0);
                acc[mi][ni] = __builtin_amdgcn_mfma_f32_16x16x32_bf16(afh[mi], bfl[ni], acc[mi][ni], 0, 0, 0);
                acc[mi][ni] = __builtin_amdgcn_mfma_f32_16x16x32_bf16(afl[mi], bfh[ni], acc[mi][ni], 0, 0, 0);
            }
        __syncthreads();
    }
    #pragma unroll
    for (int mi = 0; mi < 2; mi++)
        #pragma unroll
        for (int ni = 0; ni < 2; ni++){
            int col = wx * 32 + ni * 16 + l15;
            float bv = b2[col];
            #pragma unroll
            for (int j = 0; j < 4; j++){
                int row = wy * 32 + mi * 16 + g * 4 + j;
                float v = gelu_f(acc[mi][ni][j] + bv);
                unsigned short hs, ls;
                bf16_split(v, hs, ls);
                A2h[row * 72 + col] = hs;
                A2l[row * 72 + col] = ls;
            }
        }
    __syncthreads();
    fv4 acc3[2];
    acc3[0] = (fv4){0.f,0.f,0.f,0.f};
    acc3[1] = (fv4){0.f,0.f,0.f,0.f};
    #pragma unroll
    for (int ks = 0; ks < 2; ks++){
        unsigned aoff = (wid * 16 + l15) * 72 + ks * 32 + g * 8;
        short8 a2h = *reinterpret_cast<const short8*>(&A2h[aoff]);
        short8 a2l = *reinterpret_cast<const short8*>(&A2l[aoff]);
        #pragma unroll
        for (int ni = 0; ni < 2; ni++){
            unsigned boff = (ni * 16 + l15) * 72 + ks * 32 + g * 8;
            short8 b3h_ = *reinterpret_cast<const short8*>(&B3h[boff]);
            short8 b3l_ = *reinterpret_cast<const short8*>(&B3l[boff]);
            acc3[ni] = __builtin_amdgcn_mfma_f32_16x16x32_bf16(a2h, b3h_, acc3[ni], 0, 0, 0);
            acc3[ni] = __builtin_amdgcn_mfma_f32_16x16x32_bf16(a2h, b3l_, acc3[ni], 0, 0, 0);
            acc3[ni] = __builtin_amdgcn_mfma_f32_16x16x32_bf16(a2l, b3h_, acc3[ni], 0, 0, 0);
        }
    }
    #pragma unroll
    for (int ni = 0; ni < 2; ni++){
        int col = ni * 16 + l15;
        if (col >= 17) continue;
        float bv = b3[col];
        #pragma unroll
        for (int j = 0; j < 4; j++){
            int row = bm + wid * 16 + g * 4 + j;
            if (row >= M) continue;
            out[(size_t)row * 17 + col] = acc3[ni][j] + bv;
        }
    }
}

// ---------------- dt from p ----------------
__global__ __launch_bounds__(256) void dt_from_p(const float* __restrict__ p,
                                                 const float* __restrict__ w,
                                                 const float* __restrict__ dtb,
                                                 float* __restrict__ dtbT){
    __shared__ float wl[512];
    int tid = threadIdx.x;
    for (int i = tid; i < 512; i += 256){
        int k = i >> 2, h = i & 3;
        wl[i] = w[(size_t)k * 772 + 768 + h];
    }
    __syncthreads();
    int t = blockIdx.x * 64 + (tid >> 2);
    int h = tid & 3;
    if (t >= HW) return;
    const float* pr = p + (size_t)t * 128;
    float s = 0.f;
    for (int k = 0; k < 128; k += 4){
        fv4 v = *reinterpret_cast<const fv4*>(pr + k);
        s += v[0]*wl[k*4+h] + v[1]*wl[(k+1)*4+h] + v[2]*wl[(k+2)*4+h] + v[3]*wl[(k+3)*4+h];
    }
    s += dtb[h];
    dtbT[h * DTP + t] = (s > 20.f) ? s : log1pf(expf(s));
}

// ---------------- conv weight prepack ----------------
template<int IC, int OC, int NCHUNK>
__global__ void prep_w(const float* __restrict__ w, unsigned short* __restrict__ Wh,
                       unsigned short* __restrict__ Wl){
    const int KP = NCHUNK * 288;
    int idx = blockIdx.x * 256 + threadIdx.x;
    if (idx >= OC * KP) return;
    int o = idx / KP, k = idx % KP;
    int ch = k / 288, rest = k % 288, t = rest / 32, c = rest & 31;
    int ci = ch * 32 + c;
    float v = (ci < IC) ? w[((size_t)o * IC + ci) * 9 + t] : 0.f;
    unsigned short hs, ls;
    bf16_split(v, hs, ls);
    Wh[idx] = hs; Wl[idx] = ls;
}

// ---------------- MFMA direct conv 3x3 ----------------
template<int IC, int OC, int PAD, int NCHUNK, int NFRAG>
__global__ __launch_bounds__(256) void conv_mfma(const float* __restrict__ in,
                                                 int inH, int inW,
                                                 const unsigned short* __restrict__ Wh,
                                                 const unsigned short* __restrict__ Wl,
                                                 const float* __restrict__ bias,
                                                 float* __restrict__ out){
    const int KP = NCHUNK * 288;
    const int CST = 40;
    __shared__ __align__(16) unsigned short Xh[3 * 68 * CST], Xl[3 * 68 * CST];
    int y = blockIdx.y;
    int x0 = blockIdx.x * 64;
    int tid = threadIdx.x;
    int lane = tid & 63, wid = tid >> 6;
    int wy = wid >> 1, wx = wid & 1;
    int l15 = lane & 15, g = lane >> 4;

    fv4 acc[2][NFRAG];
    #pragma unroll
    for (int mi = 0; mi < 2; mi++)
        #pragma unroll
        for (int ni = 0; ni < NFRAG; ni++) acc[mi][ni] = (fv4){0.f,0.f,0.f,0.f};

    for (int ch = 0; ch < NCHUNK; ch++){
        int ci0 = ch * 32;
        if (ch > 0) __syncthreads();
        for (int e = tid; e < 3 * 68 * 8; e += 256){
            int qd = e & 7;
            int c  = (e >> 3) % 68;
            int r  = e / 544;
            int iy = y - PAD + r, ix = x0 - PAD + c;
            fv4 v = (fv4){0.f,0.f,0.f,0.f};
            if ((unsigned)iy < (unsigned)inH && (unsigned)ix < (unsigned)inW &&
                (ci0 + qd * 4 + 4) <= IC)
                v = *reinterpret_cast<const fv4*>(in + ((size_t)iy * inW + ix) * IC + ci0 + qd * 4);
            unsigned short hs[4], ls[4];
            #pragma unroll
            for (int j = 0; j < 4; j++) bf16_split(v[j], hs[j], ls[j]);
            unsigned off = (r * 68 + c) * CST + qd * 4;
            *reinterpret_cast<uint2*>(&Xh[off]) = make_uint2(pack2(hs[0],hs[1]), pack2(hs[2],hs[3]));
            *reinterpret_cast<uint2*>(&Xl[off]) = make_uint2(pack2(ls[0],ls[1]), pack2(ls[2],ls[3]));
        }
        __syncthreads();
        #pragma unroll
        for (int t = 0; t < 9; t++){
            int ky = t / 3, kx = t % 3;
            short8 ah[2], al[2], bh[NFRAG], bl[NFRAG];
            #pragma unroll
            for (int mi = 0; mi < 2; mi++){
                unsigned off = (ky * 68 + wy * 32 + mi * 16 + l15 + kx) * CST + g * 8;
                ah[mi] = *reinterpret_cast<const short8*>(&Xh[off]);
                al[mi] = *reinterpret_cast<const short8*>(&Xl[off]);
            }
            #pragma unroll
            for (int ni = 0; ni < NFRAG; ni++){
                int oc = wx * (16 * NFRAG) + ni * 16 + l15;
                size_t woff = (size_t)oc * KP + ch * 288 + t * 32 + g * 8;
                bh[ni] = *reinterpret_cast<const short8*>(&Wh[woff]);
                bl[ni] = *reinterpret_cast<const short8*>(&Wl[woff]);
            }
            #pragma unroll
            for (int mi = 0; mi < 2; mi++)
                #pragma unroll
                for (int ni = 0; ni < NFRAG; ni++){
                    acc[mi][ni] = __builtin_amdgcn_mfma_f32_16x16x32_bf16(ah[mi], bh[ni], acc[mi][ni], 0, 0, 0);
                    acc[mi][ni] = __builtin_amdgcn_mfma_f32_16x16x32_bf16(ah[mi], bl[ni], acc[mi][ni], 0, 0, 0);
                    acc[mi][ni] = __builtin_amdgcn_mfma_f32_16x16x32_bf16(al[mi], bh[ni], acc[mi][ni], 0, 0, 0);
                }
        }
    }
    #pragma unroll
    for (int mi = 0; mi < 2; mi++)
        #pragma unroll
        for (int ni = 0; ni < NFRAG; ni++){
            int oc = wx * (16 * NFRAG) + ni * 16 + l15;
            float bv = bias[oc];
            #pragma unroll
            for (int j = 0; j < 4; j++){
                int x = x0 + wy * 32 + mi * 16 + g * 4 + j;
                if (x >= CONVH) continue;
                out[((size_t)y * CONVH + x) * OC + oc] = gelu_f(acc[mi][ni][j] + bv);
            }
        }
}

// ---------------- adaptive pool ----------------
__global__ void pool_kernel(const float* __restrict__ c2, float* __restrict__ comb){
    int idx = blockIdx.x * 256 + threadIdx.x;
    if (idx >= HW * 64) return;
    int o = idx & 63;
    int pix = idx >> 6;
    int xo = pix % Wdim, yo = pix / Wdim;
    int ys = yo * CONVH / Hdim, ye = ((yo + 1) * CONVH + Hdim - 1) / Hdim;
    int xs = xo * CONVH / Wdim, xe = ((xo + 1) * CONVH + Wdim - 1) / Wdim;
    float s = 0.f;
    for (int yy = ys; yy < ye; yy++)
        for (int xx = xs; xx < xe; xx++)
            s += c2[((size_t)yy * CONVH + xx) * 64 + o];
    comb[(size_t)pix * 192 + 128 + o] = s / (float)((ye - ys) * (xe - xs));
}

// ---------------- conv1d + silu -> packed u32 ----------------
__global__ __launch_bounds__(256) void conv1d_tiled(const float* __restrict__ zx,
                                                    const float* __restrict__ w,
                                                    const float* __restrict__ b,
                                                    unsigned* __restrict__ xbcp){
    __shared__ float xs[67 * 128];
    __shared__ float wc[4 * 128];
    __shared__ float bc[128];
    int t0 = blockIdx.y * 64;
    int c0 = blockIdx.x * 128;
    int tid = threadIdx.x;
    for (int e = tid; e < 67 * 128; e += 256){
        int rr = e >> 7, cc = e & 127;
        int t = t0 - 3 + rr;
        xs[e] = (t >= 0 && t < HW) ? zx[(size_t)t * 772 + 256 + c0 + cc] : 0.f;
    }
    if (tid < 128){
        bc[tid] = b[c0 + tid];
        #pragma unroll
        for (int k = 0; k < 4; k++) wc[k * 128 + tid] = w[(c0 + tid) * 4 + k];
    }
    __syncthreads();
    for (int e = tid; e < 64 * 128; e += 256){
        int tt = e >> 7, cc = e & 127;
        if (t0 + tt >= HW) continue;
        float acc = bc[cc];
        #pragma unroll
        for (int k = 0; k < 4; k++) acc += xs[(tt + k) * 128 + cc] * wc[k * 128 + cc];
        xbcp[(size_t)(t0 + tt) * 512 + c0 + cc] = packsplit(silu_f(acc));
    }
}

// ---------------- chunk cumsum (wave 0) ----------------
__device__ __forceinline__ void chunk_cumsum_t(const float* __restrict__ dtbT, int t0, int Q,
                                               int h, const float* __restrict__ A_log,
                                               float* cum, float* dth){
    int tid = threadIdx.x;
    if (tid < 64){
        float d = (tid < Q) ? dtbT[h * DTP + t0 + tid] : 0.f;
        dth[tid] = d;
        float A = -expf(A_log[h]);
        float a = d * A;
        #pragma unroll
        for (int off = 1; off < 64; off <<= 1){
            float u = __shfl_up(a, off);
            if (tid >= off) a += u;
        }
        cum[tid] = a;
    }
    __syncthreads();
}

__device__ __forceinline__ bool ssd_decode(int bid, int& c, int& h){
    int m = bid & 7, rest = bid >> 3;
    h = rest & 3;
    c = (rest >> 2) * 8 + m;
    return c < NCH;
}

// ---------------- SSD phase A (MFMA; B as bf16-hi only — S is bf16 anyway) ---------
__global__ __launch_bounds__(256) void ssd_phaseA(const unsigned* __restrict__ xbcp,
                                                  const float* __restrict__ dtbT,
                                                  const float* __restrict__ A_log,
                                                  unsigned short* __restrict__ Sb,
                                                  float* __restrict__ chunkT){
    __shared__ __align__(16) unsigned short BTh[128 * SP];                // B^T hi [n][s]
    __shared__ __align__(16) unsigned short XTh[64 * SP],  XTl[64 * SP];  // (Xw)^T [p][s]
    __shared__ float cum[64], dth[64], wln[64];
    int c, h;
    if (!ssd_decode(blockIdx.x, c, h)) return;
    int t0 = c * QC, Q = min(QC, HW - t0);
    int tid = threadIdx.x;
    chunk_cumsum_t(dtbT, t0, Q, h, A_log, cum, dth);
    float T = cum[Q - 1];
    if (tid == 0) chunkT[c * 4 + h] = T;
    if (tid < 64) wln[tid] = (tid < Q) ? __expf(T - cum[tid]) * dth[tid] : 0.f;
    __syncthreads();
    for (int e2 = tid; e2 < 4096; e2 += 256){
        int nn = e2 & 127, sp = e2 >> 7;
        int s0 = 2 * sp;
        unsigned v0 = (s0 < Q)     ? xbcp[(size_t)(t0 + s0) * 512 + 256 + nn] : 0u;
        unsigned v1 = (s0 + 1 < Q) ? xbcp[(size_t)(t0 + s0 + 1) * 512 + 256 + nn] : 0u;
        *reinterpret_cast<unsigned*>(&BTh[nn * SP + s0]) = pack2((unsigned short)(v0 >> 16), (unsigned short)(v1 >> 16));
    }
    for (int e2 = tid; e2 < 2048; e2 += 256){
        int pp = e2 & 63, sp = e2 >> 6;
        int s0 = 2 * sp;
        float v0 = (s0 < Q)     ? unpackf(xbcp[(size_t)(t0 + s0) * 512 + h * 64 + pp]) * wln[s0] : 0.f;
        float v1 = (s0 + 1 < Q) ? unpackf(xbcp[(size_t)(t0 + s0 + 1) * 512 + h * 64 + pp]) * wln[s0 + 1] : 0.f;
        unsigned short h0, l0, h1, l1;
        bf16_split(v0, h0, l0); bf16_split(v1, h1, l1);
        *reinterpret_cast<unsigned*>(&XTh[pp * SP + s0]) = pack2(h0, h1);
        *reinterpret_cast<unsigned*>(&XTl[pp * SP + s0]) = pack2(l0, l1);
    }
    __syncthreads();
    int lane = tid & 63, wid = tid >> 6;
    int wy = wid >> 1, wx = wid & 1;
    int l15 = lane & 15, g = lane >> 4;
    fv4 acc[2][4];
    #pragma unroll
    for (int mi = 0; mi < 2; mi++)
        #pragma unroll
        for (int ni = 0; ni < 4; ni++) acc[mi][ni] = (fv4){0.f,0.f,0.f,0.f};
    __builtin_amdgcn_s_setprio(1);
    #pragma unroll
    for (int ks = 0; ks < 2; ks++){
        short8 ah[2], al[2], bh_[4];
        #pragma unroll
        for (int mi = 0; mi < 2; mi++){
            unsigned off = (wy * 32 + mi * 16 + l15) * SP + ks * 32 + g * 8;
            ah[mi] = *reinterpret_cast<const short8*>(&XTh[off]);
            al[mi] = *reinterpret_cast<const short8*>(&XTl[off]);
        }
        #pragma unroll
        for (int ni = 0; ni < 4; ni++){
            unsigned off = (wx * 64 + ni * 16 + l15) * SP + ks * 32 + g * 8;
            bh_[ni] = *reinterpret_cast<const short8*>(&BTh[off]);
        }
        #pragma unroll
        for (int mi = 0; mi < 2; mi++)
            #pragma unroll
            for (int ni = 0; ni < 4; ni++){
                acc[mi][ni] = __builtin_amdgcn_mfma_f32_16x16x32_bf16(ah[mi], bh_[ni], acc[mi][ni], 0, 0, 0);
                acc[mi][ni] = __builtin_amdgcn_mfma_f32_16x16x32_bf16(al[mi], bh_[ni], acc[mi][ni], 0, 0, 0);
            }
    }
    __builtin_amdgcn_s_setprio(0);
    size_t sb = (size_t)(c * 4 + h) * 8192;
    #pragma unroll
    for (int mi = 0; mi < 2; mi++)
        #pragma unroll
        for (int ni = 0; ni < 4; ni++)
            #pragma unroll
            for (int j = 0; j < 4; j++){
                int p = wy * 32 + mi * 16 + g * 4 + j;
                int n = wx * 64 + ni * 16 + l15;
                Sb[sb + p * 128 + n] = bf16rnd(acc[mi][ni][j]);
            }
}

// ---------------- SSD phase B: prefix over chunks (bf16 S, 512x64 grid) ------------
__global__ __launch_bounds__(64) void ssd_phaseB(unsigned short* __restrict__ Sb,
                                                 const float* __restrict__ chunkT){
    __shared__ float e[NCH];
    int tid = threadIdx.x;
    int idx = blockIdx.x * 64 + tid;
    int h = idx >> 13, pn = idx & 8191;
    for (int c = tid; c < NCH; c += 64) e[c] = __expf(chunkT[c * 4 + h]);
    __syncthreads();
    #define ADDR_(cc) Sb[((size_t)((cc) * 4 + h)) * 8192 + pn]
    unsigned short r0 = ADDR_(0), r1 = ADDR_(1), r2 = ADDR_(2), r3 = ADDR_(3);
    float s = 0.f;
    int c = 0;
    for (; c + 8 <= NCH; c += 4){
        unsigned short n0 = ADDR_(c + 4), n1 = ADDR_(c + 5), n2 = ADDR_(c + 6), n3 = ADDR_(c + 7);
        ADDR_(c) = bf16rnd(s);     s = fmaf(s, e[c],     bf16f(r0));
        ADDR_(c + 1) = bf16rnd(s); s = fmaf(s, e[c + 1], bf16f(r1));
        ADDR_(c + 2) = bf16rnd(s); s = fmaf(s, e[c + 2], bf16f(r2));
        ADDR_(c + 3) = bf16rnd(s); s = fmaf(s, e[c + 3], bf16f(r3));
        r0 = n0; r1 = n1; r2 = n2; r3 = n3;
    }
    for (; c < NCH; c++){
        unsigned short nx = (c + 4 < NCH) ? ADDR_(c + 4) : (unsigned short)0;
        float loc = bf16f(r0); r0 = r1; r1 = r2; r2 = r3; r3 = nx;
        ADDR_(c) = bf16rnd(s);
        s = fmaf(s, e[c], loc);
    }
    #undef ADDR_
}

// ---------------- SSD phase C (MFMA, bf16 S direct, bf16 P, fused z-gating) --------
__global__ __launch_bounds__(256) void ssd_phaseC(const unsigned* __restrict__ xbcp,
                                                  const float* __restrict__ zx,
                                                  const float* __restrict__ dtbT,
                                                  const float* __restrict__ A_log,
                                                  const float* __restrict__ Dvec,
                                                  const unsigned short* __restrict__ Sb,
                                                  float* __restrict__ y){
    __shared__ __align__(16) unsigned short U0[64 * SP];                 // P bf16 [t][s]
    __shared__ __align__(16) unsigned short U1h[64 * SP], U1l[64 * SP];  // X^T [p][s]
    __shared__ float cum[64], dth[64];
    int c, h;
    if (!ssd_decode(blockIdx.x, c, h)) return;
    int t0 = c * QC, Q = min(QC, HW - t0);
    int tid = threadIdx.x;
    chunk_cumsum_t(dtbT, t0, Q, h, A_log, cum, dth);
    int lane = tid & 63, wid = tid >> 6;
    int wy = wid >> 1, wx = wid & 1;
    int l15 = lane & 15, g = lane >> 4;

    int trow[2], srow[2], prow[2];
    #pragma unroll
    for (int i = 0; i < 2; i++){
        trow[i] = min(t0 + wy * 32 + i * 16 + l15, HW - 1);
        srow[i] = min(t0 + wx * 32 + i * 16 + l15, HW - 1);
        prow[i] = wx * 32 + i * 16 + l15;
    }

    fv4 accG[2][2], accA[2][2];
    #pragma unroll
    for (int mi = 0; mi < 2; mi++)
        #pragma unroll
        for (int ni = 0; ni < 2; ni++){ accG[mi][ni] = (fv4){0.f,0.f,0.f,0.f}; accA[mi][ni] = (fv4){0.f,0.f,0.f,0.f}; }

    const unsigned short* Sbase = Sb + (size_t)(c * 4 + h) * 8192;
    #pragma unroll
    for (int k0 = 0; k0 < 128; k0 += 32){
        short8 ah[2], al[2], bh[2], bl[2], sh[2];
        #pragma unroll
        for (int mi = 0; mi < 2; mi++)
            unpack8(xbcp + (size_t)trow[mi] * 512 + 384 + k0 + g * 8, ah[mi], al[mi]);
        #pragma unroll
        for (int ni = 0; ni < 2; ni++){
            unpack8(xbcp + (size_t)srow[ni] * 512 + 256 + k0 + g * 8, bh[ni], bl[ni]);
            sh[ni] = *reinterpret_cast<const short8*>(Sbase + prow[ni] * 128 + k0 + g * 8);
        }
        __builtin_amdgcn_s_setprio(1);
        #pragma unroll
        for (int mi = 0; mi < 2; mi++)
            #pragma unroll
            for (int ni = 0; ni < 2; ni++){
                accG[mi][ni] = __builtin_amdgcn_mfma_f32_16x16x32_bf16(ah[mi], bh[ni], accG[mi][ni], 0, 0, 0);
                accG[mi][ni] = __builtin_amdgcn_mfma_f32_16x16x32_bf16(ah[mi], bl[ni], accG[mi][ni], 0, 0, 0);
                accG[mi][ni] = __builtin_amdgcn_mfma_f32_16x16x32_bf16(al[mi], bh[ni], accG[mi][ni], 0, 0, 0);
                accA[mi][ni] = __builtin_amdgcn_mfma_f32_16x16x32_bf16(ah[mi], sh[ni], accA[mi][ni], 0, 0, 0);
                accA[mi][ni] = __builtin_amdgcn_mfma_f32_16x16x32_bf16(al[mi], sh[ni], accA[mi][ni], 0, 0, 0);
            }
        __builtin_amdgcn_s_setprio(0);
    }
    #pragma unroll
    for (int mi = 0; mi < 2; mi++)
        #pragma unroll
        for (int ni = 0; ni < 2; ni++)
            #pragma unroll
            for (int j = 0; j < 4; j++){
                int t = wy * 32 + mi * 16 + g * 4 + j;
                int s = wx * 32 + ni * 16 + l15;
                float pv = 0.f;
                if (s <= t && s < Q)
                    pv = accG[mi][ni][j] * __expf(cum[t] - cum[s]) * dth[s];
                U0[t * SP + s] = bf16rnd(pv);
            }
    for (int e2 = tid; e2 < 2048; e2 += 256){
        int pp = e2 & 63, sp = e2 >> 6;
        int s0 = 2 * sp;
        unsigned v0 = (s0 < Q)     ? xbcp[(size_t)(t0 + s0) * 512 + h * 64 + pp] : 0u;
        unsigned v1 = (s0 + 1 < Q) ? xbcp[(size_t)(t0 + s0 + 1) * 512 + h * 64 + pp] : 0u;
        *reinterpret_cast<unsigned*>(&U1h[pp * SP + s0]) = pack2((unsigned short)(v0 >> 16), (unsigned short)(v1 >> 16));
        *reinterpret_cast<unsigned*>(&U1l[pp * SP + s0]) = pack2((unsigned short)(v0 & 0xFFFFu), (unsigned short)(v1 & 0xFFFFu));
    }
    __syncthreads();
    fv4 accY[2][2];
    #pragma unroll
    for (int mi = 0; mi < 2; mi++)
        #pragma unroll
        for (int ni = 0; ni < 2; ni++)
            #pragma unroll
            for (int j = 0; j < 4; j++){
                int t = wy * 32 + mi * 16 + g * 4 + j;
                accY[mi][ni][j] = __expf(cum[t]) * accA[mi][ni][j];
            }
    __builtin_amdgcn_s_setprio(1);
    #pragma unroll
    for (int kk = 0; kk < 2; kk++){
        short8 ph[2], xh[2], xl[2];
        #pragma unroll
        for (int mi = 0; mi < 2; mi++){
            unsigned off = (wy * 32 + mi * 16 + l15) * SP + kk * 32 + g * 8;
            ph[mi] = *reinterpret_cast<const short8*>(&U0[off]);
        }
        #pragma unroll
        for (int ni = 0; ni < 2; ni++){
            unsigned off = (wx * 32 + ni * 16 + l15) * SP + kk * 32 + g * 8;
            xh[ni] = *reinterpret_cast<const short8*>(&U1h[off]);
            xl[ni] = *reinterpret_cast<const short8*>(&U1l[off]);
        }
        #pragma unroll
        for (int mi = 0; mi < 2; mi++)
            #pragma unroll
            for (int ni = 0; ni < 2; ni++){
                accY[mi][ni] = __builtin_amdgcn_mfma_f32_16x16x32_bf16(ph[mi], xh[ni], accY[mi][ni], 0, 0, 0);
                accY[mi][ni] = __builtin_amdgcn_mfma_f32_16x16x32_bf16(ph[mi], xl[ni], accY[mi][ni], 0, 0, 0);
            }
    }
    __builtin_amdgcn_s_setprio(0);
    float Dh = Dvec[h];
    #pragma unroll
    for (int mi = 0; mi < 2; mi++)
        #pragma unroll
        for (int ni = 0; ni < 2; ni++)
            #pragma unroll
            for (int j = 0; j < 4; j++){
                int t = wy * 32 + mi * 16 + g * 4 + j;
                if (t >= Q) continue;
                int p = wx * 32 + ni * 16 + l15;
                // x[t][p] from LDS (bit-identical to unpackf of xbcp): U1 is [p][s=t]
                float xv = bf16f(U1h[p * SP + t]) + bf16f(U1l[p * SP + t]);
                float zv = zx[(size_t)(t0 + t) * 772 + h * 64 + p];
                y[(size_t)(t0 + t) * 256 + h * 64 + p] = (accY[mi][ni][j] + Dh * xv) * silu_f(zv);
            }
}

// ---------------- RMSNorm (gating already applied in phaseC) ----------------
__global__ void rms_kernel(float* __restrict__ y, const float* __restrict__ nw){
    int row = blockIdx.x, tid = threadIdx.x;
    float v = y[(size_t)row * 256 + tid];
    float s = v * v;
    __shared__ float r1[4];
    #pragma unroll
    for (int o = 32; o > 0; o >>= 1) s += __shfl_down(s, o);
    if ((tid & 63) == 0) r1[tid >> 6] = s;
    __syncthreads();
    float S = r1[0] + r1[1] + r1[2] + r1[3];
    float rs = rsqrtf(S / 256.f + 1e-5f);
    y[(size_t)row * 256 + tid] = v * rs * nw[tid];
}

extern "C" void kernel_launch(void* const* d_in, const int* in_sizes, int n_in,
                              void* d_out, int out_size, void* d_ws, size_t ws_size,
                              hipStream_t stream){
    (void)in_sizes; (void)n_in; (void)out_size; (void)ws_size;
    const float* x        = (const float*)d_in[0];
    const float* ln_pre_g = (const float*)d_in[1];
    const float* ln_pre_b = (const float*)d_in[2];
    const float* fe_w1    = (const float*)d_in[3];
    const float* fe_b1    = (const float*)d_in[4];
    const float* fe_w2    = (const float*)d_in[5];
    const float* fe_b2    = (const float*)d_in[6];
    const float* cv_w1    = (const float*)d_in[7];
    const float* cv_b1    = (const float*)d_in[8];
    const float* cv_w2    = (const float*)d_in[9];
    const float* cv_b2    = (const float*)d_in[10];
    const float* mp_w     = (const float*)d_in[11];
    const float* mp_b     = (const float*)d_in[12];
    const float* mp_ln_g  = (const float*)d_in[13];
    const float* mp_ln_b  = (const float*)d_in[14];
    const float* m_in_w   = (const float*)d_in[15];
    const float* m_conv_w = (const float*)d_in[16];
    const float* m_conv_b = (const float*)d_in[17];
    const float* m_dtb    = (const float*)d_in[18];
    const float* m_A_log  = (const float*)d_in[19];
    const float* m_D      = (const float*)d_in[20];
    const float* m_norm_w = (const float*)d_in[21];
    const float* m_out_w  = (const float*)d_in[22];
    const float* cls_ln_g = (const float*)d_in[23];
    const float* cls_ln_b = (const float*)d_in[24];
    const float* cls_w1   = (const float*)d_in[25];
    const float* cls_b1   = (const float*)d_in[26];
    const float* cls_w2   = (const float*)d_in[27];
    const float* cls_b2   = (const float*)d_in[28];
    const float* cls_w3   = (const float*)d_in[29];
    const float* cls_b3   = (const float*)d_in[30];

    float* ws   = (float*)d_ws;
    float* xn   = ws + OFF_XN;
    float* f1   = ws + OFF_F1;
    float* comb = ws + OFF_COMB;
    float* p    = ws + OFF_P;
    float* zx   = ws + OFF_ZX;
    unsigned* xbcp = (unsigned*)(ws + OFF_XBC);
    unsigned short* Sb = (unsigned short*)(ws + OFF_S);
    float* dtbT = ws + OFF_DT;
    float* chkT = ws + OFF_CT;
    float* c1h  = ws + OFF_XBC;                    // before xbcp live
    float* c2h  = ws + OFF_XBC + 691488;
    float* ybuf = ws + OFF_F1;
    float* cls0 = ws + OFF_XN;
    float* cls1 = ws + OFF_P;
    unsigned short* W1h = (unsigned short*)(ws + OFF_W);
    unsigned short* W1l = (unsigned short*)(ws + OFF_W + 32256);
    unsigned short* W2h = (unsigned short*)(ws + OFF_W + 64512);
    unsigned short* W2l = (unsigned short*)(ws + OFF_W + 73728);
    const float* NUL = (const float*)nullptr;

    // 0. conv weight prepack (tiny)
    prep_w<200, 32, 7><<<(32 * 2016 + 255) / 256, 256, 0, stream>>>(cv_w1, W1h, W1l);
    prep_w<32, 64, 1><<<(64 * 288 + 255) / 256, 256, 0, stream>>>(cv_w2, W2h, W2l);
    // 1. pre-LN
    ln_kernel<0><<<HW, 256, 0, stream>>>(x, ln_pre_g, ln_pre_b, xn, NBANDS);
    // 2-3. feature MLP (f -> comb[:, :128])
    gemm_mfma_w<1, 2><<<gemm_grid(2, 329), 256, 0, stream>>>(xn, 200, fe_w1, 256, fe_b1,
        NUL, NUL, f1, 256, HW, 256, 200, 2, 329);
    gemm_mfma_w<1, 1><<<gemm_grid(1, 658), 256, 0, stream>>>(f1, 256, fe_w2, 128, fe_b2,
        NUL, NUL, comb, 192, HW, 128, 256, 1, 658);
    // 4. conv1 (MFMA implicit-im2col): 200->32, pad 2
    conv_mfma<200, 32, 2, 7, 1><<<dim3(3, CONVH), 256, 0, stream>>>(xn, Hdim, Wdim, W1h, W1l, cv_b1, c1h);
    // 5. conv2 (MFMA): 32->64, pad 1
    conv_mfma<32, 64, 1, 1, 2><<<dim3(3, CONVH), 256, 0, stream>>>(c1h, CONVH, CONVH, W2h, W2l, cv_b2, c2h);
    // 6. adaptive pool -> comb[:, 128:192]
    pool_kernel<<<(HW * 64 + 255) / 256, 256, 0, stream>>>(c2h, comb);
    // 7. mid projection + fused LN + GELU -> p
    gemm_mfma_w<3, 1><<<gemm_grid(1, 658), 256, 0, stream>>>(comb, 192, mp_w, 128, mp_b,
        mp_ln_g, mp_ln_b, p, 128, HW, 128, 192, 1, 658);
    // 8. mamba in_proj (cols 0..768 only)
    gemm_mfma_w<0, 4><<<gemm_grid(6, 165), 256, 0, stream>>>(p, 128, m_in_w, 772,
        NUL, NUL, NUL, zx, 772, HW, 768, 128, 6, 165);
    // 9. dt from p
    dt_from_p<<<(HW + 63) / 64, 256, 0, stream>>>(p, m_in_w, m_dtb, dtbT);
    // 10. depthwise causal conv + silu -> packed u32
    conv1d_tiled<<<dim3(4, NCH), 256, 0, stream>>>(zx, m_conv_w, m_conv_b, xbcp);
    // 11-13. SSD chunked scan
    ssd_phaseA<<<SSD_GRID, 256, 0, stream>>>(xbcp, dtbT, m_A_log, Sb, chkT);
    ssd_phaseB<<<512, 64, 0, stream>>>(Sb, chkT);
    ssd_phaseC<<<SSD_GRID, 256, 0, stream>>>(xbcp, zx, dtbT, m_A_log, m_D, Sb, ybuf);
    // 14. RMSNorm (gating fused into phaseC)
    rms_kernel<<<HW, 256, 0, stream>>>(ybuf, m_norm_w);
    // 15. out proj + fused cls LN -> cls0
    gemm_mfma_w<2, 1><<<gemm_grid(1, 658), 256, 0, stream>>>(ybuf, 256, m_out_w, 128,
        NUL, cls_ln_g, cls_ln_b, cls0, 128, HW, 128, 256, 1, 658);
    // 16. cls1
    gemm_mfma_w<1, 1><<<gemm_grid(1, 658), 256, 0, stream>>>(cls0, 128, cls_w1, 128, cls_b1,
        NUL, NUL, cls1, 128, HW, 128, 128, 1, 658);
    // 17. fused cls2+cls3 -> d_out
    cls_tail<<<gemm_grid(1, 329), 256, 0, stream>>>(cls1, cls_w2, cls_b2, cls_w3, cls_b3,
        (float*)d_out, HW, 329);
}